// Round 10
// baseline (2061.132 us; speedup 1.0000x reference)
//
#include <hip/hip_runtime.h>
#include <hip/hip_bf16.h>
#include <math.h>

typedef __hip_bfloat16 bf16;
typedef __attribute__((ext_vector_type(8))) short short8;
typedef __attribute__((ext_vector_type(4))) short short4v;
typedef __attribute__((ext_vector_type(4))) float f32x4;

constexpr int NB = 16;     // batch
constexpr int ND = 128;    // nodes N
constexpr int SQ = 129;    // S = N+1
constexpr int NH = 24;     // heads
constexpr int DM = 768;    // model dim
constexpr int DF = 3072;   // ffn dim
constexpr int NLAY = 12;
constexpr int MROWS = NB * SQ;  // 2064

__device__ __forceinline__ short f2bs(float f) {
  bf16 h = __float2bfloat16(f);
  return *(short*)&h;
}

__device__ __forceinline__ void gload16(const void* g, void* lds) {
  __builtin_amdgcn_global_load_lds(
      (const __attribute__((address_space(1))) unsigned int*)g,
      (__attribute__((address_space(3))) unsigned int*)lds, 16, 0, 0);
}

// ---------------- node features ----------------
__global__ void k_nodefeat(const int* __restrict__ x, const int* __restrict__ ind,
                           const int* __restrict__ outd,
                           const float* __restrict__ atom, const float* __restrict__ ide,
                           const float* __restrict__ ode, const float* __restrict__ gtok,
                           float* __restrict__ h) {
  int bs = blockIdx.x;
  int b = bs / SQ, s = bs % SQ;
  int t = threadIdx.x;
  float* hrow = h + (size_t)bs * DM;
  if (s == 0) {
    for (int c = t; c < DM; c += 256) hrow[c] = gtok[c];
  } else {
    int n = s - 1;
    const int* xr = x + (b * ND + n) * 9;
    int a0 = xr[0], a1 = xr[1], a2 = xr[2], a3 = xr[3], a4 = xr[4];
    int a5 = xr[5], a6 = xr[6], a7 = xr[7], a8 = xr[8];
    int ii = ind[b * ND + n], oo = outd[b * ND + n];
    for (int c = t; c < DM; c += 256) {
      float acc = ide[(size_t)ii * DM + c] + ode[(size_t)oo * DM + c];
      acc += atom[(size_t)a0 * DM + c];
      acc += atom[(size_t)a1 * DM + c];
      acc += atom[(size_t)a2 * DM + c];
      acc += atom[(size_t)a3 * DM + c];
      acc += atom[(size_t)a4 * DM + c];
      acc += atom[(size_t)a5 * DM + c];
      acc += atom[(size_t)a6 * DM + c];
      acc += atom[(size_t)a7 * DM + c];
      acc += atom[(size_t)a8 * DM + c];
      hrow[c] = acc;
    }
  }
}

// ---------------- gab: virtual-token borders ----------------
__global__ void k_gab_border(const float* __restrict__ ab, const float* __restrict__ virt,
                             float* __restrict__ gab) {
  int b = blockIdx.x;
  const int tot = NH * SQ + NH * ND;
  for (int idx = threadIdx.x; idx < tot; idx += 256) {
    if (idx < NH * SQ) {
      int hh = idx / SQ, j = idx % SQ;
      float v = 2.f * ab[((size_t)b * SQ + 0) * SQ + j] + virt[hh];
      gab[(((size_t)b * NH + hh) * SQ + 0) * SQ + j] = v;
    } else {
      int r = idx - NH * SQ;
      int hh = r / ND, i = r % ND + 1;
      float v = 2.f * ab[((size_t)b * SQ + i) * SQ + 0] + virt[hh];
      gab[(((size_t)b * NH + hh) * SQ + i) * SQ + 0] = v;
    }
  }
}

// ---------------- gab: spatial + multihop edge bias (MFMA, coalesced writes) ----
__global__ __launch_bounds__(256) void k_gab_edge(
    const int* __restrict__ spos, const int* __restrict__ eidx,
    const float* __restrict__ eemb, const float* __restrict__ edemb,
    const float* __restrict__ semb, const float* __restrict__ ab,
    float* __restrict__ gab) {
  __shared__ int eidxs[960];       // 64 j x 5 d x 3 f
  __shared__ short ei2[64 * 136];  // bf16 [j][dh]
  __shared__ short edT[32 * 136];  // bf16 [k][dh]
  __shared__ float ot[24][65];     // raw MFMA out [k][j], padded
  __shared__ float rinvA[64], a2A[64];
  __shared__ int spA[64];
  int bi = blockIdx.x;
  int half = bi & 1;
  int i = (bi >> 1) & 127;
  int b = bi >> 8;
  int j0 = half * 64;
  int t = threadIdx.x;
  const size_t rowbase = ((size_t)(b * ND + i)) * ND + j0;

  const int* esrc = eidx + rowbase * 15;
  for (int idx = t; idx < 960; idx += 256) eidxs[idx] = esrc[idx];
  for (int u = t; u < 720; u += 256) {
    int dh = u / 6, kq = u % 6;
    f32x4 v = *(const f32x4*)&edemb[dh * 24 + kq * 4];
    edT[(kq * 4 + 0) * 136 + dh] = f2bs(v[0]);
    edT[(kq * 4 + 1) * 136 + dh] = f2bs(v[1]);
    edT[(kq * 4 + 2) * 136 + dh] = f2bs(v[2]);
    edT[(kq * 4 + 3) * 136 + dh] = f2bs(v[3]);
  }
  for (int u = t; u < 1472; u += 256) {
    int k, dh;
    if (u < 384) { k = u >> 4; dh = 120 + (u & 15); }
    else { int v = u - 384; k = 24 + v / 136; dh = v % 136; }
    edT[k * 136 + dh] = 0;
  }
  if (t < 64) {
    int j = t;
    int sp = spos[rowbase + j];
    int spc = (sp == 0) ? 1 : sp;
    spc = (spc > 1) ? spc - 1 : spc;
    if (spc > 5) spc = 5;
    spA[j] = sp;
    rinvA[j] = 1.f / (float)spc;
    a2A[j] = 2.f * ab[((size_t)b * SQ + (i + 1)) * SQ + (j0 + j + 1)];
  }
  __syncthreads();

  {
    int j = t & 63, d = t >> 6;
#pragma unroll
    for (int pass = 0; pass < 2; pass++) {
      if (pass == 1) {
        if (t >= 64) break;
        j = t; d = 4;
      }
      const int* ep = &eidxs[j * 15 + d * 3];
      const float* r0 = eemb + (size_t)ep[0] * NH;
      const float* r1 = eemb + (size_t)ep[1] * NH;
      const float* r2 = eemb + (size_t)ep[2] * NH;
#pragma unroll
      for (int hq = 0; hq < 6; hq++) {
        f32x4 s = (*(const f32x4*)&r0[hq * 4] + *(const f32x4*)&r1[hq * 4] +
                   *(const f32x4*)&r2[hq * 4]) * (1.f / 3.f);
        short4v o;
        o[0] = f2bs(s[0]); o[1] = f2bs(s[1]); o[2] = f2bs(s[2]); o[3] = f2bs(s[3]);
        *(short4v*)&ei2[j * 136 + d * 24 + hq * 4] = o;
      }
    }
  }
  for (int idx = t; idx < 64 * 8; idx += 256) {
    int j = idx >> 3;
    ei2[j * 136 + 120 + (idx & 7)] = 0;
  }
  __syncthreads();

  int lane = t & 63, w = t >> 6;
  int fr = lane & 15, q = lane >> 4, fo = q * 8;
  f32x4 acc0 = {0.f, 0.f, 0.f, 0.f}, acc1 = {0.f, 0.f, 0.f, 0.f};
#pragma unroll
  for (int kk = 0; kk < 4; kk++) {
    short8 af = *(const short8*)&ei2[(w * 16 + fr) * 136 + kk * 32 + fo];
    short8 b0 = *(const short8*)&edT[(fr) * 136 + kk * 32 + fo];
    short8 b1 = *(const short8*)&edT[(16 + fr) * 136 + kk * 32 + fo];
    acc0 = __builtin_amdgcn_mfma_f32_16x16x32_bf16(af, b0, acc0, 0, 0, 0);
    acc1 = __builtin_amdgcn_mfma_f32_16x16x32_bf16(af, b1, acc1, 0, 0, 0);
  }
#pragma unroll
  for (int e = 0; e < 4; e++) {
    int j = w * 16 + q * 4 + e;
    ot[fr][j] = acc0[e];
    if (fr < 8) ot[16 + fr][j] = acc1[e];
  }
  __syncthreads();
  size_t obase = (((size_t)b * NH) * SQ + (i + 1)) * SQ + (j0 + 1);
  for (int idx = t; idx < 24 * 64; idx += 256) {
    int k = idx >> 6, j = idx & 63;
    float v = a2A[j] + semb[spA[j] * NH + k] + ot[k][j] * rinvA[j];
    gab[obase + (size_t)k * SQ * SQ + j] = v;
  }
}

// ---------------- weight transpose+cast: f32 [R,C] -> bf16 [C,R] ----------------
struct Ptrs4 { const float* p[4]; };

template <int NW>
__global__ void k_transpose(Ptrs4 ps, short* __restrict__ dst, int R, int C,
                            size_t sstride) {
  __shared__ short tile[64][68];
  int z = blockIdx.z;
  const float* src = ps.p[z % NW] + (size_t)(z / NW) * sstride;
  short* d = dst + (size_t)z * (size_t)R * C;
  int r0 = blockIdx.x * 64, c0 = blockIdx.y * 64;
  int t = threadIdx.x;
  int tr = t >> 4, tc = (t & 15) * 4;
#pragma unroll
  for (int i = 0; i < 4; i++) {
    int r = tr + i * 16;
    f32x4 v = *(const f32x4*)(src + (size_t)(r0 + r) * C + c0 + tc);
    tile[r][tc + 0] = f2bs(v[0]);
    tile[r][tc + 1] = f2bs(v[1]);
    tile[r][tc + 2] = f2bs(v[2]);
    tile[r][tc + 3] = f2bs(v[3]);
  }
  __syncthreads();
#pragma unroll
  for (int i = 0; i < 4; i++) {
    int rr = tr + i * 16;
    short4v o;
    o[0] = tile[tc + 0][rr];
    o[1] = tile[tc + 1][rr];
    o[2] = tile[tc + 2][rr];
    o[3] = tile[tc + 3][rr];
    *(short4v*)(d + (size_t)(c0 + rr) * R + r0 + tc) = o;
  }
}

// ---------------- LayerNorm: fp32 row -> bf16 row ----------------
__global__ void k_ln(const float* __restrict__ h, const float* __restrict__ g,
                     const float* __restrict__ bb, bf16* __restrict__ y) {
  int r = blockIdx.x;
  int t = threadIdx.x, lane = t & 63, wid = t >> 6;
  __shared__ float red[8];
  const float* row = h + (size_t)r * DM;
  float v0 = row[t], v1 = row[t + 256], v2 = row[t + 512];
  float s = v0 + v1 + v2;
#pragma unroll
  for (int o = 32; o > 0; o >>= 1) s += __shfl_xor(s, o);
  if (lane == 0) red[wid] = s;
  __syncthreads();
  float mean = (red[0] + red[1] + red[2] + red[3]) * (1.f / 768.f);
  float d0 = v0 - mean, d1 = v1 - mean, d2 = v2 - mean;
  float q = d0 * d0 + d1 * d1 + d2 * d2;
#pragma unroll
  for (int o = 32; o > 0; o >>= 1) q += __shfl_xor(q, o);
  if (lane == 0) red[4 + wid] = q;
  __syncthreads();
  float var = (red[4] + red[5] + red[6] + red[7]) * (1.f / 768.f);
  float rstd = rsqrtf(var + 1e-5f);
  bf16* yr = y + (size_t)r * DM;
  yr[t] = __float2bfloat16(d0 * rstd * g[t] + bb[t]);
  yr[t + 256] = __float2bfloat16(d1 * rstd * g[t + 256] + bb[t + 256]);
  yr[t + 512] = __float2bfloat16(d2 * rstd * g[t + 512] + bb[t + 512]);
}

// ---------------- fused: h += p0+cbias; y = LN(h) ----------------
__global__ void k_ln_add1(float* __restrict__ h, const float* __restrict__ p0,
                          const float* __restrict__ cb,
                          const float* __restrict__ g, const float* __restrict__ bb,
                          bf16* __restrict__ y) {
  int r = blockIdx.x;
  int t = threadIdx.x, lane = t & 63, wid = t >> 6;
  __shared__ float red[8];
  size_t base = (size_t)r * DM;
  float v0 = h[base + t] + p0[base + t] + cb[t];
  float v1 = h[base + t + 256] + p0[base + t + 256] + cb[t + 256];
  float v2 = h[base + t + 512] + p0[base + t + 512] + cb[t + 512];
  h[base + t] = v0;
  h[base + t + 256] = v1;
  h[base + t + 512] = v2;
  float s = v0 + v1 + v2;
#pragma unroll
  for (int o = 32; o > 0; o >>= 1) s += __shfl_xor(s, o);
  if (lane == 0) red[wid] = s;
  __syncthreads();
  float mean = (red[0] + red[1] + red[2] + red[3]) * (1.f / 768.f);
  float d0 = v0 - mean, d1 = v1 - mean, d2 = v2 - mean;
  float q = d0 * d0 + d1 * d1 + d2 * d2;
#pragma unroll
  for (int o = 32; o > 0; o >>= 1) q += __shfl_xor(q, o);
  if (lane == 0) red[4 + wid] = q;
  __syncthreads();
  float var = (red[4] + red[5] + red[6] + red[7]) * (1.f / 768.f);
  float rstd = rsqrtf(var + 1e-5f);
  bf16* yr = y + base;
  yr[t] = __float2bfloat16(d0 * rstd * g[t] + bb[t]);
  yr[t + 256] = __float2bfloat16(d1 * rstd * g[t + 256] + bb[t + 256]);
  yr[t + 512] = __float2bfloat16(d2 * rstd * g[t + 512] + bb[t + 512]);
}

// ---------------- GEMM common ----------------
// MODE 0: fp32+bias; MODE 2: GELU->bf16; MODE 3: raw fp32; MODE 4: bf16+bias
struct GemmPtrs {
  const short* bt[3];
  const float* bias[3];
  void* out[3];
  int aoff[3];
};

template <int MODE>
__device__ __forceinline__ void gemm_store(void* outp, size_t idx, float v) {
  if (MODE == 0 || MODE == 3) {
    ((float*)outp)[idx] = v;
  } else if (MODE == 4) {
    ((bf16*)outp)[idx] = __float2bfloat16(v);
  } else {
    float gg = 0.5f * v * (1.f + erff(v * 0.70710678118654752f));
    ((bf16*)outp)[idx] = __float2bfloat16(gg);
  }
}

// 128x128 block, 4 waves x 64x64, BK=32, DOUBLE-buffer, swizzled. 32KB -> 3/CU.
// Swizzle: LDS slot (row,s) holds global seg s^((row>>1)&3); reader seg q^((fr>>1)&3).
template <int MODE>
__global__ __launch_bounds__(256, 3) void k_gemm128(const short* __restrict__ A, GemmPtrs p,
                                                    int M, int N, int K, int lda, int ldb) {
  __shared__ short At[2][128 * 32];
  __shared__ short Bt[2][128 * 32];
  int z = blockIdx.z;
  const short* BT = p.bt[z];
  const float* bias = p.bias[z];
  A += p.aoff[z];
  int m0 = blockIdx.x * 128, n0 = blockIdx.y * 128;
  int t = threadIdx.x, lane = t & 63, wid = t >> 6;
  int wr = wid >> 1, wc = wid & 1;
  f32x4 acc[4][4];
#pragma unroll
  for (int a = 0; a < 4; a++)
#pragma unroll
    for (int c = 0; c < 4; c++) acc[a][c] = (f32x4){0.f, 0.f, 0.f, 0.f};

  int lrow = lane >> 2;                 // 0..15 local row
  int lseg = (lane & 3) ^ ((lane >> 3) & 3);  // pre-swizzled global seg
  const short* gA[2];
  const short* gB[2];
#pragma unroll
  for (int i = 0; i < 2; i++) {
    int ar = m0 + wid * 32 + i * 16 + lrow;
    if (ar >= M) ar = M - 1;
    gA[i] = A + (size_t)ar * lda + lseg * 8;
    int br = n0 + wid * 32 + i * 16 + lrow;
    gB[i] = BT + (size_t)br * ldb + lseg * 8;
  }

  const int NIT = K >> 5;
  // prologue: stage tile 0 into buf 0
#pragma unroll
  for (int i = 0; i < 2; i++) {
    gload16(gA[i], &At[0][(wid * 32 + i * 16) * 32]);
    gload16(gB[i], &Bt[0][(wid * 32 + i * 16) * 32]);
  }
  __syncthreads();

  int fr = lane & 15, q = lane >> 4;
  int sg = (q ^ ((fr >> 1) & 3)) * 8;
  for (int it = 0; it < NIT; ++it) {
    int cur = it & 1;
    if (it + 1 < NIT) {
      int nxt = cur ^ 1;
      int k0 = (it + 1) << 5;
#pragma unroll
      for (int i = 0; i < 2; i++) {
        gload16(gA[i] + k0, &At[nxt][(wid * 32 + i * 16) * 32]);
        gload16(gB[i] + k0, &Bt[nxt][(wid * 32 + i * 16) * 32]);
      }
    }
    const short* Ab = At[cur];
    const short* Bb = Bt[cur];
    short8 af[4], bf[4];
#pragma unroll
    for (int mr = 0; mr < 4; mr++)
      af[mr] = *(const short8*)&Ab[(wr * 64 + mr * 16 + fr) * 32 + sg];
#pragma unroll
    for (int nc = 0; nc < 4; nc++)
      bf[nc] = *(const short8*)&Bb[(wc * 64 + nc * 16 + fr) * 32 + sg];
#pragma unroll
    for (int mr = 0; mr < 4; mr++)
#pragma unroll
      for (int nc = 0; nc < 4; nc++)
        acc[mr][nc] = __builtin_amdgcn_mfma_f32_16x16x32_bf16(af[mr], bf[nc], acc[mr][nc], 0, 0, 0);
    __syncthreads();
  }

  int rsub = q * 4;
#pragma unroll
  for (int nc = 0; nc < 4; nc++) {
    int col = n0 + wc * 64 + nc * 16 + fr;
    float bv = (MODE == 3) ? 0.f : bias[col];
#pragma unroll
    for (int mr = 0; mr < 4; mr++) {
#pragma unroll
      for (int e = 0; e < 4; e++) {
        int r = m0 + wr * 64 + mr * 16 + rsub + e;
        if (r < M) gemm_store<MODE>(p.out[z], (size_t)r * N + col, acc[mr][nc][e] + bv);
      }
    }
  }
}

// 64x128 block, 4 waves x 32x64, BK=32, DOUBLE-buffer, swizzled. 24KB -> 4/CU.
template <int MODE>
__global__ __launch_bounds__(256, 4) void k_gemm64(const short* __restrict__ A, GemmPtrs p,
                                                   int M, int N, int K, int lda, int ldb) {
  __shared__ short At[2][64 * 32];
  __shared__ short Bt[2][128 * 32];
  int z = blockIdx.z;
  const short* BT = p.bt[z];
  const float* bias = p.bias[z];
  A += p.aoff[z];
  int m0 = blockIdx.x * 64, n0 = blockIdx.y * 128;
  int t = threadIdx.x, lane = t & 63, wid = t >> 6;
  int wr = wid >> 1, wc = wid & 1;
  f32x4 acc[2][4];
#pragma unroll
  for (int a = 0; a < 2; a++)
#pragma unroll
    for (int c = 0; c < 4; c++) acc[a][c] = (f32x4){0.f, 0.f, 0.f, 0.f};

  int lrow = lane >> 2;
  int lseg = (lane & 3) ^ ((lane >> 3) & 3);
  int ar = m0 + wid * 16 + lrow;
  if (ar >= M) ar = M - 1;
  const short* gA0 = A + (size_t)ar * lda + lseg * 8;
  const short* gB[2];
#pragma unroll
  for (int i = 0; i < 2; i++) {
    int br = n0 + wid * 32 + i * 16 + lrow;
    gB[i] = BT + (size_t)br * ldb + lseg * 8;
  }

  const int NIT = K >> 5;
  {
    gload16(gA0, &At[0][(wid * 16) * 32]);
#pragma unroll
    for (int i = 0; i < 2; i++) gload16(gB[i], &Bt[0][(wid * 32 + i * 16) * 32]);
  }
  __syncthreads();

  int fr = lane & 15, q = lane >> 4;
  int sg = (q ^ ((fr >> 1) & 3)) * 8;
  for (int it = 0; it < NIT; ++it) {
    int cur = it & 1;
    if (it + 1 < NIT) {
      int nxt = cur ^ 1;
      int k0 = (it + 1) << 5;
      gload16(gA0 + k0, &At[nxt][(wid * 16) * 32]);
#pragma unroll
      for (int i = 0; i < 2; i++) gload16(gB[i] + k0, &Bt[nxt][(wid * 32 + i * 16) * 32]);
    }
    const short* Ab = At[cur];
    const short* Bb = Bt[cur];
    short8 af[2], bf[4];
#pragma unroll
    for (int mr = 0; mr < 2; mr++)
      af[mr] = *(const short8*)&Ab[(wr * 32 + mr * 16 + fr) * 32 + sg];
#pragma unroll
    for (int nc = 0; nc < 4; nc++)
      bf[nc] = *(const short8*)&Bb[(wc * 64 + nc * 16 + fr) * 32 + sg];
#pragma unroll
    for (int mr = 0; mr < 2; mr++)
#pragma unroll
      for (int nc = 0; nc < 4; nc++)
        acc[mr][nc] = __builtin_amdgcn_mfma_f32_16x16x32_bf16(af[mr], bf[nc], acc[mr][nc], 0, 0, 0);
    __syncthreads();
  }

  int rsub = q * 4;
#pragma unroll
  for (int nc = 0; nc < 4; nc++) {
    int col = n0 + wc * 64 + nc * 16 + fr;
    float bv = (MODE == 3) ? 0.f : bias[col];
#pragma unroll
    for (int mr = 0; mr < 2; mr++) {
#pragma unroll
      for (int e = 0; e < 4; e++) {
        int r = m0 + wr * 32 + mr * 16 + rsub + e;
        if (r < M) gemm_store<MODE>(p.out[z], (size_t)r * N + col, acc[mr][nc][e] + bv);
      }
    }
  }
}

// ---------------- attention: MFMA flash, one block per (b,h) ----------------
__global__ __launch_bounds__(256) void k_attn(const bf16* __restrict__ Q,
                                              const bf16* __restrict__ Kb,
                                              const bf16* __restrict__ Vb,
                                              const float* __restrict__ gab,
                                              bf16* __restrict__ ctx) {
  __shared__ short Ql[144 * 40];   // [row][k], rows 129+ zeroed
  __shared__ short Kl[144 * 40];   // [kk][k], rows 129+ zeroed
  __shared__ short Vt[32 * 168];   // [d][kk], kk 128+ zeroed
  __shared__ short Pc[144 * 40];   // P chunk [row][kk_local], wave-private rows
  int bh = blockIdx.x;
  int b = bh / NH, hh = bh % NH;
  int t = threadIdx.x;
  for (int idx = t; idx < 32 * 40; idx += 256) {
    int d = idx / 40, kk = 128 + (idx % 40);
    Vt[d * 168 + kk] = 0;
  }
  for (int idx = t; idx < 129 * 4; idx += 256) {
    int s = idx >> 2, seg = idx & 3;
    size_t src = ((size_t)(b * SQ + s)) * DM + hh * 32 + seg * 8;
    *(short8*)&Ql[s * 40 + seg * 8] = *(const short8*)((const short*)Q + src);
    *(short8*)&Kl[s * 40 + seg * 8] = *(const short8*)((const short*)Kb + src);
  }
  for (int idx = t; idx < 15 * 4; idx += 256) {
    int s = 129 + (idx >> 2), seg = idx & 3;
    short8 zz = {0, 0, 0, 0, 0, 0, 0, 0};
    *(short8*)&Ql[s * 40 + seg * 8] = zz;
    *(short8*)&Kl[s * 40 + seg * 8] = zz;
  }
  for (int idx = t; idx < 129 * 4; idx += 256) {
    int kk = idx >> 2, seg = idx & 3;
    size_t src = ((size_t)(b * SQ + kk)) * DM + hh * 32 + seg * 8;
    short8 v = *(const short8*)((const short*)Vb + src);
#pragma unroll
    for (int j = 0; j < 8; j++) Vt[(seg * 8 + j) * 168 + kk] = v[j];
  }
  __syncthreads();

  int lane = t & 63, w = t >> 6;
  int c16 = lane & 15, q4 = lane >> 4;
  const float scale = 0.17677669529663689f;  // 1/sqrt(32)
  const float* gabp = gab + (((size_t)(b * NH + hh)) * SQ) * SQ;

  for (int mt = w; mt < 9; mt += 4) {
    f32x4 sc[9];
    short8 aq = *(const short8*)&Ql[(mt * 16 + c16) * 40 + q4 * 8];
#pragma unroll
    for (int nt = 0; nt < 9; nt++) {
      short8 bk = *(const short8*)&Kl[(nt * 16 + c16) * 40 + q4 * 8];
      f32x4 zz = {0.f, 0.f, 0.f, 0.f};
      sc[nt] = __builtin_amdgcn_mfma_f32_16x16x32_bf16(aq, bk, zz, 0, 0, 0);
    }
#pragma unroll
    for (int e = 0; e < 4; e++) {
      int row = mt * 16 + q4 * 4 + e;
      int rr = row < 129 ? row : 128;
      const float* grow = gabp + (size_t)rr * SQ;
      float mloc = -1e30f;
#pragma unroll
      for (int nt = 0; nt < 9; nt++) {
        int col = nt * 16 + c16;
        float s = (col < 129) ? (sc[nt][e] * scale + grow[col]) : -1e30f;
        sc[nt][e] = s;
        mloc = fmaxf(mloc, s);
      }
#pragma unroll
      for (int o = 1; o < 16; o <<= 1) mloc = fmaxf(mloc, __shfl_xor(mloc, o));
      float sum = 0.f;
#pragma unroll
      for (int nt = 0; nt < 9; nt++) {
        float pp = __expf(sc[nt][e] - mloc);
        sc[nt][e] = pp;
        sum += pp;
      }
#pragma unroll
      for (int o = 1; o < 16; o <<= 1) sum += __shfl_xor(sum, o);
      float inv = 1.f / sum;
#pragma unroll
      for (int nt = 0; nt < 9; nt++) sc[nt][e] *= inv;
    }
    f32x4 oacc0 = {0.f, 0.f, 0.f, 0.f}, oacc1 = {0.f, 0.f, 0.f, 0.f};
#pragma unroll
    for (int c = 0; c < 5; c++) {
#pragma unroll
      for (int u = 0; u < 2; u++) {
        int nt = c * 2 + u;
        if (nt < 9) {
#pragma unroll
          for (int e = 0; e < 4; e++)
            Pc[(mt * 16 + q4 * 4 + e) * 40 + u * 16 + c16] = f2bs(sc[nt][e]);
        } else {
#pragma unroll
          for (int e = 0; e < 4; e++)
            Pc[(mt * 16 + q4 * 4 + e) * 40 + u * 16 + c16] = 0;
        }
      }
      asm volatile("s_waitcnt lgkmcnt(0)" ::: "memory");
      __builtin_amdgcn_sched_barrier(0);
      short8 ap = *(const short8*)&Pc[(mt * 16 + c16) * 40 + q4 * 8];
      short8 bv0 = *(const short8*)&Vt[(c16) * 168 + c * 32 + q4 * 8];
      short8 bv1 = *(const short8*)&Vt[(16 + c16) * 168 + c * 32 + q4 * 8];
      oacc0 = __builtin_amdgcn_mfma_f32_16x16x32_bf16(ap, bv0, oacc0, 0, 0, 0);
      oacc1 = __builtin_amdgcn_mfma_f32_16x16x32_bf16(ap, bv1, oacc1, 0, 0, 0);
    }
#pragma unroll
    for (int e = 0; e < 4; e++) {
      int row = mt * 16 + q4 * 4 + e;
      if (row < 129) {
        size_t obase = ((size_t)(b * SQ + row)) * DM + hh * 32;
        ctx[obase + c16] = __float2bfloat16(oacc0[e]);
        ctx[obase + 16 + c16] = __float2bfloat16(oacc1[e]);
      }
    }
  }
}

// ---------------- final: h_row0 + p0 + cbias -> LN -> project ----------------
__global__ void k_final_add1(const float* __restrict__ h, const float* __restrict__ p0,
                             const float* __restrict__ cb,
                             const float* __restrict__ g, const float* __restrict__ bb,
                             const float* __restrict__ ow, const float* __restrict__ ob,
                             float* __restrict__ out) {
  int b = blockIdx.x;
  int t = threadIdx.x, lane = t & 63, wid = t >> 6;
  __shared__ float red[8];
  __shared__ float yn[768];
  size_t base = (size_t)(b * SQ) * DM;
  float v0 = h[base + t] + p0[base + t] + cb[t];
  float v1 = h[base + t + 256] + p0[base + t + 256] + cb[t + 256];
  float v2 = h[base + t + 512] + p0[base + t + 512] + cb[t + 512];
  float s = v0 + v1 + v2;
#pragma unroll
  for (int o = 32; o > 0; o >>= 1) s += __shfl_xor(s, o);
  if (lane == 0) red[wid] = s;
  __syncthreads();
  float mean = (red[0] + red[1] + red[2] + red[3]) * (1.f / 768.f);
  float d0 = v0 - mean, d1 = v1 - mean, d2 = v2 - mean;
  float q = d0 * d0 + d1 * d1 + d2 * d2;
#pragma unroll
  for (int o = 32; o > 0; o >>= 1) q += __shfl_xor(q, o);
  if (lane == 0) red[4 + wid] = q;
  __syncthreads();
  float var = (red[4] + red[5] + red[6] + red[7]) * (1.f / 768.f);
  float rstd = rsqrtf(var + 1e-5f);
  yn[t] = d0 * rstd * g[t] + bb[t];
  yn[t + 256] = d1 * rstd * g[t + 256] + bb[t + 256];
  yn[t + 512] = d2 * rstd * g[t + 512] + bb[t + 512];
  __syncthreads();
  if (t < 128) {
    float acc = ob[t];
    for (int d = 0; d < 768; d++) acc += yn[d] * ow[d * 128 + t];
    out[b * 128 + t] = acc;
  }
}

extern "C" void kernel_launch(void* const* d_in, const int* in_sizes, int n_in,
                              void* d_out, int out_size, void* d_ws, size_t ws_size,
                              hipStream_t stream) {
  (void)in_sizes; (void)n_in; (void)out_size;
  const int* x     = (const int*)d_in[0];
  const int* ind   = (const int*)d_in[1];
  const int* outd  = (const int*)d_in[2];
  const int* spos  = (const int*)d_in[3];
  const int* eidx  = (const int*)d_in[4];
  const float* ab   = (const float*)d_in[5];
  const float* atom = (const float*)d_in[6];
  const float* ide  = (const float*)d_in[7];
  const float* ode  = (const float*)d_in[8];
  const float* gtok = (const float*)d_in[9];
  const float* eemb = (const float*)d_in[10];
  const float* edemb= (const float*)d_in[11];
  const float* semb = (const float*)d_in[12];
  const float* virt = (const float*)d_in[13];
  const float* ln1g = (const float*)d_in[14];
  const float* ln1b = (const float*)d_in[15];
  const float* wq  = (const float*)d_in[16];
  const float* bq   = (const float*)d_in[17];
  const float* wk  = (const float*)d_in[18];
  const float* bk   = (const float*)d_in[19];
  const float* wv  = (const float*)d_in[20];
  const float* bv   = (const float*)d_in[21];
  const float* wo  = (const float*)d_in[22];
  const float* bo   = (const float*)d_in[23];
  const float* ln2g = (const float*)d_in[24];
  const float* ln2b = (const float*)d_in[25];
  const float* w1  = (const float*)d_in[26];
  const float* b1   = (const float*)d_in[27];
  const float* w2  = (const float*)d_in[28];
  const float* b2   = (const float*)d_in[29];
  const float* fg   = (const float*)d_in[30];
  const float* fb   = (const float*)d_in[31];
  const float* ow   = (const float*)d_in[32];
  const float* ob   = (const float*)d_in[33];
  float* out = (float*)d_out;

  const int DD2 = DM * DM;
  const size_t WQKVO = (size_t)DD2;
  const size_t WFF = (size_t)DM * DF;

  char* ws = (char*)d_ws;
  size_t off = 0;
  auto alloc = [&](size_t bytes) -> void* {
    void* p = ws + off;
    off += (bytes + 255) & ~(size_t)255;
    return p;
  };
  float* gab = (float*)alloc((size_t)NB * NH * SQ * SQ * 4);
  float* h   = (float*)alloc((size_t)MROWS * DM * 4);
  bf16* y    = (bf16*)alloc((size_t)MROWS * DM * 2);
  bf16* qb   = (bf16*)alloc((size_t)MROWS * DM * 2);
  bf16* kb2  = (bf16*)alloc((size_t)MROWS * DM * 2);
  bf16* vb2  = (bf16*)alloc((size_t)MROWS * DM * 2);
  bf16* ctx  = (bf16*)alloc((size_t)MROWS * DM * 2);
  bf16* t1   = (bf16*)alloc((size_t)MROWS * DF * 2);
  float* p0  = (float*)alloc((size_t)MROWS * DM * 4);

  size_t need_hoist = off + ((size_t)NLAY * 4 * WQKVO + 2 * (size_t)NLAY * WFF) * 2 + (1 << 20);
  bool hoist = ws_size >= need_hoist;
  short* wT  = (short*)alloc((hoist ? (size_t)NLAY * 4 * WQKVO : 4 * WQKVO) * 2);
  short* w1T = (short*)alloc((hoist ? (size_t)NLAY * WFF : WFF) * 2);
  short* w2T = (short*)alloc((hoist ? (size_t)NLAY * WFF : WFF) * 2);

  dim3 blk(256);
  k_nodefeat<<<dim3(NB * SQ), blk, 0, stream>>>(x, ind, outd, atom, ide, ode, gtok, h);
  k_gab_border<<<dim3(NB), blk, 0, stream>>>(ab, virt, gab);
  k_gab_edge<<<dim3(NB * ND * 2), blk, 0, stream>>>(spos, eidx, eemb, edemb, semb, ab, gab);

  if (hoist) {
    Ptrs4 pq; pq.p[0] = wq; pq.p[1] = wk; pq.p[2] = wv; pq.p[3] = wo;
    k_transpose<4><<<dim3(12, 12, 48), blk, 0, stream>>>(pq, wT, DM, DM, WQKVO);
    Ptrs4 pa; pa.p[0] = w1; pa.p[1] = pa.p[2] = pa.p[3] = w1;
    k_transpose<1><<<dim3(12, 48, 12), blk, 0, stream>>>(pa, w1T, DM, DF, WFF);
    Ptrs4 pb; pb.p[0] = w2; pb.p[1] = pb.p[2] = pb.p[3] = w2;
    k_transpose<1><<<dim3(48, 12, 12), blk, 0, stream>>>(pb, w2T, DF, DM, WFF);
  }

  for (int l = 0; l < NLAY; l++) {
    if (!hoist) {
      Ptrs4 pq;
      pq.p[0] = wq + (size_t)l * DD2; pq.p[1] = wk + (size_t)l * DD2;
      pq.p[2] = wv + (size_t)l * DD2; pq.p[3] = wo + (size_t)l * DD2;
      k_transpose<4><<<dim3(12, 12, 4), blk, 0, stream>>>(pq, wT, DM, DM, 0);
      Ptrs4 pa; pa.p[0] = w1 + (size_t)l * WFF; pa.p[1] = pa.p[2] = pa.p[3] = pa.p[0];
      k_transpose<1><<<dim3(12, 48, 1), blk, 0, stream>>>(pa, w1T, DM, DF, 0);
      Ptrs4 pb; pb.p[0] = w2 + (size_t)l * WFF; pb.p[1] = pb.p[2] = pb.p[3] = pb.p[0];
      k_transpose<1><<<dim3(48, 12, 1), blk, 0, stream>>>(pb, w2T, DF, DM, 0);
    }
    const short* wTl  = wT  + (hoist ? (size_t)l * 4 * WQKVO : 0);
    const short* w1Tl = w1T + (hoist ? (size_t)l * WFF : 0);
    const short* w2Tl = w2T + (hoist ? (size_t)l * WFF : 0);

    if (l == 0)
      k_ln<<<dim3(MROWS), blk, 0, stream>>>(h, ln1g, ln1b, y);

    GemmPtrs gq;
    gq.bt[0] = wTl; gq.bt[1] = wTl + DD2; gq.bt[2] = wTl + 2 * DD2;
    gq.bias[0] = bq + l * DM; gq.bias[1] = bk + l * DM; gq.bias[2] = bv + l * DM;
    gq.out[0] = qb; gq.out[1] = kb2; gq.out[2] = vb2;
    gq.aoff[0] = gq.aoff[1] = gq.aoff[2] = 0;
    k_gemm128<4><<<dim3(17, 6, 3), blk, 0, stream>>>((const short*)y, gq, MROWS, DM, DM, DM, DM);

    k_attn<<<dim3(NB * NH), blk, 0, stream>>>(qb, kb2, vb2, gab, ctx);

    GemmPtrs go;  // Wo: full K, single z
    go.bt[0] = go.bt[1] = go.bt[2] = wTl + 3 * DD2;
    go.bias[0] = go.bias[1] = go.bias[2] = nullptr;
    go.out[0] = go.out[1] = go.out[2] = p0;
    go.aoff[0] = go.aoff[1] = go.aoff[2] = 0;
    k_gemm64<3><<<dim3(33, 6, 1), blk, 0, stream>>>((const short*)ctx, go, MROWS, DM, DM, DM, DM);

    k_ln_add1<<<dim3(MROWS), blk, 0, stream>>>(h, p0, bo + l * DM,
                                               ln2g + l * DM, ln2b + l * DM, y);

    GemmPtrs g1;
    g1.bt[0] = g1.bt[1] = g1.bt[2] = w1Tl;
    g1.bias[0] = g1.bias[1] = g1.bias[2] = b1 + l * DF;
    g1.out[0] = g1.out[1] = g1.out[2] = t1;
    g1.aoff[0] = g1.aoff[1] = g1.aoff[2] = 0;
    k_gemm128<2><<<dim3(17, 24, 1), blk, 0, stream>>>((const short*)y, g1, MROWS, DF, DM, DM, DM);

    GemmPtrs g2;  // FFN2: full K=3072, single z
    g2.bt[0] = g2.bt[1] = g2.bt[2] = w2Tl;
    g2.bias[0] = g2.bias[1] = g2.bias[2] = nullptr;
    g2.out[0] = g2.out[1] = g2.out[2] = p0;
    g2.aoff[0] = g2.aoff[1] = g2.aoff[2] = 0;
    k_gemm64<3><<<dim3(33, 6, 1), blk, 0, stream>>>((const short*)t1, g2, MROWS, DM, DF, DF, DF);

    if (l < NLAY - 1) {
      k_ln_add1<<<dim3(MROWS), blk, 0, stream>>>(h, p0, b2 + l * DM,
                                                 ln1g + (l + 1) * DM, ln1b + (l + 1) * DM, y);
    } else {
      k_final_add1<<<dim3(NB), blk, 0, stream>>>(h, p0, b2 + l * DM, fg, fb, ow, ob, out);
    }
  }
}

// Round 11
// 1613.715 us; speedup vs baseline: 1.2773x; 1.2773x over previous
//
#include <hip/hip_runtime.h>
#include <hip/hip_bf16.h>
#include <math.h>

typedef __hip_bfloat16 bf16;
typedef __attribute__((ext_vector_type(8))) short short8;
typedef __attribute__((ext_vector_type(4))) short short4v;
typedef __attribute__((ext_vector_type(4))) float f32x4;

constexpr int NB = 16;     // batch
constexpr int ND = 128;    // nodes N
constexpr int SQ = 129;    // S = N+1
constexpr int NH = 24;     // heads
constexpr int DM = 768;    // model dim
constexpr int DF = 3072;   // ffn dim
constexpr int NLAY = 12;
constexpr int MROWS = NB * SQ;  // 2064
constexpr int DD2C = DM * DM;

__device__ __forceinline__ short f2bs(float f) {
  bf16 h = __float2bfloat16(f);
  return *(short*)&h;
}

__device__ __forceinline__ void gload16(const void* g, void* lds) {
  __builtin_amdgcn_global_load_lds(
      (const __attribute__((address_space(1))) unsigned int*)g,
      (__attribute__((address_space(3))) unsigned int*)lds, 16, 0, 0);
}

// ---------------- node features ----------------
__global__ void k_nodefeat(const int* __restrict__ x, const int* __restrict__ ind,
                           const int* __restrict__ outd,
                           const float* __restrict__ atom, const float* __restrict__ ide,
                           const float* __restrict__ ode, const float* __restrict__ gtok,
                           float* __restrict__ h) {
  int bs = blockIdx.x;
  int b = bs / SQ, s = bs % SQ;
  int t = threadIdx.x;
  float* hrow = h + (size_t)bs * DM;
  if (s == 0) {
    for (int c = t; c < DM; c += 256) hrow[c] = gtok[c];
  } else {
    int n = s - 1;
    const int* xr = x + (b * ND + n) * 9;
    int a0 = xr[0], a1 = xr[1], a2 = xr[2], a3 = xr[3], a4 = xr[4];
    int a5 = xr[5], a6 = xr[6], a7 = xr[7], a8 = xr[8];
    int ii = ind[b * ND + n], oo = outd[b * ND + n];
    for (int c = t; c < DM; c += 256) {
      float acc = ide[(size_t)ii * DM + c] + ode[(size_t)oo * DM + c];
      acc += atom[(size_t)a0 * DM + c];
      acc += atom[(size_t)a1 * DM + c];
      acc += atom[(size_t)a2 * DM + c];
      acc += atom[(size_t)a3 * DM + c];
      acc += atom[(size_t)a4 * DM + c];
      acc += atom[(size_t)a5 * DM + c];
      acc += atom[(size_t)a6 * DM + c];
      acc += atom[(size_t)a7 * DM + c];
      acc += atom[(size_t)a8 * DM + c];
      hrow[c] = acc;
    }
  }
}

// ---------------- gab: virtual-token borders ----------------
__global__ void k_gab_border(const float* __restrict__ ab, const float* __restrict__ virt,
                             float* __restrict__ gab) {
  int b = blockIdx.x;
  const int tot = NH * SQ + NH * ND;
  for (int idx = threadIdx.x; idx < tot; idx += 256) {
    if (idx < NH * SQ) {
      int hh = idx / SQ, j = idx % SQ;
      float v = 2.f * ab[((size_t)b * SQ + 0) * SQ + j] + virt[hh];
      gab[(((size_t)b * NH + hh) * SQ + 0) * SQ + j] = v;
    } else {
      int r = idx - NH * SQ;
      int hh = r / ND, i = r % ND + 1;
      float v = 2.f * ab[((size_t)b * SQ + i) * SQ + 0] + virt[hh];
      gab[(((size_t)b * NH + hh) * SQ + i) * SQ + 0] = v;
    }
  }
}

// ---------------- gab: spatial + multihop edge bias (MFMA, coalesced writes) ----
__global__ __launch_bounds__(256) void k_gab_edge(
    const int* __restrict__ spos, const int* __restrict__ eidx,
    const float* __restrict__ eemb, const float* __restrict__ edemb,
    const float* __restrict__ semb, const float* __restrict__ ab,
    float* __restrict__ gab) {
  __shared__ int eidxs[960];
  __shared__ short ei2[64 * 136];
  __shared__ short edT[32 * 136];
  __shared__ float ot[24][65];
  __shared__ float rinvA[64], a2A[64];
  __shared__ int spA[64];
  int bi = blockIdx.x;
  int half = bi & 1;
  int i = (bi >> 1) & 127;
  int b = bi >> 8;
  int j0 = half * 64;
  int t = threadIdx.x;
  const size_t rowbase = ((size_t)(b * ND + i)) * ND + j0;

  const int* esrc = eidx + rowbase * 15;
  for (int idx = t; idx < 960; idx += 256) eidxs[idx] = esrc[idx];
  for (int u = t; u < 720; u += 256) {
    int dh = u / 6, kq = u % 6;
    f32x4 v = *(const f32x4*)&edemb[dh * 24 + kq * 4];
    edT[(kq * 4 + 0) * 136 + dh] = f2bs(v[0]);
    edT[(kq * 4 + 1) * 136 + dh] = f2bs(v[1]);
    edT[(kq * 4 + 2) * 136 + dh] = f2bs(v[2]);
    edT[(kq * 4 + 3) * 136 + dh] = f2bs(v[3]);
  }
  for (int u = t; u < 1472; u += 256) {
    int k, dh;
    if (u < 384) { k = u >> 4; dh = 120 + (u & 15); }
    else { int v = u - 384; k = 24 + v / 136; dh = v % 136; }
    edT[k * 136 + dh] = 0;
  }
  if (t < 64) {
    int j = t;
    int sp = spos[rowbase + j];
    int spc = (sp == 0) ? 1 : sp;
    spc = (spc > 1) ? spc - 1 : spc;
    if (spc > 5) spc = 5;
    spA[j] = sp;
    rinvA[j] = 1.f / (float)spc;
    a2A[j] = 2.f * ab[((size_t)b * SQ + (i + 1)) * SQ + (j0 + j + 1)];
  }
  __syncthreads();

  {
    int j = t & 63, d = t >> 6;
#pragma unroll
    for (int pass = 0; pass < 2; pass++) {
      if (pass == 1) {
        if (t >= 64) break;
        j = t; d = 4;
      }
      const int* ep = &eidxs[j * 15 + d * 3];
      const float* r0 = eemb + (size_t)ep[0] * NH;
      const float* r1 = eemb + (size_t)ep[1] * NH;
      const float* r2 = eemb + (size_t)ep[2] * NH;
#pragma unroll
      for (int hq = 0; hq < 6; hq++) {
        f32x4 s = (*(const f32x4*)&r0[hq * 4] + *(const f32x4*)&r1[hq * 4] +
                   *(const f32x4*)&r2[hq * 4]) * (1.f / 3.f);
        short4v o;
        o[0] = f2bs(s[0]); o[1] = f2bs(s[1]); o[2] = f2bs(s[2]); o[3] = f2bs(s[3]);
        *(short4v*)&ei2[j * 136 + d * 24 + hq * 4] = o;
      }
    }
  }
  for (int idx = t; idx < 64 * 8; idx += 256) {
    int j = idx >> 3;
    ei2[j * 136 + 120 + (idx & 7)] = 0;
  }
  __syncthreads();

  int lane = t & 63, w = t >> 6;
  int fr = lane & 15, q = lane >> 4, fo = q * 8;
  f32x4 acc0 = {0.f, 0.f, 0.f, 0.f}, acc1 = {0.f, 0.f, 0.f, 0.f};
#pragma unroll
  for (int kk = 0; kk < 4; kk++) {
    short8 af = *(const short8*)&ei2[(w * 16 + fr) * 136 + kk * 32 + fo];
    short8 b0 = *(const short8*)&edT[(fr) * 136 + kk * 32 + fo];
    short8 b1 = *(const short8*)&edT[(16 + fr) * 136 + kk * 32 + fo];
    acc0 = __builtin_amdgcn_mfma_f32_16x16x32_bf16(af, b0, acc0, 0, 0, 0);
    acc1 = __builtin_amdgcn_mfma_f32_16x16x32_bf16(af, b1, acc1, 0, 0, 0);
  }
#pragma unroll
  for (int e = 0; e < 4; e++) {
    int j = w * 16 + q * 4 + e;
    ot[fr][j] = acc0[e];
    if (fr < 8) ot[16 + fr][j] = acc1[e];
  }
  __syncthreads();
  size_t obase = (((size_t)b * NH) * SQ + (i + 1)) * SQ + (j0 + 1);
  for (int idx = t; idx < 24 * 64; idx += 256) {
    int k = idx >> 6, j = idx & 63;
    float v = a2A[j] + semb[spA[j] * NH + k] + ot[k][j] * rinvA[j];
    gab[obase + (size_t)k * SQ * SQ + j] = v;
  }
}

// ---------------- weight transpose+cast: f32 [R,C] -> bf16 [C,R] ----------------
struct Ptrs4 { const float* p[4]; };

template <int NW>
__global__ void k_transpose(Ptrs4 ps, short* __restrict__ dst, int R, int C,
                            size_t sstride) {
  __shared__ short tile[64][68];
  int z = blockIdx.z;
  const float* src = ps.p[z % NW] + (size_t)(z / NW) * sstride;
  short* d = dst + (size_t)z * (size_t)R * C;
  int r0 = blockIdx.x * 64, c0 = blockIdx.y * 64;
  int t = threadIdx.x;
  int tr = t >> 4, tc = (t & 15) * 4;
#pragma unroll
  for (int i = 0; i < 4; i++) {
    int r = tr + i * 16;
    f32x4 v = *(const f32x4*)(src + (size_t)(r0 + r) * C + c0 + tc);
    tile[r][tc + 0] = f2bs(v[0]);
    tile[r][tc + 1] = f2bs(v[1]);
    tile[r][tc + 2] = f2bs(v[2]);
    tile[r][tc + 3] = f2bs(v[3]);
  }
  __syncthreads();
#pragma unroll
  for (int i = 0; i < 4; i++) {
    int rr = tr + i * 16;
    short4v o;
    o[0] = tile[tc + 0][rr];
    o[1] = tile[tc + 1][rr];
    o[2] = tile[tc + 2][rr];
    o[3] = tile[tc + 3][rr];
    *(short4v*)(d + (size_t)(c0 + rr) * R + r0 + tc) = o;
  }
}

// ---------------- LayerNorm: fp32 row -> bf16 row ----------------
__global__ void k_ln(const float* __restrict__ h, const float* __restrict__ g,
                     const float* __restrict__ bb, bf16* __restrict__ y) {
  int r = blockIdx.x;
  int t = threadIdx.x, lane = t & 63, wid = t >> 6;
  __shared__ float red[8];
  const float* row = h + (size_t)r * DM;
  float v0 = row[t], v1 = row[t + 256], v2 = row[t + 512];
  float s = v0 + v1 + v2;
#pragma unroll
  for (int o = 32; o > 0; o >>= 1) s += __shfl_xor(s, o);
  if (lane == 0) red[wid] = s;
  __syncthreads();
  float mean = (red[0] + red[1] + red[2] + red[3]) * (1.f / 768.f);
  float d0 = v0 - mean, d1 = v1 - mean, d2 = v2 - mean;
  float q = d0 * d0 + d1 * d1 + d2 * d2;
#pragma unroll
  for (int o = 32; o > 0; o >>= 1) q += __shfl_xor(q, o);
  if (lane == 0) red[4 + wid] = q;
  __syncthreads();
  float var = (red[4] + red[5] + red[6] + red[7]) * (1.f / 768.f);
  float rstd = rsqrtf(var + 1e-5f);
  bf16* yr = y + (size_t)r * DM;
  yr[t] = __float2bfloat16(d0 * rstd * g[t] + bb[t]);
  yr[t + 256] = __float2bfloat16(d1 * rstd * g[t + 256] + bb[t + 256]);
  yr[t + 512] = __float2bfloat16(d2 * rstd * g[t + 512] + bb[t + 512]);
}

// ---------------- fused: h += p0+p1+cbias; y = LN(h) ----------------
__global__ void k_ln_add2(float* __restrict__ h, const float* __restrict__ p0,
                          const float* __restrict__ p1, const float* __restrict__ cb,
                          const float* __restrict__ g, const float* __restrict__ bb,
                          bf16* __restrict__ y) {
  int r = blockIdx.x;
  int t = threadIdx.x, lane = t & 63, wid = t >> 6;
  __shared__ float red[8];
  size_t base = (size_t)r * DM;
  float v0 = h[base + t] + p0[base + t] + p1[base + t] + cb[t];
  float v1 = h[base + t + 256] + p0[base + t + 256] + p1[base + t + 256] + cb[t + 256];
  float v2 = h[base + t + 512] + p0[base + t + 512] + p1[base + t + 512] + cb[t + 512];
  h[base + t] = v0;
  h[base + t + 256] = v1;
  h[base + t + 512] = v2;
  float s = v0 + v1 + v2;
#pragma unroll
  for (int o = 32; o > 0; o >>= 1) s += __shfl_xor(s, o);
  if (lane == 0) red[wid] = s;
  __syncthreads();
  float mean = (red[0] + red[1] + red[2] + red[3]) * (1.f / 768.f);
  float d0 = v0 - mean, d1 = v1 - mean, d2 = v2 - mean;
  float q = d0 * d0 + d1 * d1 + d2 * d2;
#pragma unroll
  for (int o = 32; o > 0; o >>= 1) q += __shfl_xor(q, o);
  if (lane == 0) red[4 + wid] = q;
  __syncthreads();
  float var = (red[4] + red[5] + red[6] + red[7]) * (1.f / 768.f);
  float rstd = rsqrtf(var + 1e-5f);
  bf16* yr = y + base;
  yr[t] = __float2bfloat16(d0 * rstd * g[t] + bb[t]);
  yr[t + 256] = __float2bfloat16(d1 * rstd * g[t + 256] + bb[t + 256]);
  yr[t + 512] = __float2bfloat16(d2 * rstd * g[t + 512] + bb[t + 512]);
}

// ---------------- GEMM common ----------------
// MODE 2: GELU->bf16; MODE 3: raw fp32
struct GemmPtrs {
  const short* bt[3];
  const float* bias[3];
  void* out[3];
  int aoff[3];
};

template <int MODE>
__device__ __forceinline__ void gemm_store(void* outp, size_t idx, float v) {
  if (MODE == 3) {
    ((float*)outp)[idx] = v;
  } else {
    float gg = 0.5f * v * (1.f + erff(v * 0.70710678118654752f));
    ((bf16*)outp)[idx] = __float2bfloat16(gg);
  }
}

// 128x128 block, 4 waves x 64x64, BK=64, single-buffer, swizzled. 32KB -> 3/CU.
template <int MODE>
__global__ __launch_bounds__(256, 3) void k_gemm128(const short* __restrict__ A, GemmPtrs p,
                                                    int M, int N, int K, int lda, int ldb) {
  __shared__ short At[128 * 64];
  __shared__ short Bt[128 * 64];
  int z = blockIdx.z;
  const short* BT = p.bt[z];
  const float* bias = p.bias[z];
  A += p.aoff[z];
  int m0 = blockIdx.x * 128, n0 = blockIdx.y * 128;
  int t = threadIdx.x, lane = t & 63, wid = t >> 6;
  int wr = wid >> 1, wc = wid & 1;
  f32x4 acc[4][4];
#pragma unroll
  for (int a = 0; a < 4; a++)
#pragma unroll
    for (int c = 0; c < 4; c++) acc[a][c] = (f32x4){0.f, 0.f, 0.f, 0.f};

  int lrow8 = lane >> 3;
  int lseg = (lane & 7) ^ lrow8;
  const short* gA[4];
  const short* gB[4];
#pragma unroll
  for (int i = 0; i < 4; i++) {
    int ar = m0 + wid * 32 + i * 8 + lrow8;
    if (ar >= M) ar = M - 1;
    gA[i] = A + (size_t)ar * lda + lseg * 8;
    int br = n0 + wid * 32 + i * 8 + lrow8;
    gB[i] = BT + (size_t)br * ldb + lseg * 8;
  }

  const int NIT = K >> 6;
  int fr = lane & 15, q = lane >> 4;
  for (int it = 0; it < NIT; ++it) {
    int k0 = it << 6;
#pragma unroll
    for (int i = 0; i < 4; i++) {
      gload16(gA[i] + k0, &At[(wid * 32 + i * 8) * 64]);
      gload16(gB[i] + k0, &Bt[(wid * 32 + i * 8) * 64]);
    }
    __syncthreads();
#pragma unroll
    for (int kk = 0; kk < 2; kk++) {
      int sg = ((q + kk * 4) ^ (fr & 7)) * 8;
      short8 af[4], bf[4];
#pragma unroll
      for (int mr = 0; mr < 4; mr++)
        af[mr] = *(const short8*)&At[(wr * 64 + mr * 16 + fr) * 64 + sg];
#pragma unroll
      for (int nc = 0; nc < 4; nc++)
        bf[nc] = *(const short8*)&Bt[(wc * 64 + nc * 16 + fr) * 64 + sg];
#pragma unroll
      for (int mr = 0; mr < 4; mr++)
#pragma unroll
        for (int nc = 0; nc < 4; nc++)
          acc[mr][nc] = __builtin_amdgcn_mfma_f32_16x16x32_bf16(af[mr], bf[nc], acc[mr][nc], 0, 0, 0);
    }
    __syncthreads();
  }

  int rsub = q * 4;
#pragma unroll
  for (int nc = 0; nc < 4; nc++) {
    int col = n0 + wc * 64 + nc * 16 + fr;
    float bv = (MODE == 3) ? 0.f : bias[col];
#pragma unroll
    for (int mr = 0; mr < 4; mr++) {
#pragma unroll
      for (int e = 0; e < 4; e++) {
        int r = m0 + wr * 64 + mr * 16 + rsub + e;
        if (r < M) gemm_store<MODE>(p.out[z], (size_t)r * N + col, acc[mr][nc][e] + bv);
      }
    }
  }
}

// 64x128 block, 4 waves x 32x64, BK=64, single-buffer, swizzled. 24KB -> 4/CU.
template <int MODE>
__global__ __launch_bounds__(256, 4) void k_gemm64(const short* __restrict__ A, GemmPtrs p,
                                                   int M, int N, int K, int lda, int ldb) {
  __shared__ short At[64 * 64];
  __shared__ short Bt[128 * 64];
  int z = blockIdx.z;
  const short* BT = p.bt[z];
  const float* bias = p.bias[z];
  A += p.aoff[z];
  int m0 = blockIdx.x * 64, n0 = blockIdx.y * 128;
  int t = threadIdx.x, lane = t & 63, wid = t >> 6;
  int wr = wid >> 1, wc = wid & 1;
  f32x4 acc[2][4];
#pragma unroll
  for (int a = 0; a < 2; a++)
#pragma unroll
    for (int c = 0; c < 4; c++) acc[a][c] = (f32x4){0.f, 0.f, 0.f, 0.f};

  int lrow8 = lane >> 3;
  int lseg = (lane & 7) ^ lrow8;
  const short* gA[2];
  const short* gB[4];
#pragma unroll
  for (int i = 0; i < 2; i++) {
    int ar = m0 + wid * 16 + i * 8 + lrow8;
    if (ar >= M) ar = M - 1;
    gA[i] = A + (size_t)ar * lda + lseg * 8;
  }
#pragma unroll
  for (int i = 0; i < 4; i++) {
    int br = n0 + wid * 32 + i * 8 + lrow8;
    gB[i] = BT + (size_t)br * ldb + lseg * 8;
  }

  const int NIT = K >> 6;
  int fr = lane & 15, q = lane >> 4;
  for (int it = 0; it < NIT; ++it) {
    int k0 = it << 6;
#pragma unroll
    for (int i = 0; i < 2; i++) gload16(gA[i] + k0, &At[(wid * 16 + i * 8) * 64]);
#pragma unroll
    for (int i = 0; i < 4; i++) gload16(gB[i] + k0, &Bt[(wid * 32 + i * 8) * 64]);
    __syncthreads();
#pragma unroll
    for (int kk = 0; kk < 2; kk++) {
      int sg = ((q + kk * 4) ^ (fr & 7)) * 8;
      short8 af[2], bf[4];
#pragma unroll
      for (int mr = 0; mr < 2; mr++)
        af[mr] = *(const short8*)&At[(wr * 32 + mr * 16 + fr) * 64 + sg];
#pragma unroll
      for (int nc = 0; nc < 4; nc++)
        bf[nc] = *(const short8*)&Bt[(wc * 64 + nc * 16 + fr) * 64 + sg];
#pragma unroll
      for (int mr = 0; mr < 2; mr++)
#pragma unroll
        for (int nc = 0; nc < 4; nc++)
          acc[mr][nc] = __builtin_amdgcn_mfma_f32_16x16x32_bf16(af[mr], bf[nc], acc[mr][nc], 0, 0, 0);
    }
    __syncthreads();
  }

  int rsub = q * 4;
#pragma unroll
  for (int nc = 0; nc < 4; nc++) {
    int col = n0 + wc * 64 + nc * 16 + fr;
    float bv = (MODE == 3) ? 0.f : bias[col];
#pragma unroll
    for (int mr = 0; mr < 2; mr++) {
#pragma unroll
      for (int e = 0; e < 4; e++) {
        int r = m0 + wr * 32 + mr * 16 + rsub + e;
        if (r < M) gemm_store<MODE>(p.out[z], (size_t)r * N + col, acc[mr][nc][e] + bv);
      }
    }
  }
}

// ---------------- fused QKV projection + MFMA flash attention ----------------
// one block per (b,h). Phase 1: Q/K/V = y @ W{q,k,v}[:, h*32:+32] + bias via MFMA
// into LDS. Phase 2: QK^T -> softmax -> PV (round-8-verified code).
__global__ __launch_bounds__(256) void k_fattn(const bf16* __restrict__ y,
                                               const short* __restrict__ wTl,
                                               const float* __restrict__ bq,
                                               const float* __restrict__ bk,
                                               const float* __restrict__ bv,
                                               const float* __restrict__ gab,
                                               bf16* __restrict__ ctx) {
  __shared__ short Ql[144 * 40];
  __shared__ short Kl[144 * 40];
  __shared__ short Vt[32 * 168];
  __shared__ short U[7680];      // phase1: Ay[144*32] + Bw[3*32*32]; phase2: Pc[144*40]
  __shared__ float bqa[32], bka[32], bva[32];
  short* Ay = U;
  short* Bw = U + 144 * 32;
  short* Pc = U;
  int bh = blockIdx.x;
  int b = bh / NH, hh = bh % NH;
  int t = threadIdx.x;
  int lane = t & 63, w = t >> 6;

  // Vt tail zero (kk in [129,168)); biases to LDS
  for (int idx = t; idx < 32 * 39; idx += 256) {
    int d = idx / 39, kk = 129 + (idx % 39);
    Vt[d * 168 + kk] = 0;
  }
  if (t < 32) {
    bqa[t] = bq[hh * 32 + t];
    bka[t] = bk[hh * 32 + t];
    bva[t] = bv[hh * 32 + t];
  }

  // ---- phase 1: QKV via MFMA over 24 K-tiles of 32 ----
  f32x4 acc[3][3][2];
#pragma unroll
  for (int i = 0; i < 3; i++)
#pragma unroll
    for (int m = 0; m < 3; m++)
#pragma unroll
      for (int nt = 0; nt < 2; nt++) acc[i][m][nt] = (f32x4){0.f, 0.f, 0.f, 0.f};

  int lr = lane >> 2;                      // local row in 16-row group
  int lsg = (lane & 3) ^ (lr & 3);         // pre-swizzled global seg
  int fr = lane & 15, q = lane >> 4;
  const short* ybase = (const short*)y + (size_t)(b * SQ) * DM;

  for (int kt = 0; kt < 24; ++kt) {
    __syncthreads();
    // stage A: y rows (9 x 16-row groups; rows >=129 garbage, contained)
    for (int i = w; i < 9; i += 4) {
      int grow_ = i * 16 + lr;
      gload16(ybase + (size_t)grow_ * DM + kt * 32 + lsg * 8, &Ay[(i * 16) * 32]);
    }
    // stage B: wT rows hh*32.. for q,k,v (6 x 16-row groups)
    for (int i = w; i < 6; i += 4) {
      int m = i >> 1, half = i & 1;
      int nrow = hh * 32 + half * 16 + lr;
      gload16(wTl + (size_t)m * DD2C + (size_t)nrow * DM + kt * 32 + lsg * 8,
              &Bw[(m * 32 + half * 16) * 32]);
    }
    __syncthreads();
    int sg = (q ^ (fr & 3)) * 8;
#pragma unroll
    for (int i = 0; i < 3; i++) {
      int mt = w + 4 * i;
      if (mt > 8) break;
      short8 af = *(const short8*)&Ay[(mt * 16 + fr) * 32 + sg];
#pragma unroll
      for (int m = 0; m < 3; m++)
#pragma unroll
        for (int nt = 0; nt < 2; nt++) {
          short8 bf = *(const short8*)&Bw[(m * 32 + nt * 16 + fr) * 32 + sg];
          acc[i][m][nt] = __builtin_amdgcn_mfma_f32_16x16x32_bf16(af, bf, acc[i][m][nt], 0, 0, 0);
        }
    }
  }
  __syncthreads();
  // scatter Q,K,V (+bias) into Ql/Kl/Vt (bf16)
#pragma unroll
  for (int i = 0; i < 3; i++) {
    int mt = w + 4 * i;
    if (mt > 8) break;
#pragma unroll
    for (int nt = 0; nt < 2; nt++) {
      int coll = nt * 16 + fr;
      float bqv = bqa[coll], bkv = bka[coll], bvv = bva[coll];
#pragma unroll
      for (int e = 0; e < 4; e++) {
        int row = mt * 16 + q * 4 + e;
        Ql[row * 40 + coll] = f2bs(acc[i][0][nt][e] + bqv);
        Kl[row * 40 + coll] = f2bs(acc[i][1][nt][e] + bkv);
        if (row < 129) Vt[coll * 168 + row] = f2bs(acc[i][2][nt][e] + bvv);
      }
    }
  }
  __syncthreads();

  // ---- phase 2: QK^T -> softmax -> PV (verified) ----
  int c16 = lane & 15, q4 = lane >> 4;
  const float scale = 0.17677669529663689f;  // 1/sqrt(32)
  const float* gabp = gab + (((size_t)(b * NH + hh)) * SQ) * SQ;

  for (int mt = w; mt < 9; mt += 4) {
    f32x4 sc[9];
    short8 aq = *(const short8*)&Ql[(mt * 16 + c16) * 40 + q4 * 8];
#pragma unroll
    for (int nt = 0; nt < 9; nt++) {
      short8 bk8 = *(const short8*)&Kl[(nt * 16 + c16) * 40 + q4 * 8];
      f32x4 zz = {0.f, 0.f, 0.f, 0.f};
      sc[nt] = __builtin_amdgcn_mfma_f32_16x16x32_bf16(aq, bk8, zz, 0, 0, 0);
    }
#pragma unroll
    for (int e = 0; e < 4; e++) {
      int row = mt * 16 + q4 * 4 + e;
      int rr = row < 129 ? row : 128;
      const float* grow = gabp + (size_t)rr * SQ;
      float mloc = -1e30f;
#pragma unroll
      for (int nt = 0; nt < 9; nt++) {
        int col = nt * 16 + c16;
        float s = (col < 129) ? (sc[nt][e] * scale + grow[col]) : -1e30f;
        sc[nt][e] = s;
        mloc = fmaxf(mloc, s);
      }
#pragma unroll
      for (int o = 1; o < 16; o <<= 1) mloc = fmaxf(mloc, __shfl_xor(mloc, o));
      float sum = 0.f;
#pragma unroll
      for (int nt = 0; nt < 9; nt++) {
        float pp = __expf(sc[nt][e] - mloc);
        sc[nt][e] = pp;
        sum += pp;
      }
#pragma unroll
      for (int o = 1; o < 16; o <<= 1) sum += __shfl_xor(sum, o);
      float inv = 1.f / sum;
#pragma unroll
      for (int nt = 0; nt < 9; nt++) sc[nt][e] *= inv;
    }
    f32x4 oacc0 = {0.f, 0.f, 0.f, 0.f}, oacc1 = {0.f, 0.f, 0.f, 0.f};
#pragma unroll
    for (int c = 0; c < 5; c++) {
#pragma unroll
      for (int u = 0; u < 2; u++) {
        int nt = c * 2 + u;
        if (nt < 9) {
#pragma unroll
          for (int e = 0; e < 4; e++)
            Pc[(mt * 16 + q4 * 4 + e) * 40 + u * 16 + c16] = f2bs(sc[nt][e]);
        } else {
#pragma unroll
          for (int e = 0; e < 4; e++)
            Pc[(mt * 16 + q4 * 4 + e) * 40 + u * 16 + c16] = 0;
        }
      }
      asm volatile("s_waitcnt lgkmcnt(0)" ::: "memory");
      __builtin_amdgcn_sched_barrier(0);
      short8 ap = *(const short8*)&Pc[(mt * 16 + c16) * 40 + q4 * 8];
      short8 bv0 = *(const short8*)&Vt[(c16) * 168 + c * 32 + q4 * 8];
      short8 bv1 = *(const short8*)&Vt[(16 + c16) * 168 + c * 32 + q4 * 8];
      oacc0 = __builtin_amdgcn_mfma_f32_16x16x32_bf16(ap, bv0, oacc0, 0, 0, 0);
      oacc1 = __builtin_amdgcn_mfma_f32_16x16x32_bf16(ap, bv1, oacc1, 0, 0, 0);
    }
#pragma unroll
    for (int e = 0; e < 4; e++) {
      int row = mt * 16 + q4 * 4 + e;
      if (row < 129) {
        size_t obase = ((size_t)(b * SQ + row)) * DM + hh * 32;
        ctx[obase + c16] = __float2bfloat16(oacc0[e]);
        ctx[obase + 16 + c16] = __float2bfloat16(oacc1[e]);
      }
    }
  }
}

// ---------------- final: h_row0 + p0 + p1 + cbias -> LN -> project ----------------
__global__ void k_final_add2(const float* __restrict__ h, const float* __restrict__ p0,
                             const float* __restrict__ p1, const float* __restrict__ cb,
                             const float* __restrict__ g, const float* __restrict__ bb,
                             const float* __restrict__ ow, const float* __restrict__ ob,
                             float* __restrict__ out) {
  int b = blockIdx.x;
  int t = threadIdx.x, lane = t & 63, wid = t >> 6;
  __shared__ float red[8];
  __shared__ float yn[768];
  size_t base = (size_t)(b * SQ) * DM;
  float v0 = h[base + t] + p0[base + t] + p1[base + t] + cb[t];
  float v1 = h[base + t + 256] + p0[base + t + 256] + p1[base + t + 256] + cb[t + 256];
  float v2 = h[base + t + 512] + p0[base + t + 512] + p1[base + t + 512] + cb[t + 512];
  float s = v0 + v1 + v2;
#pragma unroll
  for (int o = 32; o > 0; o >>= 1) s += __shfl_xor(s, o);
  if (lane == 0) red[wid] = s;
  __syncthreads();
  float mean = (red[0] + red[1] + red[2] + red[3]) * (1.f / 768.f);
  float d0 = v0 - mean, d1 = v1 - mean, d2 = v2 - mean;
  float q = d0 * d0 + d1 * d1 + d2 * d2;
#pragma unroll
  for (int o = 32; o > 0; o >>= 1) q += __shfl_xor(q, o);
  if (lane == 0) red[4 + wid] = q;
  __syncthreads();
  float var = (red[4] + red[5] + red[6] + red[7]) * (1.f / 768.f);
  float rstd = rsqrtf(var + 1e-5f);
  yn[t] = d0 * rstd * g[t] + bb[t];
  yn[t + 256] = d1 * rstd * g[t + 256] + bb[t + 256];
  yn[t + 512] = d2 * rstd * g[t + 512] + bb[t + 512];
  __syncthreads();
  if (t < 128) {
    float acc = ob[t];
    for (int d = 0; d < 768; d++) acc += yn[d] * ow[d * 128 + t];
    out[b * 128 + t] = acc;
  }
}

extern "C" void kernel_launch(void* const* d_in, const int* in_sizes, int n_in,
                              void* d_out, int out_size, void* d_ws, size_t ws_size,
                              hipStream_t stream) {
  (void)in_sizes; (void)n_in; (void)out_size;
  const int* x     = (const int*)d_in[0];
  const int* ind   = (const int*)d_in[1];
  const int* outd  = (const int*)d_in[2];
  const int* spos  = (const int*)d_in[3];
  const int* eidx  = (const int*)d_in[4];
  const float* ab   = (const float*)d_in[5];
  const float* atom = (const float*)d_in[6];
  const float* ide  = (const float*)d_in[7];
  const float* ode  = (const float*)d_in[8];
  const float* gtok = (const float*)d_in[9];
  const float* eemb = (const float*)d_in[10];
  const float* edemb= (const float*)d_in[11];
  const float* semb = (const float*)d_in[12];
  const float* virt = (const float*)d_in[13];
  const float* ln1g = (const float*)d_in[14];
  const float* ln1b = (const float*)d_in[15];
  const float* wq  = (const float*)d_in[16];
  const float* bq   = (const float*)d_in[17];
  const float* wk  = (const float*)d_in[18];
  const float* bk   = (const float*)d_in[19];
  const float* wv  = (const float*)d_in[20];
  const float* bv   = (const float*)d_in[21];
  const float* wo  = (const float*)d_in[22];
  const float* bo   = (const float*)d_in[23];
  const float* ln2g = (const float*)d_in[24];
  const float* ln2b = (const float*)d_in[25];
  const float* w1  = (const float*)d_in[26];
  const float* b1   = (const float*)d_in[27];
  const float* w2  = (const float*)d_in[28];
  const float* b2   = (const float*)d_in[29];
  const float* fg   = (const float*)d_in[30];
  const float* fb   = (const float*)d_in[31];
  const float* ow   = (const float*)d_in[32];
  const float* ob   = (const float*)d_in[33];
  float* out = (float*)d_out;

  const int DD2 = DM * DM;
  const size_t WQKVO = (size_t)DD2;
  const size_t WFF = (size_t)DM * DF;

  char* ws = (char*)d_ws;
  size_t off = 0;
  auto alloc = [&](size_t bytes) -> void* {
    void* p = ws + off;
    off += (bytes + 255) & ~(size_t)255;
    return p;
  };
  float* gab = (float*)alloc((size_t)NB * NH * SQ * SQ * 4);
  float* h   = (float*)alloc((size_t)MROWS * DM * 4);
  bf16* y    = (bf16*)alloc((size_t)MROWS * DM * 2);
  bf16* ctx  = (bf16*)alloc((size_t)MROWS * DM * 2);
  bf16* t1   = (bf16*)alloc((size_t)MROWS * DF * 2);
  float* p0  = (float*)alloc((size_t)MROWS * DM * 4);
  float* p1  = (float*)alloc((size_t)MROWS * DM * 4);

  size_t need_hoist = off + ((size_t)NLAY * 4 * WQKVO + 2 * (size_t)NLAY * WFF) * 2 + (1 << 20);
  bool hoist = ws_size >= need_hoist;
  short* wT  = (short*)alloc((hoist ? (size_t)NLAY * 4 * WQKVO : 4 * WQKVO) * 2);
  short* w1T = (short*)alloc((hoist ? (size_t)NLAY * WFF : WFF) * 2);
  short* w2T = (short*)alloc((hoist ? (size_t)NLAY * WFF : WFF) * 2);

  dim3 blk(256);
  k_nodefeat<<<dim3(NB * SQ), blk, 0, stream>>>(x, ind, outd, atom, ide, ode, gtok, h);
  k_gab_border<<<dim3(NB), blk, 0, stream>>>(ab, virt, gab);
  k_gab_edge<<<dim3(NB * ND * 2), blk, 0, stream>>>(spos, eidx, eemb, edemb, semb, ab, gab);

  if (hoist) {
    Ptrs4 pq; pq.p[0] = wq; pq.p[1] = wk; pq.p[2] = wv; pq.p[3] = wo;
    k_transpose<4><<<dim3(12, 12, 48), blk, 0, stream>>>(pq, wT, DM, DM, WQKVO);
    Ptrs4 pa; pa.p[0] = w1; pa.p[1] = pa.p[2] = pa.p[3] = w1;
    k_transpose<1><<<dim3(12, 48, 12), blk, 0, stream>>>(pa, w1T, DM, DF, WFF);
    Ptrs4 pb; pb.p[0] = w2; pb.p[1] = pb.p[2] = pb.p[3] = w2;
    k_transpose<1><<<dim3(48, 12, 12), blk, 0, stream>>>(pb, w2T, DF, DM, WFF);
  }

  for (int l = 0; l < NLAY; l++) {
    if (!hoist) {
      Ptrs4 pq;
      pq.p[0] = wq + (size_t)l * DD2; pq.p[1] = wk + (size_t)l * DD2;
      pq.p[2] = wv + (size_t)l * DD2; pq.p[3] = wo + (size_t)l * DD2;
      k_transpose<4><<<dim3(12, 12, 4), blk, 0, stream>>>(pq, wT, DM, DM, 0);
      Ptrs4 pa; pa.p[0] = w1 + (size_t)l * WFF; pa.p[1] = pa.p[2] = pa.p[3] = pa.p[0];
      k_transpose<1><<<dim3(12, 48, 1), blk, 0, stream>>>(pa, w1T, DM, DF, 0);
      Ptrs4 pb; pb.p[0] = w2 + (size_t)l * WFF; pb.p[1] = pb.p[2] = pb.p[3] = pb.p[0];
      k_transpose<1><<<dim3(48, 12, 1), blk, 0, stream>>>(pb, w2T, DF, DM, 0);
    }
    const short* wTl  = wT  + (hoist ? (size_t)l * 4 * WQKVO : 0);
    const short* w1Tl = w1T + (hoist ? (size_t)l * WFF : 0);
    const short* w2Tl = w2T + (hoist ? (size_t)l * WFF : 0);

    if (l == 0)
      k_ln<<<dim3(MROWS), blk, 0, stream>>>(h, ln1g, ln1b, y);

    // fused QKV + attention
    k_fattn<<<dim3(NB * NH), blk, 0, stream>>>(y, wTl, bq + l * DM, bk + l * DM,
                                               bv + l * DM, gab, ctx);

    GemmPtrs go;  // Wo split-K: K=768 -> 2 x 384
    go.bt[0] = wTl + 3 * DD2; go.bt[1] = wTl + 3 * DD2 + 384;
    go.bias[0] = go.bias[1] = nullptr;
    go.out[0] = p0; go.out[1] = p1;
    go.aoff[0] = 0; go.aoff[1] = 384;
    go.bt[2] = go.bt[0]; go.out[2] = p0; go.aoff[2] = 0; go.bias[2] = nullptr;
    k_gemm64<3><<<dim3(33, 6, 2), blk, 0, stream>>>((const short*)ctx, go, MROWS, DM, 384, DM, DM);

    k_ln_add2<<<dim3(MROWS), blk, 0, stream>>>(h, p0, p1, bo + l * DM,
                                               ln2g + l * DM, ln2b + l * DM, y);

    GemmPtrs g1;
    g1.bt[0] = g1.bt[1] = g1.bt[2] = w1Tl;
    g1.bias[0] = g1.bias[1] = g1.bias[2] = b1 + l * DF;
    g1.out[0] = g1.out[1] = g1.out[2] = t1;
    g1.aoff[0] = g1.aoff[1] = g1.aoff[2] = 0;
    k_gemm128<2><<<dim3(17, 24, 1), blk, 0, stream>>>((const short*)y, g1, MROWS, DF, DM, DM, DM);

    GemmPtrs g2;  // FFN2 split-K: K=3072 -> 2 x 1536
    g2.bt[0] = w2Tl; g2.bt[1] = w2Tl + 1536;
    g2.bias[0] = g2.bias[1] = nullptr;
    g2.out[0] = p0; g2.out[1] = p1;
    g2.aoff[0] = 0; g2.aoff[1] = 1536;
    g2.bt[2] = g2.bt[0]; g2.out[2] = p0; g2.aoff[2] = 0; g2.bias[2] = nullptr;
    k_gemm64<3><<<dim3(33, 6, 2), blk, 0, stream>>>((const short*)t1, g2, MROWS, DM, 1536, DF, DF);

    if (l < NLAY - 1) {
      k_ln_add2<<<dim3(MROWS), blk, 0, stream>>>(h, p0, p1, b2 + l * DM,
                                                 ln1g + (l + 1) * DM, ln1b + (l + 1) * DM, y);
    } else {
      k_final_add2<<<dim3(NB), blk, 0, stream>>>(h, p0, p1, b2 + l * DM, fg, fb, ow, ob, out);
    }
  }
}

// Round 12
// 1547.573 us; speedup vs baseline: 1.3318x; 1.0427x over previous
//
#include <hip/hip_runtime.h>
#include <hip/hip_bf16.h>
#include <math.h>

typedef __hip_bfloat16 bf16;
typedef __attribute__((ext_vector_type(8))) short short8;
typedef __attribute__((ext_vector_type(4))) short short4v;
typedef __attribute__((ext_vector_type(4))) float f32x4;

constexpr int NB = 16;     // batch
constexpr int ND = 128;    // nodes N
constexpr int SQ = 129;    // S = N+1
constexpr int NH = 24;     // heads
constexpr int DM = 768;    // model dim
constexpr int DF = 3072;   // ffn dim
constexpr int NLAY = 12;
constexpr int MROWS = NB * SQ;  // 2064
constexpr int DD2C = DM * DM;

__device__ __forceinline__ short f2bs(float f) {
  bf16 h = __float2bfloat16(f);
  return *(short*)&h;
}

__device__ __forceinline__ void gload16(const void* g, void* lds) {
  __builtin_amdgcn_global_load_lds(
      (const __attribute__((address_space(1))) unsigned int*)g,
      (__attribute__((address_space(3))) unsigned int*)lds, 16, 0, 0);
}

// ---------------- node features + first LN + gab borders ----------------
__global__ void k_nodefeat_ln(const int* __restrict__ x, const int* __restrict__ ind,
                              const int* __restrict__ outd,
                              const float* __restrict__ atom, const float* __restrict__ ide,
                              const float* __restrict__ ode, const float* __restrict__ gtok,
                              const float* __restrict__ ab, const float* __restrict__ virt,
                              const float* __restrict__ g, const float* __restrict__ bb,
                              float* __restrict__ h, bf16* __restrict__ y,
                              float* __restrict__ gab) {
  int bs = blockIdx.x;
  int b = bs / SQ, s = bs % SQ;
  int t = threadIdx.x, lane = t & 63, wid = t >> 6;
  __shared__ float red[8];
  float vv[3];
  if (s == 0) {
    vv[0] = gtok[t]; vv[1] = gtok[t + 256]; vv[2] = gtok[t + 512];
  } else {
    int n = s - 1;
    const int* xr = x + (b * ND + n) * 9;
    int a0 = xr[0], a1 = xr[1], a2 = xr[2], a3 = xr[3], a4 = xr[4];
    int a5 = xr[5], a6 = xr[6], a7 = xr[7], a8 = xr[8];
    int ii = ind[b * ND + n], oo = outd[b * ND + n];
#pragma unroll
    for (int u = 0; u < 3; u++) {
      int c = t + u * 256;
      float acc = ide[(size_t)ii * DM + c] + ode[(size_t)oo * DM + c];
      acc += atom[(size_t)a0 * DM + c];
      acc += atom[(size_t)a1 * DM + c];
      acc += atom[(size_t)a2 * DM + c];
      acc += atom[(size_t)a3 * DM + c];
      acc += atom[(size_t)a4 * DM + c];
      acc += atom[(size_t)a5 * DM + c];
      acc += atom[(size_t)a6 * DM + c];
      acc += atom[(size_t)a7 * DM + c];
      acc += atom[(size_t)a8 * DM + c];
      vv[u] = acc;
    }
  }
  float* hrow = h + (size_t)bs * DM;
  hrow[t] = vv[0]; hrow[t + 256] = vv[1]; hrow[t + 512] = vv[2];
  // LN
  float sum = vv[0] + vv[1] + vv[2];
#pragma unroll
  for (int o = 32; o > 0; o >>= 1) sum += __shfl_xor(sum, o);
  if (lane == 0) red[wid] = sum;
  __syncthreads();
  float mean = (red[0] + red[1] + red[2] + red[3]) * (1.f / 768.f);
  float d0 = vv[0] - mean, d1 = vv[1] - mean, d2 = vv[2] - mean;
  float q = d0 * d0 + d1 * d1 + d2 * d2;
#pragma unroll
  for (int o = 32; o > 0; o >>= 1) q += __shfl_xor(q, o);
  if (lane == 0) red[4 + wid] = q;
  __syncthreads();
  float var = (red[4] + red[5] + red[6] + red[7]) * (1.f / 768.f);
  float rstd = rsqrtf(var + 1e-5f);
  bf16* yr = y + (size_t)bs * DM;
  yr[t] = __float2bfloat16(d0 * rstd * g[t] + bb[t]);
  yr[t + 256] = __float2bfloat16(d1 * rstd * g[t + 256] + bb[t + 256]);
  yr[t + 512] = __float2bfloat16(d2 * rstd * g[t + 512] + bb[t + 512]);
  // gab virtual-token borders (blocks 0..15 handle batch b=bs)
  if (bs < NB) {
    int bb2 = bs;
    const int tot = NH * SQ + NH * ND;
    for (int idx = t; idx < tot; idx += 256) {
      if (idx < NH * SQ) {
        int hh = idx / SQ, j = idx % SQ;
        float v = 2.f * ab[((size_t)bb2 * SQ + 0) * SQ + j] + virt[hh];
        gab[(((size_t)bb2 * NH + hh) * SQ + 0) * SQ + j] = v;
      } else {
        int r = idx - NH * SQ;
        int hh = r / ND, i = r % ND + 1;
        float v = 2.f * ab[((size_t)bb2 * SQ + i) * SQ + 0] + virt[hh];
        gab[(((size_t)bb2 * NH + hh) * SQ + i) * SQ + 0] = v;
      }
    }
  }
}

// ---------------- gab: spatial + multihop edge bias (MFMA, coalesced writes) ----
__global__ __launch_bounds__(256) void k_gab_edge(
    const int* __restrict__ spos, const int* __restrict__ eidx,
    const float* __restrict__ eemb, const float* __restrict__ edemb,
    const float* __restrict__ semb, const float* __restrict__ ab,
    float* __restrict__ gab) {
  __shared__ int eidxs[960];
  __shared__ short ei2[64 * 136];
  __shared__ short edT[32 * 136];
  __shared__ float ot[24][65];
  __shared__ float rinvA[64], a2A[64];
  __shared__ int spA[64];
  int bi = blockIdx.x;
  int half = bi & 1;
  int i = (bi >> 1) & 127;
  int b = bi >> 8;
  int j0 = half * 64;
  int t = threadIdx.x;
  const size_t rowbase = ((size_t)(b * ND + i)) * ND + j0;

  const int* esrc = eidx + rowbase * 15;
  for (int idx = t; idx < 960; idx += 256) eidxs[idx] = esrc[idx];
  for (int u = t; u < 720; u += 256) {
    int dh = u / 6, kq = u % 6;
    f32x4 v = *(const f32x4*)&edemb[dh * 24 + kq * 4];
    edT[(kq * 4 + 0) * 136 + dh] = f2bs(v[0]);
    edT[(kq * 4 + 1) * 136 + dh] = f2bs(v[1]);
    edT[(kq * 4 + 2) * 136 + dh] = f2bs(v[2]);
    edT[(kq * 4 + 3) * 136 + dh] = f2bs(v[3]);
  }
  for (int u = t; u < 1472; u += 256) {
    int k, dh;
    if (u < 384) { k = u >> 4; dh = 120 + (u & 15); }
    else { int v = u - 384; k = 24 + v / 136; dh = v % 136; }
    edT[k * 136 + dh] = 0;
  }
  if (t < 64) {
    int j = t;
    int sp = spos[rowbase + j];
    int spc = (sp == 0) ? 1 : sp;
    spc = (spc > 1) ? spc - 1 : spc;
    if (spc > 5) spc = 5;
    spA[j] = sp;
    rinvA[j] = 1.f / (float)spc;
    a2A[j] = 2.f * ab[((size_t)b * SQ + (i + 1)) * SQ + (j0 + j + 1)];
  }
  __syncthreads();

  {
    int j = t & 63, d = t >> 6;
#pragma unroll
    for (int pass = 0; pass < 2; pass++) {
      if (pass == 1) {
        if (t >= 64) break;
        j = t; d = 4;
      }
      const int* ep = &eidxs[j * 15 + d * 3];
      const float* r0 = eemb + (size_t)ep[0] * NH;
      const float* r1 = eemb + (size_t)ep[1] * NH;
      const float* r2 = eemb + (size_t)ep[2] * NH;
#pragma unroll
      for (int hq = 0; hq < 6; hq++) {
        f32x4 s = (*(const f32x4*)&r0[hq * 4] + *(const f32x4*)&r1[hq * 4] +
                   *(const f32x4*)&r2[hq * 4]) * (1.f / 3.f);
        short4v o;
        o[0] = f2bs(s[0]); o[1] = f2bs(s[1]); o[2] = f2bs(s[2]); o[3] = f2bs(s[3]);
        *(short4v*)&ei2[j * 136 + d * 24 + hq * 4] = o;
      }
    }
  }
  for (int idx = t; idx < 64 * 8; idx += 256) {
    int j = idx >> 3;
    ei2[j * 136 + 120 + (idx & 7)] = 0;
  }
  __syncthreads();

  int lane = t & 63, w = t >> 6;
  int fr = lane & 15, q = lane >> 4, fo = q * 8;
  f32x4 acc0 = {0.f, 0.f, 0.f, 0.f}, acc1 = {0.f, 0.f, 0.f, 0.f};
#pragma unroll
  for (int kk = 0; kk < 4; kk++) {
    short8 af = *(const short8*)&ei2[(w * 16 + fr) * 136 + kk * 32 + fo];
    short8 b0 = *(const short8*)&edT[(fr) * 136 + kk * 32 + fo];
    short8 b1 = *(const short8*)&edT[(16 + fr) * 136 + kk * 32 + fo];
    acc0 = __builtin_amdgcn_mfma_f32_16x16x32_bf16(af, b0, acc0, 0, 0, 0);
    acc1 = __builtin_amdgcn_mfma_f32_16x16x32_bf16(af, b1, acc1, 0, 0, 0);
  }
#pragma unroll
  for (int e = 0; e < 4; e++) {
    int j = w * 16 + q * 4 + e;
    ot[fr][j] = acc0[e];
    if (fr < 8) ot[16 + fr][j] = acc1[e];
  }
  __syncthreads();
  size_t obase = (((size_t)b * NH) * SQ + (i + 1)) * SQ + (j0 + 1);
  for (int idx = t; idx < 24 * 64; idx += 256) {
    int k = idx >> 6, j = idx & 63;
    float v = a2A[j] + semb[spA[j] * NH + k] + ot[k][j] * rinvA[j];
    gab[obase + (size_t)k * SQ * SQ + j] = v;
  }
}

// ---------------- all weight transposes in one dispatch ----------------
struct TAll {
  const float* wq; const float* wk; const float* wv; const float* wo;
  const float* w1; const float* w2;
  short* wT; short* w1T; short* w2T;
};

__global__ void k_transpose_all(TAll p) {
  __shared__ short tile[64][68];
  int id = blockIdx.x;
  const float* src; short* d; int R, C, r0, c0;
  if (id < 6912) {
    int l = id / 576, rem = id % 576, mat = rem / 144, tl = rem % 144;
    const float* srcs[4] = {p.wq, p.wk, p.wv, p.wo};
    src = srcs[mat] + (size_t)l * DD2C;
    d = p.wT + ((size_t)l * 4 + mat) * DD2C;
    R = 768; C = 768;
    r0 = (tl / 12) * 64; c0 = (tl % 12) * 64;
  } else if (id < 13824) {
    int id2 = id - 6912;
    int l = id2 / 576, tl = id2 % 576;
    src = p.w1 + (size_t)l * DM * DF;
    d = p.w1T + (size_t)l * DM * DF;
    R = 768; C = 3072;
    r0 = (tl / 48) * 64; c0 = (tl % 48) * 64;
  } else {
    int id2 = id - 13824;
    int l = id2 / 576, tl = id2 % 576;
    src = p.w2 + (size_t)l * DM * DF;
    d = p.w2T + (size_t)l * DM * DF;
    R = 3072; C = 768;
    r0 = (tl / 12) * 64; c0 = (tl % 12) * 64;
  }
  int t = threadIdx.x;
  int tr = t >> 4, tc = (t & 15) * 4;
#pragma unroll
  for (int i = 0; i < 4; i++) {
    int r = tr + i * 16;
    f32x4 v = *(const f32x4*)(src + (size_t)(r0 + r) * C + c0 + tc);
    tile[r][tc + 0] = f2bs(v[0]);
    tile[r][tc + 1] = f2bs(v[1]);
    tile[r][tc + 2] = f2bs(v[2]);
    tile[r][tc + 3] = f2bs(v[3]);
  }
  __syncthreads();
#pragma unroll
  for (int i = 0; i < 4; i++) {
    int rr = tr + i * 16;
    short4v o;
    o[0] = tile[tc + 0][rr];
    o[1] = tile[tc + 1][rr];
    o[2] = tile[tc + 2][rr];
    o[3] = tile[tc + 3][rr];
    *(short4v*)(d + (size_t)(c0 + rr) * R + r0 + tc) = o;
  }
}

// per-layer fallback transpose (non-hoist path)
struct Ptrs4 { const float* p[4]; };

template <int NW>
__global__ void k_transpose(Ptrs4 ps, short* __restrict__ dst, int R, int C,
                            size_t sstride) {
  __shared__ short tile[64][68];
  int z = blockIdx.z;
  const float* src = ps.p[z % NW] + (size_t)(z / NW) * sstride;
  short* d = dst + (size_t)z * (size_t)R * C;
  int r0 = blockIdx.x * 64, c0 = blockIdx.y * 64;
  int t = threadIdx.x;
  int tr = t >> 4, tc = (t & 15) * 4;
#pragma unroll
  for (int i = 0; i < 4; i++) {
    int r = tr + i * 16;
    f32x4 v = *(const f32x4*)(src + (size_t)(r0 + r) * C + c0 + tc);
    tile[r][tc + 0] = f2bs(v[0]);
    tile[r][tc + 1] = f2bs(v[1]);
    tile[r][tc + 2] = f2bs(v[2]);
    tile[r][tc + 3] = f2bs(v[3]);
  }
  __syncthreads();
#pragma unroll
  for (int i = 0; i < 4; i++) {
    int rr = tr + i * 16;
    short4v o;
    o[0] = tile[tc + 0][rr];
    o[1] = tile[tc + 1][rr];
    o[2] = tile[tc + 2][rr];
    o[3] = tile[tc + 3][rr];
    *(short4v*)(d + (size_t)(c0 + rr) * R + r0 + tc) = o;
  }
}

// ---------------- fused: h += p0+p1+cbias; y = LN(h) ----------------
__global__ void k_ln_add2(float* __restrict__ h, const float* __restrict__ p0,
                          const float* __restrict__ p1, const float* __restrict__ cb,
                          const float* __restrict__ g, const float* __restrict__ bb,
                          bf16* __restrict__ y) {
  int r = blockIdx.x;
  int t = threadIdx.x, lane = t & 63, wid = t >> 6;
  __shared__ float red[8];
  size_t base = (size_t)r * DM;
  float v0 = h[base + t] + p0[base + t] + p1[base + t] + cb[t];
  float v1 = h[base + t + 256] + p0[base + t + 256] + p1[base + t + 256] + cb[t + 256];
  float v2 = h[base + t + 512] + p0[base + t + 512] + p1[base + t + 512] + cb[t + 512];
  h[base + t] = v0;
  h[base + t + 256] = v1;
  h[base + t + 512] = v2;
  float s = v0 + v1 + v2;
#pragma unroll
  for (int o = 32; o > 0; o >>= 1) s += __shfl_xor(s, o);
  if (lane == 0) red[wid] = s;
  __syncthreads();
  float mean = (red[0] + red[1] + red[2] + red[3]) * (1.f / 768.f);
  float d0 = v0 - mean, d1 = v1 - mean, d2 = v2 - mean;
  float q = d0 * d0 + d1 * d1 + d2 * d2;
#pragma unroll
  for (int o = 32; o > 0; o >>= 1) q += __shfl_xor(q, o);
  if (lane == 0) red[4 + wid] = q;
  __syncthreads();
  float var = (red[4] + red[5] + red[6] + red[7]) * (1.f / 768.f);
  float rstd = rsqrtf(var + 1e-5f);
  bf16* yr = y + base;
  yr[t] = __float2bfloat16(d0 * rstd * g[t] + bb[t]);
  yr[t + 256] = __float2bfloat16(d1 * rstd * g[t + 256] + bb[t + 256]);
  yr[t + 512] = __float2bfloat16(d2 * rstd * g[t + 512] + bb[t + 512]);
}

// ---------------- GEMM common ----------------
// MODE 2: GELU->bf16; MODE 3: raw fp32
struct GemmPtrs {
  const short* bt[3];
  const float* bias[3];
  void* out[3];
  int aoff[3];
};

template <int MODE>
__device__ __forceinline__ void gemm_store(void* outp, size_t idx, float v) {
  if (MODE == 3) {
    ((float*)outp)[idx] = v;
  } else {
    float gg = 0.5f * v * (1.f + erff(v * 0.70710678118654752f));
    ((bf16*)outp)[idx] = __float2bfloat16(gg);
  }
}

// 128x128 block, 4 waves x 64x64, BK=64, single-buffer, swizzled. 32KB -> 3/CU.
template <int MODE>
__global__ __launch_bounds__(256, 3) void k_gemm128(const short* __restrict__ A, GemmPtrs p,
                                                    int M, int N, int K, int lda, int ldb) {
  __shared__ short At[128 * 64];
  __shared__ short Bt[128 * 64];
  int z = blockIdx.z;
  const short* BT = p.bt[z];
  const float* bias = p.bias[z];
  A += p.aoff[z];
  int m0 = blockIdx.x * 128, n0 = blockIdx.y * 128;
  int t = threadIdx.x, lane = t & 63, wid = t >> 6;
  int wr = wid >> 1, wc = wid & 1;
  f32x4 acc[4][4];
#pragma unroll
  for (int a = 0; a < 4; a++)
#pragma unroll
    for (int c = 0; c < 4; c++) acc[a][c] = (f32x4){0.f, 0.f, 0.f, 0.f};

  int lrow8 = lane >> 3;
  int lseg = (lane & 7) ^ lrow8;
  const short* gA[4];
  const short* gB[4];
#pragma unroll
  for (int i = 0; i < 4; i++) {
    int ar = m0 + wid * 32 + i * 8 + lrow8;
    if (ar >= M) ar = M - 1;
    gA[i] = A + (size_t)ar * lda + lseg * 8;
    int br = n0 + wid * 32 + i * 8 + lrow8;
    gB[i] = BT + (size_t)br * ldb + lseg * 8;
  }

  const int NIT = K >> 6;
  int fr = lane & 15, q = lane >> 4;
  for (int it = 0; it < NIT; ++it) {
    int k0 = it << 6;
#pragma unroll
    for (int i = 0; i < 4; i++) {
      gload16(gA[i] + k0, &At[(wid * 32 + i * 8) * 64]);
      gload16(gB[i] + k0, &Bt[(wid * 32 + i * 8) * 64]);
    }
    __syncthreads();
#pragma unroll
    for (int kk = 0; kk < 2; kk++) {
      int sg = ((q + kk * 4) ^ (fr & 7)) * 8;
      short8 af[4], bf[4];
#pragma unroll
      for (int mr = 0; mr < 4; mr++)
        af[mr] = *(const short8*)&At[(wr * 64 + mr * 16 + fr) * 64 + sg];
#pragma unroll
      for (int nc = 0; nc < 4; nc++)
        bf[nc] = *(const short8*)&Bt[(wc * 64 + nc * 16 + fr) * 64 + sg];
#pragma unroll
      for (int mr = 0; mr < 4; mr++)
#pragma unroll
        for (int nc = 0; nc < 4; nc++)
          acc[mr][nc] = __builtin_amdgcn_mfma_f32_16x16x32_bf16(af[mr], bf[nc], acc[mr][nc], 0, 0, 0);
    }
    __syncthreads();
  }

  int rsub = q * 4;
#pragma unroll
  for (int nc = 0; nc < 4; nc++) {
    int col = n0 + wc * 64 + nc * 16 + fr;
    float bv = (MODE == 3) ? 0.f : bias[col];
#pragma unroll
    for (int mr = 0; mr < 4; mr++) {
#pragma unroll
      for (int e = 0; e < 4; e++) {
        int r = m0 + wr * 64 + mr * 16 + rsub + e;
        if (r < M) gemm_store<MODE>(p.out[z], (size_t)r * N + col, acc[mr][nc][e] + bv);
      }
    }
  }
}

// 64x128 block, 4 waves x 32x64, BK=64, single-buffer, swizzled. 24KB -> 4/CU.
template <int MODE>
__global__ __launch_bounds__(256, 4) void k_gemm64(const short* __restrict__ A, GemmPtrs p,
                                                   int M, int N, int K, int lda, int ldb) {
  __shared__ short At[64 * 64];
  __shared__ short Bt[128 * 64];
  int z = blockIdx.z;
  const short* BT = p.bt[z];
  const float* bias = p.bias[z];
  A += p.aoff[z];
  int m0 = blockIdx.x * 64, n0 = blockIdx.y * 128;
  int t = threadIdx.x, lane = t & 63, wid = t >> 6;
  int wr = wid >> 1, wc = wid & 1;
  f32x4 acc[2][4];
#pragma unroll
  for (int a = 0; a < 2; a++)
#pragma unroll
    for (int c = 0; c < 4; c++) acc[a][c] = (f32x4){0.f, 0.f, 0.f, 0.f};

  int lrow8 = lane >> 3;
  int lseg = (lane & 7) ^ lrow8;
  const short* gA[2];
  const short* gB[4];
#pragma unroll
  for (int i = 0; i < 2; i++) {
    int ar = m0 + wid * 16 + i * 8 + lrow8;
    if (ar >= M) ar = M - 1;
    gA[i] = A + (size_t)ar * lda + lseg * 8;
  }
#pragma unroll
  for (int i = 0; i < 4; i++) {
    int br = n0 + wid * 32 + i * 8 + lrow8;
    gB[i] = BT + (size_t)br * ldb + lseg * 8;
  }

  const int NIT = K >> 6;
  int fr = lane & 15, q = lane >> 4;
  for (int it = 0; it < NIT; ++it) {
    int k0 = it << 6;
#pragma unroll
    for (int i = 0; i < 2; i++) gload16(gA[i] + k0, &At[(wid * 16 + i * 8) * 64]);
#pragma unroll
    for (int i = 0; i < 4; i++) gload16(gB[i] + k0, &Bt[(wid * 32 + i * 8) * 64]);
    __syncthreads();
#pragma unroll
    for (int kk = 0; kk < 2; kk++) {
      int sg = ((q + kk * 4) ^ (fr & 7)) * 8;
      short8 af[2], bf[4];
#pragma unroll
      for (int mr = 0; mr < 2; mr++)
        af[mr] = *(const short8*)&At[(wr * 32 + mr * 16 + fr) * 64 + sg];
#pragma unroll
      for (int nc = 0; nc < 4; nc++)
        bf[nc] = *(const short8*)&Bt[(wc * 64 + nc * 16 + fr) * 64 + sg];
#pragma unroll
      for (int mr = 0; mr < 2; mr++)
#pragma unroll
        for (int nc = 0; nc < 4; nc++)
          acc[mr][nc] = __builtin_amdgcn_mfma_f32_16x16x32_bf16(af[mr], bf[nc], acc[mr][nc], 0, 0, 0);
    }
    __syncthreads();
  }

  int rsub = q * 4;
#pragma unroll
  for (int nc = 0; nc < 4; nc++) {
    int col = n0 + wc * 64 + nc * 16 + fr;
    float bv = (MODE == 3) ? 0.f : bias[col];
#pragma unroll
    for (int mr = 0; mr < 2; mr++) {
#pragma unroll
      for (int e = 0; e < 4; e++) {
        int r = m0 + wr * 32 + mr * 16 + rsub + e;
        if (r < M) gemm_store<MODE>(p.out[z], (size_t)r * N + col, acc[mr][nc][e] + bv);
      }
    }
  }
}

// ---------------- fused QKV projection + MFMA flash attention ----------------
// Phase 1: BK=64 staged QKV GEMM into LDS; phase 2: QK^T -> softmax -> PV.
__global__ __launch_bounds__(256) void k_fattn(const bf16* __restrict__ y,
                                               const short* __restrict__ wTl,
                                               const float* __restrict__ bq,
                                               const float* __restrict__ bk,
                                               const float* __restrict__ bv,
                                               const float* __restrict__ gab,
                                               bf16* __restrict__ ctx) {
  __shared__ short Ql[144 * 40];
  __shared__ short Kl[144 * 40];
  __shared__ short Vt[32 * 168];
  __shared__ short U[15360];     // phase1: Ay[144*64]=9216 + Bw[96*64]=6144; phase2: Pc
  __shared__ float bqa[32], bka[32], bva[32];
  short* Ay = U;
  short* Bw = U + 9216;
  short* Pc = U;
  int bh = blockIdx.x;
  int b = bh / NH, hh = bh % NH;
  int t = threadIdx.x;
  int lane = t & 63, w = t >> 6;

  for (int idx = t; idx < 32 * 39; idx += 256) {
    int d = idx / 39, kk = 129 + (idx % 39);
    Vt[d * 168 + kk] = 0;
  }
  if (t < 32) {
    bqa[t] = bq[hh * 32 + t];
    bka[t] = bk[hh * 32 + t];
    bva[t] = bv[hh * 32 + t];
  }

  // ---- phase 1: QKV via MFMA over 12 K-tiles of 64 ----
  f32x4 acc[3][3][2];
#pragma unroll
  for (int i = 0; i < 3; i++)
#pragma unroll
    for (int m = 0; m < 3; m++)
#pragma unroll
      for (int nt = 0; nt < 2; nt++) acc[i][m][nt] = (f32x4){0.f, 0.f, 0.f, 0.f};

  int lrow8 = lane >> 3;
  int lseg8 = (lane & 7) ^ lrow8;
  int fr = lane & 15, q = lane >> 4;
  const short* ybase = (const short*)y + (size_t)(b * SQ) * DM;

  for (int kt = 0; kt < 12; ++kt) {
    int k0 = kt << 6;
    __syncthreads();
    // stage A: 9 groups of 16 rows, 2 gloads each (rows g*16+lrow8, +8)
    for (int i = w; i < 9; i += 4) {
      gload16(ybase + (size_t)(i * 16 + lrow8) * DM + k0 + lseg8 * 8, &Ay[(i * 16) * 64]);
      gload16(ybase + (size_t)(i * 16 + 8 + lrow8) * DM + k0 + lseg8 * 8,
              &Ay[(i * 16 + 8) * 64]);
    }
    // stage B: 6 groups of 16 rows (3 mats x 2 halves)
    for (int i = w; i < 6; i += 4) {
      int m = i >> 1, half = i & 1;
      const short* wb = wTl + (size_t)m * DD2C + (size_t)(hh * 32 + half * 16) * DM + k0;
      gload16(wb + (size_t)lrow8 * DM + lseg8 * 8, &Bw[(m * 32 + half * 16) * 64]);
      gload16(wb + (size_t)(8 + lrow8) * DM + lseg8 * 8, &Bw[(m * 32 + half * 16 + 8) * 64]);
    }
    __syncthreads();
#pragma unroll
    for (int kk = 0; kk < 2; kk++) {
      int sg = ((q + kk * 4) ^ (fr & 7)) * 8;
#pragma unroll
      for (int i = 0; i < 3; i++) {
        int mt = w + 4 * i;
        if (mt > 8) break;
        short8 af = *(const short8*)&Ay[(mt * 16 + fr) * 64 + sg];
#pragma unroll
        for (int m = 0; m < 3; m++)
#pragma unroll
          for (int nt = 0; nt < 2; nt++) {
            short8 bf = *(const short8*)&Bw[(m * 32 + nt * 16 + fr) * 64 + sg];
            acc[i][m][nt] = __builtin_amdgcn_mfma_f32_16x16x32_bf16(af, bf, acc[i][m][nt], 0, 0, 0);
          }
      }
    }
  }
  __syncthreads();
  // scatter Q,K,V (+bias) into Ql/Kl/Vt (bf16)
#pragma unroll
  for (int i = 0; i < 3; i++) {
    int mt = w + 4 * i;
    if (mt > 8) break;
#pragma unroll
    for (int nt = 0; nt < 2; nt++) {
      int coll = nt * 16 + fr;
      float bqv = bqa[coll], bkv = bka[coll], bvv = bva[coll];
#pragma unroll
      for (int e = 0; e < 4; e++) {
        int row = mt * 16 + q * 4 + e;
        Ql[row * 40 + coll] = f2bs(acc[i][0][nt][e] + bqv);
        Kl[row * 40 + coll] = f2bs(acc[i][1][nt][e] + bkv);
        if (row < 129) Vt[coll * 168 + row] = f2bs(acc[i][2][nt][e] + bvv);
      }
    }
  }
  __syncthreads();

  // ---- phase 2: QK^T -> softmax -> PV ----
  int c16 = lane & 15, q4 = lane >> 4;
  const float scale = 0.17677669529663689f;  // 1/sqrt(32)
  const float* gabp = gab + (((size_t)(b * NH + hh)) * SQ) * SQ;

  for (int mt = w; mt < 9; mt += 4) {
    f32x4 sc[9];
    short8 aq = *(const short8*)&Ql[(mt * 16 + c16) * 40 + q4 * 8];
#pragma unroll
    for (int nt = 0; nt < 9; nt++) {
      short8 bk8 = *(const short8*)&Kl[(nt * 16 + c16) * 40 + q4 * 8];
      f32x4 zz = {0.f, 0.f, 0.f, 0.f};
      sc[nt] = __builtin_amdgcn_mfma_f32_16x16x32_bf16(aq, bk8, zz, 0, 0, 0);
    }
#pragma unroll
    for (int e = 0; e < 4; e++) {
      int row = mt * 16 + q4 * 4 + e;
      int rr = row < 129 ? row : 128;
      const float* grow = gabp + (size_t)rr * SQ;
      float mloc = -1e30f;
#pragma unroll
      for (int nt = 0; nt < 9; nt++) {
        int col = nt * 16 + c16;
        float s = (col < 129) ? (sc[nt][e] * scale + grow[col]) : -1e30f;
        sc[nt][e] = s;
        mloc = fmaxf(mloc, s);
      }
#pragma unroll
      for (int o = 1; o < 16; o <<= 1) mloc = fmaxf(mloc, __shfl_xor(mloc, o));
      float sum = 0.f;
#pragma unroll
      for (int nt = 0; nt < 9; nt++) {
        float pp = __expf(sc[nt][e] - mloc);
        sc[nt][e] = pp;
        sum += pp;
      }
#pragma unroll
      for (int o = 1; o < 16; o <<= 1) sum += __shfl_xor(sum, o);
      float inv = 1.f / sum;
#pragma unroll
      for (int nt = 0; nt < 9; nt++) sc[nt][e] *= inv;
    }
    f32x4 oacc0 = {0.f, 0.f, 0.f, 0.f}, oacc1 = {0.f, 0.f, 0.f, 0.f};
#pragma unroll
    for (int c = 0; c < 5; c++) {
#pragma unroll
      for (int u = 0; u < 2; u++) {
        int nt = c * 2 + u;
        if (nt < 9) {
#pragma unroll
          for (int e = 0; e < 4; e++)
            Pc[(mt * 16 + q4 * 4 + e) * 40 + u * 16 + c16] = f2bs(sc[nt][e]);
        } else {
#pragma unroll
          for (int e = 0; e < 4; e++)
            Pc[(mt * 16 + q4 * 4 + e) * 40 + u * 16 + c16] = 0;
        }
      }
      asm volatile("s_waitcnt lgkmcnt(0)" ::: "memory");
      __builtin_amdgcn_sched_barrier(0);
      short8 ap = *(const short8*)&Pc[(mt * 16 + c16) * 40 + q4 * 8];
      short8 bv0 = *(const short8*)&Vt[(c16) * 168 + c * 32 + q4 * 8];
      short8 bv1 = *(const short8*)&Vt[(16 + c16) * 168 + c * 32 + q4 * 8];
      oacc0 = __builtin_amdgcn_mfma_f32_16x16x32_bf16(ap, bv0, oacc0, 0, 0, 0);
      oacc1 = __builtin_amdgcn_mfma_f32_16x16x32_bf16(ap, bv1, oacc1, 0, 0, 0);
    }
#pragma unroll
    for (int e = 0; e < 4; e++) {
      int row = mt * 16 + q4 * 4 + e;
      if (row < 129) {
        size_t obase = ((size_t)(b * SQ + row)) * DM + hh * 32;
        ctx[obase + c16] = __float2bfloat16(oacc0[e]);
        ctx[obase + 16 + c16] = __float2bfloat16(oacc1[e]);
      }
    }
  }
}

// ---------------- final: h_row0 + p0 + p1 + cbias -> LN -> project ----------------
__global__ void k_final_add2(const float* __restrict__ h, const float* __restrict__ p0,
                             const float* __restrict__ p1, const float* __restrict__ cb,
                             const float* __restrict__ g, const float* __restrict__ bb,
                             const float* __restrict__ ow, const float* __restrict__ ob,
                             float* __restrict__ out) {
  int b = blockIdx.x;
  int t = threadIdx.x, lane = t & 63, wid = t >> 6;
  __shared__ float red[8];
  __shared__ float yn[768];
  size_t base = (size_t)(b * SQ) * DM;
  float v0 = h[base + t] + p0[base + t] + p1[base + t] + cb[t];
  float v1 = h[base + t + 256] + p0[base + t + 256] + p1[base + t + 256] + cb[t + 256];
  float v2 = h[base + t + 512] + p0[base + t + 512] + p1[base + t + 512] + cb[t + 512];
  float s = v0 + v1 + v2;
#pragma unroll
  for (int o = 32; o > 0; o >>= 1) s += __shfl_xor(s, o);
  if (lane == 0) red[wid] = s;
  __syncthreads();
  float mean = (red[0] + red[1] + red[2] + red[3]) * (1.f / 768.f);
  float d0 = v0 - mean, d1 = v1 - mean, d2 = v2 - mean;
  float q = d0 * d0 + d1 * d1 + d2 * d2;
#pragma unroll
  for (int o = 32; o > 0; o >>= 1) q += __shfl_xor(q, o);
  if (lane == 0) red[4 + wid] = q;
  __syncthreads();
  float var = (red[4] + red[5] + red[6] + red[7]) * (1.f / 768.f);
  float rstd = rsqrtf(var + 1e-5f);
  yn[t] = d0 * rstd * g[t] + bb[t];
  yn[t + 256] = d1 * rstd * g[t + 256] + bb[t + 256];
  yn[t + 512] = d2 * rstd * g[t + 512] + bb[t + 512];
  __syncthreads();
  if (t < 128) {
    float acc = ob[t];
    for (int d = 0; d < 768; d++) acc += yn[d] * ow[d * 128 + t];
    out[b * 128 + t] = acc;
  }
}

extern "C" void kernel_launch(void* const* d_in, const int* in_sizes, int n_in,
                              void* d_out, int out_size, void* d_ws, size_t ws_size,
                              hipStream_t stream) {
  (void)in_sizes; (void)n_in; (void)out_size;
  const int* x     = (const int*)d_in[0];
  const int* ind   = (const int*)d_in[1];
  const int* outd  = (const int*)d_in[2];
  const int* spos  = (const int*)d_in[3];
  const int* eidx  = (const int*)d_in[4];
  const float* ab   = (const float*)d_in[5];
  const float* atom = (const float*)d_in[6];
  const float* ide  = (const float*)d_in[7];
  const float* ode  = (const float*)d_in[8];
  const float* gtok = (const float*)d_in[9];
  const float* eemb = (const float*)d_in[10];
  const float* edemb= (const float*)d_in[11];
  const float* semb = (const float*)d_in[12];
  const float* virt = (const float*)d_in[13];
  const float* ln1g = (const float*)d_in[14];
  const float* ln1b = (const float*)d_in[15];
  const float* wq  = (const float*)d_in[16];
  const float* bq   = (const float*)d_in[17];
  const float* wk  = (const float*)d_in[18];
  const float* bk   = (const float*)d_in[19];
  const float* wv  = (const float*)d_in[20];
  const float* bv   = (const float*)d_in[21];
  const float* wo  = (const float*)d_in[22];
  const float* bo   = (const float*)d_in[23];
  const float* ln2g = (const float*)d_in[24];
  const float* ln2b = (const float*)d_in[25];
  const float* w1  = (const float*)d_in[26];
  const float* b1   = (const float*)d_in[27];
  const float* w2  = (const float*)d_in[28];
  const float* b2   = (const float*)d_in[29];
  const float* fg   = (const float*)d_in[30];
  const float* fb   = (const float*)d_in[31];
  const float* ow   = (const float*)d_in[32];
  const float* ob   = (const float*)d_in[33];
  float* out = (float*)d_out;

  const int DD2 = DM * DM;
  const size_t WQKVO = (size_t)DD2;
  const size_t WFF = (size_t)DM * DF;

  char* ws = (char*)d_ws;
  size_t off = 0;
  auto alloc = [&](size_t bytes) -> void* {
    void* p = ws + off;
    off += (bytes + 255) & ~(size_t)255;
    return p;
  };
  float* gab = (float*)alloc((size_t)NB * NH * SQ * SQ * 4);
  float* h   = (float*)alloc((size_t)MROWS * DM * 4);
  bf16* y    = (bf16*)alloc((size_t)MROWS * DM * 2);
  bf16* ctx  = (bf16*)alloc((size_t)MROWS * DM * 2);
  bf16* t1   = (bf16*)alloc((size_t)MROWS * DF * 2);
  float* p0  = (float*)alloc((size_t)MROWS * DM * 4);
  float* p1  = (float*)alloc((size_t)MROWS * DM * 4);

  size_t need_hoist = off + ((size_t)NLAY * 4 * WQKVO + 2 * (size_t)NLAY * WFF) * 2 + (1 << 20);
  bool hoist = ws_size >= need_hoist;
  short* wT  = (short*)alloc((hoist ? (size_t)NLAY * 4 * WQKVO : 4 * WQKVO) * 2);
  short* w1T = (short*)alloc((hoist ? (size_t)NLAY * WFF : WFF) * 2);
  short* w2T = (short*)alloc((hoist ? (size_t)NLAY * WFF : WFF) * 2);

  dim3 blk(256);
  // node features + first LN + gab borders (one dispatch)
  k_nodefeat_ln<<<dim3(MROWS), blk, 0, stream>>>(x, ind, outd, atom, ide, ode, gtok,
                                                 ab, virt, ln1g, ln1b, h, y, gab);
  k_gab_edge<<<dim3(NB * ND * 2), blk, 0, stream>>>(spos, eidx, eemb, edemb, semb, ab, gab);

  if (hoist) {
    TAll ta;
    ta.wq = wq; ta.wk = wk; ta.wv = wv; ta.wo = wo; ta.w1 = w1; ta.w2 = w2;
    ta.wT = wT; ta.w1T = w1T; ta.w2T = w2T;
    k_transpose_all<<<dim3(20736), blk, 0, stream>>>(ta);
  }

  for (int l = 0; l < NLAY; l++) {
    if (!hoist) {
      Ptrs4 pq;
      pq.p[0] = wq + (size_t)l * DD2; pq.p[1] = wk + (size_t)l * DD2;
      pq.p[2] = wv + (size_t)l * DD2; pq.p[3] = wo + (size_t)l * DD2;
      k_transpose<4><<<dim3(12, 12, 4), blk, 0, stream>>>(pq, wT, DM, DM, 0);
      Ptrs4 pa; pa.p[0] = w1 + (size_t)l * WFF; pa.p[1] = pa.p[2] = pa.p[3] = pa.p[0];
      k_transpose<1><<<dim3(12, 48, 1), blk, 0, stream>>>(pa, w1T, DM, DF, 0);
      Ptrs4 pb; pb.p[0] = w2 + (size_t)l * WFF; pb.p[1] = pb.p[2] = pb.p[3] = pb.p[0];
      k_transpose<1><<<dim3(48, 12, 1), blk, 0, stream>>>(pb, w2T, DF, DM, 0);
    }
    const short* wTl  = wT  + (hoist ? (size_t)l * 4 * WQKVO : 0);
    const short* w1Tl = w1T + (hoist ? (size_t)l * WFF : 0);
    const short* w2Tl = w2T + (hoist ? (size_t)l * WFF : 0);

    // fused QKV + attention
    k_fattn<<<dim3(NB * NH), blk, 0, stream>>>(y, wTl, bq + l * DM, bk + l * DM,
                                               bv + l * DM, gab, ctx);

    GemmPtrs go;  // Wo split-K: K=768 -> 2 x 384
    go.bt[0] = wTl + 3 * DD2; go.bt[1] = wTl + 3 * DD2 + 384;
    go.bias[0] = go.bias[1] = nullptr;
    go.out[0] = p0; go.out[1] = p1;
    go.aoff[0] = 0; go.aoff[1] = 384;
    go.bt[2] = go.bt[0]; go.out[2] = p0; go.aoff[2] = 0; go.bias[2] = nullptr;
    k_gemm64<3><<<dim3(33, 6, 2), blk, 0, stream>>>((const short*)ctx, go, MROWS, DM, 384, DM, DM);

    k_ln_add2<<<dim3(MROWS), blk, 0, stream>>>(h, p0, p1, bo + l * DM,
                                               ln2g + l * DM, ln2b + l * DM, y);

    GemmPtrs g1;
    g1.bt[0] = g1.bt[1] = g1.bt[2] = w1Tl;
    g1.bias[0] = g1.bias[1] = g1.bias[2] = b1 + l * DF;
    g1.out[0] = g1.out[1] = g1.out[2] = t1;
    g1.aoff[0] = g1.aoff[1] = g1.aoff[2] = 0;
    k_gemm128<2><<<dim3(17, 24, 1), blk, 0, stream>>>((const short*)y, g1, MROWS, DF, DM, DM, DM);

    GemmPtrs g2;  // FFN2 split-K: K=3072 -> 2 x 1536
    g2.bt[0] = w2Tl; g2.bt[1] = w2Tl + 1536;
    g2.bias[0] = g2.bias[1] = nullptr;
    g2.out[0] = p0; g2.out[1] = p1;
    g2.aoff[0] = 0; g2.aoff[1] = 1536;
    g2.bt[2] = g2.bt[0]; g2.out[2] = p0; g2.aoff[2] = 0; g2.bias[2] = nullptr;
    k_gemm64<3><<<dim3(33, 6, 2), blk, 0, stream>>>((const short*)t1, g2, MROWS, DM, 1536, DF, DF);

    if (l < NLAY - 1) {
      k_ln_add2<<<dim3(MROWS), blk, 0, stream>>>(h, p0, p1, b2 + l * DM,
                                                 ln1g + (l + 1) * DM, ln1b + (l + 1) * DM, y);
    } else {
      k_final_add2<<<dim3(NB), blk, 0, stream>>>(h, p0, p1, b2 + l * DM, fg, fb, ow, ob, out);
    }
  }
}

// Round 13
// 1508.241 us; speedup vs baseline: 1.3666x; 1.0261x over previous
//
#include <hip/hip_runtime.h>
#include <hip/hip_bf16.h>
#include <math.h>

typedef __hip_bfloat16 bf16;
typedef __attribute__((ext_vector_type(8))) short short8;
typedef __attribute__((ext_vector_type(4))) short short4v;
typedef __attribute__((ext_vector_type(4))) float f32x4;

constexpr int NB = 16;     // batch
constexpr int ND = 128;    // nodes N
constexpr int SQ = 129;    // S = N+1
constexpr int NH = 24;     // heads
constexpr int DM = 768;    // model dim
constexpr int DF = 3072;   // ffn dim
constexpr int NLAY = 12;
constexpr int MROWS = NB * SQ;  // 2064
constexpr int DD2C = DM * DM;

__device__ __forceinline__ short f2bs(float f) {
  bf16 h = __float2bfloat16(f);
  return *(short*)&h;
}

__device__ __forceinline__ void gload16(const void* g, void* lds) {
  __builtin_amdgcn_global_load_lds(
      (const __attribute__((address_space(1))) unsigned int*)g,
      (__attribute__((address_space(3))) unsigned int*)lds, 16, 0, 0);
}

// ================= device bodies (shared by fused prologue + fallbacks) ======

__device__ __forceinline__ void dev_nodefeat_ln(
    char* smem, int bs, int t,
    const int* x, const int* ind, const int* outd,
    const float* atom, const float* ide, const float* ode, const float* gtok,
    const float* ab, const float* virt, const float* g, const float* bb,
    float* h, bf16* y, float* gab) {
  float* red = (float*)smem;
  int b = bs / SQ, s = bs % SQ;
  int lane = t & 63, wid = t >> 6;
  float vv[3];
  if (s == 0) {
    vv[0] = gtok[t]; vv[1] = gtok[t + 256]; vv[2] = gtok[t + 512];
  } else {
    int n = s - 1;
    const int* xr = x + (b * ND + n) * 9;
    int a0 = xr[0], a1 = xr[1], a2 = xr[2], a3 = xr[3], a4 = xr[4];
    int a5 = xr[5], a6 = xr[6], a7 = xr[7], a8 = xr[8];
    int ii = ind[b * ND + n], oo = outd[b * ND + n];
#pragma unroll
    for (int u = 0; u < 3; u++) {
      int c = t + u * 256;
      float acc = ide[(size_t)ii * DM + c] + ode[(size_t)oo * DM + c];
      acc += atom[(size_t)a0 * DM + c];
      acc += atom[(size_t)a1 * DM + c];
      acc += atom[(size_t)a2 * DM + c];
      acc += atom[(size_t)a3 * DM + c];
      acc += atom[(size_t)a4 * DM + c];
      acc += atom[(size_t)a5 * DM + c];
      acc += atom[(size_t)a6 * DM + c];
      acc += atom[(size_t)a7 * DM + c];
      acc += atom[(size_t)a8 * DM + c];
      vv[u] = acc;
    }
  }
  float* hrow = h + (size_t)bs * DM;
  hrow[t] = vv[0]; hrow[t + 256] = vv[1]; hrow[t + 512] = vv[2];
  float sum = vv[0] + vv[1] + vv[2];
#pragma unroll
  for (int o = 32; o > 0; o >>= 1) sum += __shfl_xor(sum, o);
  if (lane == 0) red[wid] = sum;
  __syncthreads();
  float mean = (red[0] + red[1] + red[2] + red[3]) * (1.f / 768.f);
  float d0 = vv[0] - mean, d1 = vv[1] - mean, d2 = vv[2] - mean;
  float q = d0 * d0 + d1 * d1 + d2 * d2;
#pragma unroll
  for (int o = 32; o > 0; o >>= 1) q += __shfl_xor(q, o);
  if (lane == 0) red[4 + wid] = q;
  __syncthreads();
  float var = (red[4] + red[5] + red[6] + red[7]) * (1.f / 768.f);
  float rstd = rsqrtf(var + 1e-5f);
  bf16* yr = y + (size_t)bs * DM;
  yr[t] = __float2bfloat16(d0 * rstd * g[t] + bb[t]);
  yr[t + 256] = __float2bfloat16(d1 * rstd * g[t + 256] + bb[t + 256]);
  yr[t + 512] = __float2bfloat16(d2 * rstd * g[t + 512] + bb[t + 512]);
  if (bs < NB) {
    int bb2 = bs;
    const int tot = NH * SQ + NH * ND;
    for (int idx = t; idx < tot; idx += 256) {
      if (idx < NH * SQ) {
        int hh = idx / SQ, j = idx % SQ;
        float v = 2.f * ab[((size_t)bb2 * SQ + 0) * SQ + j] + virt[hh];
        gab[(((size_t)bb2 * NH + hh) * SQ + 0) * SQ + j] = v;
      } else {
        int r = idx - NH * SQ;
        int hh = r / ND, i = r % ND + 1;
        float v = 2.f * ab[((size_t)bb2 * SQ + i) * SQ + 0] + virt[hh];
        gab[(((size_t)bb2 * NH + hh) * SQ + i) * SQ + 0] = v;
      }
    }
  }
}

__device__ __forceinline__ void dev_gab_edge(
    char* smem, int bi, int t,
    const int* spos, const int* eidx, const float* eemb, const float* edemb,
    const float* semb, const float* ab, float* gab) {
  int* eidxs = (int*)smem;                       // 960 ints @0
  short* ei2 = (short*)(smem + 3840);            // 64*136 shorts
  short* edT = (short*)(smem + 21248);           // 32*136 shorts
  float* ot = (float*)(smem + 29952);            // 24*65 floats
  float* rinvA = (float*)(smem + 36192);
  float* a2A = (float*)(smem + 36448);
  int* spA = (int*)(smem + 36704);
  int half = bi & 1;
  int i = (bi >> 1) & 127;
  int b = bi >> 8;
  int j0 = half * 64;
  const size_t rowbase = ((size_t)(b * ND + i)) * ND + j0;

  const int* esrc = eidx + rowbase * 15;
  for (int idx = t; idx < 960; idx += 256) eidxs[idx] = esrc[idx];
  for (int u = t; u < 720; u += 256) {
    int dh = u / 6, kq = u % 6;
    f32x4 v = *(const f32x4*)&edemb[dh * 24 + kq * 4];
    edT[(kq * 4 + 0) * 136 + dh] = f2bs(v[0]);
    edT[(kq * 4 + 1) * 136 + dh] = f2bs(v[1]);
    edT[(kq * 4 + 2) * 136 + dh] = f2bs(v[2]);
    edT[(kq * 4 + 3) * 136 + dh] = f2bs(v[3]);
  }
  for (int u = t; u < 1472; u += 256) {
    int k, dh;
    if (u < 384) { k = u >> 4; dh = 120 + (u & 15); }
    else { int v = u - 384; k = 24 + v / 136; dh = v % 136; }
    edT[k * 136 + dh] = 0;
  }
  if (t < 64) {
    int j = t;
    int sp = spos[rowbase + j];
    int spc = (sp == 0) ? 1 : sp;
    spc = (spc > 1) ? spc - 1 : spc;
    if (spc > 5) spc = 5;
    spA[j] = sp;
    rinvA[j] = 1.f / (float)spc;
    a2A[j] = 2.f * ab[((size_t)b * SQ + (i + 1)) * SQ + (j0 + j + 1)];
  }
  __syncthreads();

  {
    int j = t & 63, d = t >> 6;
#pragma unroll
    for (int pass = 0; pass < 2; pass++) {
      if (pass == 1) {
        if (t >= 64) break;
        j = t; d = 4;
      }
      const int* ep = &eidxs[j * 15 + d * 3];
      const float* r0 = eemb + (size_t)ep[0] * NH;
      const float* r1 = eemb + (size_t)ep[1] * NH;
      const float* r2 = eemb + (size_t)ep[2] * NH;
#pragma unroll
      for (int hq = 0; hq < 6; hq++) {
        f32x4 s = (*(const f32x4*)&r0[hq * 4] + *(const f32x4*)&r1[hq * 4] +
                   *(const f32x4*)&r2[hq * 4]) * (1.f / 3.f);
        short4v o;
        o[0] = f2bs(s[0]); o[1] = f2bs(s[1]); o[2] = f2bs(s[2]); o[3] = f2bs(s[3]);
        *(short4v*)&ei2[j * 136 + d * 24 + hq * 4] = o;
      }
    }
  }
  for (int idx = t; idx < 64 * 8; idx += 256) {
    int j = idx >> 3;
    ei2[j * 136 + 120 + (idx & 7)] = 0;
  }
  __syncthreads();

  int lane = t & 63, w = t >> 6;
  int fr = lane & 15, q = lane >> 4, fo = q * 8;
  f32x4 acc0 = {0.f, 0.f, 0.f, 0.f}, acc1 = {0.f, 0.f, 0.f, 0.f};
#pragma unroll
  for (int kk = 0; kk < 4; kk++) {
    short8 af = *(const short8*)&ei2[(w * 16 + fr) * 136 + kk * 32 + fo];
    short8 b0 = *(const short8*)&edT[(fr) * 136 + kk * 32 + fo];
    short8 b1 = *(const short8*)&edT[(16 + fr) * 136 + kk * 32 + fo];
    acc0 = __builtin_amdgcn_mfma_f32_16x16x32_bf16(af, b0, acc0, 0, 0, 0);
    acc1 = __builtin_amdgcn_mfma_f32_16x16x32_bf16(af, b1, acc1, 0, 0, 0);
  }
#pragma unroll
  for (int e = 0; e < 4; e++) {
    int j = w * 16 + q * 4 + e;
    ot[fr * 65 + j] = acc0[e];
    if (fr < 8) ot[(16 + fr) * 65 + j] = acc1[e];
  }
  __syncthreads();
  size_t obase = (((size_t)b * NH) * SQ + (i + 1)) * SQ + (j0 + 1);
  for (int idx = t; idx < 24 * 64; idx += 256) {
    int k = idx >> 6, j = idx & 63;
    float v = a2A[j] + semb[spA[j] * NH + k] + ot[k * 65 + j] * rinvA[j];
    gab[obase + (size_t)k * SQ * SQ + j] = v;
  }
}

struct TAll {
  const float* wq; const float* wk; const float* wv; const float* wo;
  const float* w1; const float* w2;
  short* wT; short* w1T; short* w2T;
};

__device__ __forceinline__ void dev_transpose_all(char* smem, int id, int t, TAll p) {
  short* tile = (short*)smem;  // [64][66]
  const float* src; short* d; int R, C, r0, c0;
  if (id < 6912) {
    int l = id / 576, rem = id % 576, mat = rem / 144, tl = rem % 144;
    const float* srcs[4] = {p.wq, p.wk, p.wv, p.wo};
    src = srcs[mat] + (size_t)l * DD2C;
    d = p.wT + ((size_t)l * 4 + mat) * DD2C;
    R = 768; C = 768;
    r0 = (tl / 12) * 64; c0 = (tl % 12) * 64;
  } else if (id < 13824) {
    int id2 = id - 6912;
    int l = id2 / 576, tl = id2 % 576;
    src = p.w1 + (size_t)l * DM * DF;
    d = p.w1T + (size_t)l * DM * DF;
    R = 768; C = 3072;
    r0 = (tl / 48) * 64; c0 = (tl % 48) * 64;
  } else {
    int id2 = id - 13824;
    int l = id2 / 576, tl = id2 % 576;
    src = p.w2 + (size_t)l * DM * DF;
    d = p.w2T + (size_t)l * DM * DF;
    R = 3072; C = 768;
    r0 = (tl / 12) * 64; c0 = (tl % 12) * 64;
  }
  int tr = t >> 4, tc = (t & 15) * 4;
#pragma unroll
  for (int i = 0; i < 4; i++) {
    int r = tr + i * 16;
    f32x4 v = *(const f32x4*)(src + (size_t)(r0 + r) * C + c0 + tc);
    tile[r * 66 + tc + 0] = f2bs(v[0]);
    tile[r * 66 + tc + 1] = f2bs(v[1]);
    tile[r * 66 + tc + 2] = f2bs(v[2]);
    tile[r * 66 + tc + 3] = f2bs(v[3]);
  }
  __syncthreads();
#pragma unroll
  for (int i = 0; i < 4; i++) {
    int rr = tr + i * 16;
    short4v o;
    o[0] = tile[(tc + 0) * 66 + rr];
    o[1] = tile[(tc + 1) * 66 + rr];
    o[2] = tile[(tc + 2) * 66 + rr];
    o[3] = tile[(tc + 3) * 66 + rr];
    *(short4v*)(d + (size_t)(c0 + rr) * R + r0 + tc) = o;
  }
}

// ================= fused prologue (hoist path) =================
struct ProArgs {
  const int* x; const int* ind; const int* outd;
  const float* atom; const float* ide; const float* ode; const float* gtok;
  const float* ab; const float* virt; const float* g; const float* bb;
  float* h; bf16* y; float* gab;
  const int* spos; const int* eidx; const float* eemb; const float* edemb;
  const float* semb;
  TAll ta;
};

__global__ __launch_bounds__(256) void k_prologue(ProArgs a) {
  __shared__ char smem[37376];
  int id = blockIdx.x;
  int t = threadIdx.x;
  if (id < 2048) {
    dev_gab_edge(smem, id, t, a.spos, a.eidx, a.eemb, a.edemb, a.semb, a.ab, a.gab);
  } else if (id < 2048 + MROWS) {
    dev_nodefeat_ln(smem, id - 2048, t, a.x, a.ind, a.outd, a.atom, a.ide, a.ode,
                    a.gtok, a.ab, a.virt, a.g, a.bb, a.h, a.y, a.gab);
  } else {
    dev_transpose_all(smem, id - 2048 - MROWS, t, a.ta);
  }
}

// ---- fallbacks (non-hoist) ----
__global__ void k_nodefeat_ln(const int* x, const int* ind, const int* outd,
                              const float* atom, const float* ide, const float* ode,
                              const float* gtok, const float* ab, const float* virt,
                              const float* g, const float* bb,
                              float* h, bf16* y, float* gab) {
  __shared__ char smem[64];
  dev_nodefeat_ln(smem, blockIdx.x, threadIdx.x, x, ind, outd, atom, ide, ode, gtok,
                  ab, virt, g, bb, h, y, gab);
}

__global__ __launch_bounds__(256) void k_gab_edge(
    const int* spos, const int* eidx, const float* eemb, const float* edemb,
    const float* semb, const float* ab, float* gab) {
  __shared__ char smem[37376];
  dev_gab_edge(smem, blockIdx.x, threadIdx.x, spos, eidx, eemb, edemb, semb, ab, gab);
}

struct Ptrs4 { const float* p[4]; };

template <int NW>
__global__ void k_transpose(Ptrs4 ps, short* __restrict__ dst, int R, int C,
                            size_t sstride) {
  __shared__ short tile[64][66];
  int z = blockIdx.z;
  const float* src = ps.p[z % NW] + (size_t)(z / NW) * sstride;
  short* d = dst + (size_t)z * (size_t)R * C;
  int r0 = blockIdx.x * 64, c0 = blockIdx.y * 64;
  int t = threadIdx.x;
  int tr = t >> 4, tc = (t & 15) * 4;
#pragma unroll
  for (int i = 0; i < 4; i++) {
    int r = tr + i * 16;
    f32x4 v = *(const f32x4*)(src + (size_t)(r0 + r) * C + c0 + tc);
    tile[r][tc + 0] = f2bs(v[0]);
    tile[r][tc + 1] = f2bs(v[1]);
    tile[r][tc + 2] = f2bs(v[2]);
    tile[r][tc + 3] = f2bs(v[3]);
  }
  __syncthreads();
#pragma unroll
  for (int i = 0; i < 4; i++) {
    int rr = tr + i * 16;
    short4v o;
    o[0] = tile[tc + 0][rr];
    o[1] = tile[tc + 1][rr];
    o[2] = tile[tc + 2][rr];
    o[3] = tile[tc + 3][rr];
    *(short4v*)(d + (size_t)(c0 + rr) * R + r0 + tc) = o;
  }
}

// ---------------- fused: h += p0+p1+cbias; y = LN(h) ----------------
__global__ void k_ln_add2(float* __restrict__ h, const float* __restrict__ p0,
                          const float* __restrict__ p1, const float* __restrict__ cb,
                          const float* __restrict__ g, const float* __restrict__ bb,
                          bf16* __restrict__ y) {
  int r = blockIdx.x;
  int t = threadIdx.x, lane = t & 63, wid = t >> 6;
  __shared__ float red[8];
  size_t base = (size_t)r * DM;
  float v0 = h[base + t] + p0[base + t] + p1[base + t] + cb[t];
  float v1 = h[base + t + 256] + p0[base + t + 256] + p1[base + t + 256] + cb[t + 256];
  float v2 = h[base + t + 512] + p0[base + t + 512] + p1[base + t + 512] + cb[t + 512];
  h[base + t] = v0;
  h[base + t + 256] = v1;
  h[base + t + 512] = v2;
  float s = v0 + v1 + v2;
#pragma unroll
  for (int o = 32; o > 0; o >>= 1) s += __shfl_xor(s, o);
  if (lane == 0) red[wid] = s;
  __syncthreads();
  float mean = (red[0] + red[1] + red[2] + red[3]) * (1.f / 768.f);
  float d0 = v0 - mean, d1 = v1 - mean, d2 = v2 - mean;
  float q = d0 * d0 + d1 * d1 + d2 * d2;
#pragma unroll
  for (int o = 32; o > 0; o >>= 1) q += __shfl_xor(q, o);
  if (lane == 0) red[4 + wid] = q;
  __syncthreads();
  float var = (red[4] + red[5] + red[6] + red[7]) * (1.f / 768.f);
  float rstd = rsqrtf(var + 1e-5f);
  bf16* yr = y + base;
  yr[t] = __float2bfloat16(d0 * rstd * g[t] + bb[t]);
  yr[t + 256] = __float2bfloat16(d1 * rstd * g[t + 256] + bb[t + 256]);
  yr[t + 512] = __float2bfloat16(d2 * rstd * g[t + 512] + bb[t + 512]);
}

// ---------------- GEMM common ----------------
// MODE 2: GELU->bf16; MODE 3: raw fp32
struct GemmPtrs {
  const short* bt[3];
  const float* bias[3];
  void* out[3];
  int aoff[3];
};

template <int MODE>
__device__ __forceinline__ void gemm_store(void* outp, size_t idx, float v) {
  if (MODE == 3) {
    ((float*)outp)[idx] = v;
  } else {
    float gg = 0.5f * v * (1.f + erff(v * 0.70710678118654752f));
    ((bf16*)outp)[idx] = __float2bfloat16(gg);
  }
}

// 128x128 block, 4 waves x 64x64, BK=64, single-buffer, swizzled. 32KB -> 3/CU.
template <int MODE>
__global__ __launch_bounds__(256, 3) void k_gemm128(const short* __restrict__ A, GemmPtrs p,
                                                    int M, int N, int K, int lda, int ldb) {
  __shared__ short At[128 * 64];
  __shared__ short Bt[128 * 64];
  int z = blockIdx.z;
  const short* BT = p.bt[z];
  const float* bias = p.bias[z];
  A += p.aoff[z];
  int m0 = blockIdx.x * 128, n0 = blockIdx.y * 128;
  int t = threadIdx.x, lane = t & 63, wid = t >> 6;
  int wr = wid >> 1, wc = wid & 1;
  f32x4 acc[4][4];
#pragma unroll
  for (int a = 0; a < 4; a++)
#pragma unroll
    for (int c = 0; c < 4; c++) acc[a][c] = (f32x4){0.f, 0.f, 0.f, 0.f};

  int lrow8 = lane >> 3;
  int lseg = (lane & 7) ^ lrow8;
  const short* gA[4];
  const short* gB[4];
#pragma unroll
  for (int i = 0; i < 4; i++) {
    int ar = m0 + wid * 32 + i * 8 + lrow8;
    if (ar >= M) ar = M - 1;
    gA[i] = A + (size_t)ar * lda + lseg * 8;
    int br = n0 + wid * 32 + i * 8 + lrow8;
    gB[i] = BT + (size_t)br * ldb + lseg * 8;
  }

  const int NIT = K >> 6;
  int fr = lane & 15, q = lane >> 4;
  for (int it = 0; it < NIT; ++it) {
    int k0 = it << 6;
#pragma unroll
    for (int i = 0; i < 4; i++) {
      gload16(gA[i] + k0, &At[(wid * 32 + i * 8) * 64]);
      gload16(gB[i] + k0, &Bt[(wid * 32 + i * 8) * 64]);
    }
    __syncthreads();
#pragma unroll
    for (int kk = 0; kk < 2; kk++) {
      int sg = ((q + kk * 4) ^ (fr & 7)) * 8;
      short8 af[4], bf[4];
#pragma unroll
      for (int mr = 0; mr < 4; mr++)
        af[mr] = *(const short8*)&At[(wr * 64 + mr * 16 + fr) * 64 + sg];
#pragma unroll
      for (int nc = 0; nc < 4; nc++)
        bf[nc] = *(const short8*)&Bt[(wc * 64 + nc * 16 + fr) * 64 + sg];
#pragma unroll
      for (int mr = 0; mr < 4; mr++)
#pragma unroll
        for (int nc = 0; nc < 4; nc++)
          acc[mr][nc] = __builtin_amdgcn_mfma_f32_16x16x32_bf16(af[mr], bf[nc], acc[mr][nc], 0, 0, 0);
    }
    __syncthreads();
  }

  int rsub = q * 4;
#pragma unroll
  for (int nc = 0; nc < 4; nc++) {
    int col = n0 + wc * 64 + nc * 16 + fr;
    float bv = (MODE == 3) ? 0.f : bias[col];
#pragma unroll
    for (int mr = 0; mr < 4; mr++) {
#pragma unroll
      for (int e = 0; e < 4; e++) {
        int r = m0 + wr * 64 + mr * 16 + rsub + e;
        if (r < M) gemm_store<MODE>(p.out[z], (size_t)r * N + col, acc[mr][nc][e] + bv);
      }
    }
  }
}

// 64x128 block, 4 waves x 32x64, BK=64, single-buffer, swizzled. 24KB -> 4/CU.
template <int MODE>
__global__ __launch_bounds__(256, 4) void k_gemm64(const short* __restrict__ A, GemmPtrs p,
                                                   int M, int N, int K, int lda, int ldb) {
  __shared__ short At[64 * 64];
  __shared__ short Bt[128 * 64];
  int z = blockIdx.z;
  const short* BT = p.bt[z];
  const float* bias = p.bias[z];
  A += p.aoff[z];
  int m0 = blockIdx.x * 64, n0 = blockIdx.y * 128;
  int t = threadIdx.x, lane = t & 63, wid = t >> 6;
  int wr = wid >> 1, wc = wid & 1;
  f32x4 acc[2][4];
#pragma unroll
  for (int a = 0; a < 2; a++)
#pragma unroll
    for (int c = 0; c < 4; c++) acc[a][c] = (f32x4){0.f, 0.f, 0.f, 0.f};

  int lrow8 = lane >> 3;
  int lseg = (lane & 7) ^ lrow8;
  const short* gA[2];
  const short* gB[4];
#pragma unroll
  for (int i = 0; i < 2; i++) {
    int ar = m0 + wid * 16 + i * 8 + lrow8;
    if (ar >= M) ar = M - 1;
    gA[i] = A + (size_t)ar * lda + lseg * 8;
  }
#pragma unroll
  for (int i = 0; i < 4; i++) {
    int br = n0 + wid * 32 + i * 8 + lrow8;
    gB[i] = BT + (size_t)br * ldb + lseg * 8;
  }

  const int NIT = K >> 6;
  int fr = lane & 15, q = lane >> 4;
  for (int it = 0; it < NIT; ++it) {
    int k0 = it << 6;
#pragma unroll
    for (int i = 0; i < 2; i++) gload16(gA[i] + k0, &At[(wid * 16 + i * 8) * 64]);
#pragma unroll
    for (int i = 0; i < 4; i++) gload16(gB[i] + k0, &Bt[(wid * 32 + i * 8) * 64]);
    __syncthreads();
#pragma unroll
    for (int kk = 0; kk < 2; kk++) {
      int sg = ((q + kk * 4) ^ (fr & 7)) * 8;
      short8 af[2], bf[4];
#pragma unroll
      for (int mr = 0; mr < 2; mr++)
        af[mr] = *(const short8*)&At[(wr * 32 + mr * 16 + fr) * 64 + sg];
#pragma unroll
      for (int nc = 0; nc < 4; nc++)
        bf[nc] = *(const short8*)&Bt[(wc * 64 + nc * 16 + fr) * 64 + sg];
#pragma unroll
      for (int mr = 0; mr < 2; mr++)
#pragma unroll
        for (int nc = 0; nc < 4; nc++)
          acc[mr][nc] = __builtin_amdgcn_mfma_f32_16x16x32_bf16(af[mr], bf[nc], acc[mr][nc], 0, 0, 0);
    }
    __syncthreads();
  }

  int rsub = q * 4;
#pragma unroll
  for (int nc = 0; nc < 4; nc++) {
    int col = n0 + wc * 64 + nc * 16 + fr;
    float bv = (MODE == 3) ? 0.f : bias[col];
#pragma unroll
    for (int mr = 0; mr < 2; mr++) {
#pragma unroll
      for (int e = 0; e < 4; e++) {
        int r = m0 + wr * 32 + mr * 16 + rsub + e;
        if (r < M) gemm_store<MODE>(p.out[z], (size_t)r * N + col, acc[mr][nc][e] + bv);
      }
    }
  }
}

// ---------------- fused QKV projection + MFMA flash attention ----------------
__global__ __launch_bounds__(256) void k_fattn(const bf16* __restrict__ y,
                                               const short* __restrict__ wTl,
                                               const float* __restrict__ bq,
                                               const float* __restrict__ bk,
                                               const float* __restrict__ bv,
                                               const float* __restrict__ gab,
                                               bf16* __restrict__ ctx) {
  __shared__ short Ql[144 * 40];
  __shared__ short Kl[144 * 40];
  __shared__ short Vt[32 * 168];
  __shared__ short U[15360];     // phase1: Ay[144*64]=9216 + Bw[96*64]=6144; phase2: Pc
  __shared__ float bqa[32], bka[32], bva[32];
  short* Ay = U;
  short* Bw = U + 9216;
  short* Pc = U;
  int bh = blockIdx.x;
  int b = bh / NH, hh = bh % NH;
  int t = threadIdx.x;
  int lane = t & 63, w = t >> 6;

  for (int idx = t; idx < 32 * 39; idx += 256) {
    int d = idx / 39, kk = 129 + (idx % 39);
    Vt[d * 168 + kk] = 0;
  }
  if (t < 32) {
    bqa[t] = bq[hh * 32 + t];
    bka[t] = bk[hh * 32 + t];
    bva[t] = bv[hh * 32 + t];
  }

  // ---- phase 1: QKV via MFMA over 12 K-tiles of 64 ----
  f32x4 acc[3][3][2];
#pragma unroll
  for (int i = 0; i < 3; i++)
#pragma unroll
    for (int m = 0; m < 3; m++)
#pragma unroll
      for (int nt = 0; nt < 2; nt++) acc[i][m][nt] = (f32x4){0.f, 0.f, 0.f, 0.f};

  int lrow8 = lane >> 3;
  int lseg8 = (lane & 7) ^ lrow8;
  int fr = lane & 15, q = lane >> 4;
  const short* ybase = (const short*)y + (size_t)(b * SQ) * DM;

  for (int kt = 0; kt < 12; ++kt) {
    int k0 = kt << 6;
    __syncthreads();
    for (int i = w; i < 9; i += 4) {
      gload16(ybase + (size_t)(i * 16 + lrow8) * DM + k0 + lseg8 * 8, &Ay[(i * 16) * 64]);
      gload16(ybase + (size_t)(i * 16 + 8 + lrow8) * DM + k0 + lseg8 * 8,
              &Ay[(i * 16 + 8) * 64]);
    }
    for (int i = w; i < 6; i += 4) {
      int m = i >> 1, half = i & 1;
      const short* wb = wTl + (size_t)m * DD2C + (size_t)(hh * 32 + half * 16) * DM + k0;
      gload16(wb + (size_t)lrow8 * DM + lseg8 * 8, &Bw[(m * 32 + half * 16) * 64]);
      gload16(wb + (size_t)(8 + lrow8) * DM + lseg8 * 8, &Bw[(m * 32 + half * 16 + 8) * 64]);
    }
    __syncthreads();
#pragma unroll
    for (int kk = 0; kk < 2; kk++) {
      int sg = ((q + kk * 4) ^ (fr & 7)) * 8;
#pragma unroll
      for (int i = 0; i < 3; i++) {
        int mt = w + 4 * i;
        if (mt > 8) break;
        short8 af = *(const short8*)&Ay[(mt * 16 + fr) * 64 + sg];
#pragma unroll
        for (int m = 0; m < 3; m++)
#pragma unroll
          for (int nt = 0; nt < 2; nt++) {
            short8 bf = *(const short8*)&Bw[(m * 32 + nt * 16 + fr) * 64 + sg];
            acc[i][m][nt] = __builtin_amdgcn_mfma_f32_16x16x32_bf16(af, bf, acc[i][m][nt], 0, 0, 0);
          }
      }
    }
  }
  __syncthreads();
#pragma unroll
  for (int i = 0; i < 3; i++) {
    int mt = w + 4 * i;
    if (mt > 8) break;
#pragma unroll
    for (int nt = 0; nt < 2; nt++) {
      int coll = nt * 16 + fr;
      float bqv = bqa[coll], bkv = bka[coll], bvv = bva[coll];
#pragma unroll
      for (int e = 0; e < 4; e++) {
        int row = mt * 16 + q * 4 + e;
        Ql[row * 40 + coll] = f2bs(acc[i][0][nt][e] + bqv);
        Kl[row * 40 + coll] = f2bs(acc[i][1][nt][e] + bkv);
        if (row < 129) Vt[coll * 168 + row] = f2bs(acc[i][2][nt][e] + bvv);
      }
    }
  }
  __syncthreads();

  // ---- phase 2: QK^T -> softmax -> PV ----
  int c16 = lane & 15, q4 = lane >> 4;
  const float scale = 0.17677669529663689f;  // 1/sqrt(32)
  const float* gabp = gab + (((size_t)(b * NH + hh)) * SQ) * SQ;

  for (int mt = w; mt < 9; mt += 4) {
    f32x4 sc[9];
    short8 aq = *(const short8*)&Ql[(mt * 16 + c16) * 40 + q4 * 8];
#pragma unroll
    for (int nt = 0; nt < 9; nt++) {
      short8 bk8 = *(const short8*)&Kl[(nt * 16 + c16) * 40 + q4 * 8];
      f32x4 zz = {0.f, 0.f, 0.f, 0.f};
      sc[nt] = __builtin_amdgcn_mfma_f32_16x16x32_bf16(aq, bk8, zz, 0, 0, 0);
    }
#pragma unroll
    for (int e = 0; e < 4; e++) {
      int row = mt * 16 + q4 * 4 + e;
      int rr = row < 129 ? row : 128;
      const float* grow = gabp + (size_t)rr * SQ;
      float mloc = -1e30f;
#pragma unroll
      for (int nt = 0; nt < 9; nt++) {
        int col = nt * 16 + c16;
        float s = (col < 129) ? (sc[nt][e] * scale + grow[col]) : -1e30f;
        sc[nt][e] = s;
        mloc = fmaxf(mloc, s);
      }
#pragma unroll
      for (int o = 1; o < 16; o <<= 1) mloc = fmaxf(mloc, __shfl_xor(mloc, o));
      float sum = 0.f;
#pragma unroll
      for (int nt = 0; nt < 9; nt++) {
        float pp = __expf(sc[nt][e] - mloc);
        sc[nt][e] = pp;
        sum += pp;
      }
#pragma unroll
      for (int o = 1; o < 16; o <<= 1) sum += __shfl_xor(sum, o);
      float inv = 1.f / sum;
#pragma unroll
      for (int nt = 0; nt < 9; nt++) sc[nt][e] *= inv;
    }
    f32x4 oacc0 = {0.f, 0.f, 0.f, 0.f}, oacc1 = {0.f, 0.f, 0.f, 0.f};
#pragma unroll
    for (int c = 0; c < 5; c++) {
#pragma unroll
      for (int u = 0; u < 2; u++) {
        int nt = c * 2 + u;
        if (nt < 9) {
#pragma unroll
          for (int e = 0; e < 4; e++)
            Pc[(mt * 16 + q4 * 4 + e) * 40 + u * 16 + c16] = f2bs(sc[nt][e]);
        } else {
#pragma unroll
          for (int e = 0; e < 4; e++)
            Pc[(mt * 16 + q4 * 4 + e) * 40 + u * 16 + c16] = 0;
        }
      }
      asm volatile("s_waitcnt lgkmcnt(0)" ::: "memory");
      __builtin_amdgcn_sched_barrier(0);
      short8 ap = *(const short8*)&Pc[(mt * 16 + c16) * 40 + q4 * 8];
      short8 bv0 = *(const short8*)&Vt[(c16) * 168 + c * 32 + q4 * 8];
      short8 bv1 = *(const short8*)&Vt[(16 + c16) * 168 + c * 32 + q4 * 8];
      oacc0 = __builtin_amdgcn_mfma_f32_16x16x32_bf16(ap, bv0, oacc0, 0, 0, 0);
      oacc1 = __builtin_amdgcn_mfma_f32_16x16x32_bf16(ap, bv1, oacc1, 0, 0, 0);
    }
#pragma unroll
    for (int e = 0; e < 4; e++) {
      int row = mt * 16 + q4 * 4 + e;
      if (row < 129) {
        size_t obase = ((size_t)(b * SQ + row)) * DM + hh * 32;
        ctx[obase + c16] = __float2bfloat16(oacc0[e]);
        ctx[obase + 16 + c16] = __float2bfloat16(oacc1[e]);
      }
    }
  }
}

// ---------------- final: h_row0 + p0 + p1 + cbias -> LN -> project ----------------
__global__ void k_final_add2(const float* __restrict__ h, const float* __restrict__ p0,
                             const float* __restrict__ p1, const float* __restrict__ cb,
                             const float* __restrict__ g, const float* __restrict__ bb,
                             const float* __restrict__ ow, const float* __restrict__ ob,
                             float* __restrict__ out) {
  int b = blockIdx.x;
  int t = threadIdx.x, lane = t & 63, wid = t >> 6;
  __shared__ float red[8];
  __shared__ float yn[768];
  size_t base = (size_t)(b * SQ) * DM;
  float v0 = h[base + t] + p0[base + t] + p1[base + t] + cb[t];
  float v1 = h[base + t + 256] + p0[base + t + 256] + p1[base + t + 256] + cb[t + 256];
  float v2 = h[base + t + 512] + p0[base + t + 512] + p1[base + t + 512] + cb[t + 512];
  float s = v0 + v1 + v2;
#pragma unroll
  for (int o = 32; o > 0; o >>= 1) s += __shfl_xor(s, o);
  if (lane == 0) red[wid] = s;
  __syncthreads();
  float mean = (red[0] + red[1] + red[2] + red[3]) * (1.f / 768.f);
  float d0 = v0 - mean, d1 = v1 - mean, d2 = v2 - mean;
  float q = d0 * d0 + d1 * d1 + d2 * d2;
#pragma unroll
  for (int o = 32; o > 0; o >>= 1) q += __shfl_xor(q, o);
  if (lane == 0) red[4 + wid] = q;
  __syncthreads();
  float var = (red[4] + red[5] + red[6] + red[7]) * (1.f / 768.f);
  float rstd = rsqrtf(var + 1e-5f);
  yn[t] = d0 * rstd * g[t] + bb[t];
  yn[t + 256] = d1 * rstd * g[t + 256] + bb[t + 256];
  yn[t + 512] = d2 * rstd * g[t + 512] + bb[t + 512];
  __syncthreads();
  if (t < 128) {
    float acc = ob[t];
    for (int d = 0; d < 768; d++) acc += yn[d] * ow[d * 128 + t];
    out[b * 128 + t] = acc;
  }
}

extern "C" void kernel_launch(void* const* d_in, const int* in_sizes, int n_in,
                              void* d_out, int out_size, void* d_ws, size_t ws_size,
                              hipStream_t stream) {
  (void)in_sizes; (void)n_in; (void)out_size;
  const int* x     = (const int*)d_in[0];
  const int* ind   = (const int*)d_in[1];
  const int* outd  = (const int*)d_in[2];
  const int* spos  = (const int*)d_in[3];
  const int* eidx  = (const int*)d_in[4];
  const float* ab   = (const float*)d_in[5];
  const float* atom = (const float*)d_in[6];
  const float* ide  = (const float*)d_in[7];
  const float* ode  = (const float*)d_in[8];
  const float* gtok = (const float*)d_in[9];
  const float* eemb = (const float*)d_in[10];
  const float* edemb= (const float*)d_in[11];
  const float* semb = (const float*)d_in[12];
  const float* virt = (const float*)d_in[13];
  const float* ln1g = (const float*)d_in[14];
  const float* ln1b = (const float*)d_in[15];
  const float* wq  = (const float*)d_in[16];
  const float* bq   = (const float*)d_in[17];
  const float* wk  = (const float*)d_in[18];
  const float* bk   = (const float*)d_in[19];
  const float* wv  = (const float*)d_in[20];
  const float* bv   = (const float*)d_in[21];
  const float* wo  = (const float*)d_in[22];
  const float* bo   = (const float*)d_in[23];
  const float* ln2g = (const float*)d_in[24];
  const float* ln2b = (const float*)d_in[25];
  const float* w1  = (const float*)d_in[26];
  const float* b1   = (const float*)d_in[27];
  const float* w2  = (const float*)d_in[28];
  const float* b2   = (const float*)d_in[29];
  const float* fg   = (const float*)d_in[30];
  const float* fb   = (const float*)d_in[31];
  const float* ow   = (const float*)d_in[32];
  const float* ob   = (const float*)d_in[33];
  float* out = (float*)d_out;

  const int DD2 = DM * DM;
  const size_t WQKVO = (size_t)DD2;
  const size_t WFF = (size_t)DM * DF;

  char* ws = (char*)d_ws;
  size_t off = 0;
  auto alloc = [&](size_t bytes) -> void* {
    void* p = ws + off;
    off += (bytes + 255) & ~(size_t)255;
    return p;
  };
  float* gab = (float*)alloc((size_t)NB * NH * SQ * SQ * 4);
  float* h   = (float*)alloc((size_t)MROWS * DM * 4);
  bf16* y    = (bf16*)alloc((size_t)MROWS * DM * 2);
  bf16* ctx  = (bf16*)alloc((size_t)MROWS * DM * 2);
  bf16* t1   = (bf16*)alloc((size_t)MROWS * DF * 2);
  float* p0  = (float*)alloc((size_t)MROWS * DM * 4);
  float* p1  = (float*)alloc((size_t)MROWS * DM * 4);

  size_t need_hoist = off + ((size_t)NLAY * 4 * WQKVO + 2 * (size_t)NLAY * WFF) * 2 + (1 << 20);
  bool hoist = ws_size >= need_hoist;
  short* wT  = (short*)alloc((hoist ? (size_t)NLAY * 4 * WQKVO : 4 * WQKVO) * 2);
  short* w1T = (short*)alloc((hoist ? (size_t)NLAY * WFF : WFF) * 2);
  short* w2T = (short*)alloc((hoist ? (size_t)NLAY * WFF : WFF) * 2);

  dim3 blk(256);
  if (hoist) {
    ProArgs pa;
    pa.x = x; pa.ind = ind; pa.outd = outd;
    pa.atom = atom; pa.ide = ide; pa.ode = ode; pa.gtok = gtok;
    pa.ab = ab; pa.virt = virt; pa.g = ln1g; pa.bb = ln1b;
    pa.h = h; pa.y = y; pa.gab = gab;
    pa.spos = spos; pa.eidx = eidx; pa.eemb = eemb; pa.edemb = edemb; pa.semb = semb;
    pa.ta.wq = wq; pa.ta.wk = wk; pa.ta.wv = wv; pa.ta.wo = wo;
    pa.ta.w1 = w1; pa.ta.w2 = w2;
    pa.ta.wT = wT; pa.ta.w1T = w1T; pa.ta.w2T = w2T;
    k_prologue<<<dim3(2048 + MROWS + 20736), blk, 0, stream>>>(pa);
  } else {
    k_nodefeat_ln<<<dim3(MROWS), blk, 0, stream>>>(x, ind, outd, atom, ide, ode, gtok,
                                                   ab, virt, ln1g, ln1b, h, y, gab);
    k_gab_edge<<<dim3(NB * ND * 2), blk, 0, stream>>>(spos, eidx, eemb, edemb, semb, ab, gab);
  }

  for (int l = 0; l < NLAY; l++) {
    if (!hoist) {
      Ptrs4 pq;
      pq.p[0] = wq + (size_t)l * DD2; pq.p[1] = wk + (size_t)l * DD2;
      pq.p[2] = wv + (size_t)l * DD2; pq.p[3] = wo + (size_t)l * DD2;
      k_transpose<4><<<dim3(12, 12, 4), blk, 0, stream>>>(pq, wT, DM, DM, 0);
      Ptrs4 pa2; pa2.p[0] = w1 + (size_t)l * WFF; pa2.p[1] = pa2.p[2] = pa2.p[3] = pa2.p[0];
      k_transpose<1><<<dim3(12, 48, 1), blk, 0, stream>>>(pa2, w1T, DM, DF, 0);
      Ptrs4 pb; pb.p[0] = w2 + (size_t)l * WFF; pb.p[1] = pb.p[2] = pb.p[3] = pb.p[0];
      k_transpose<1><<<dim3(48, 12, 1), blk, 0, stream>>>(pb, w2T, DF, DM, 0);
    }
    const short* wTl  = wT  + (hoist ? (size_t)l * 4 * WQKVO : 0);
    const short* w1Tl = w1T + (hoist ? (size_t)l * WFF : 0);
    const short* w2Tl = w2T + (hoist ? (size_t)l * WFF : 0);

    // fused QKV + attention
    k_fattn<<<dim3(NB * NH), blk, 0, stream>>>(y, wTl, bq + l * DM, bk + l * DM,
                                               bv + l * DM, gab, ctx);

    GemmPtrs go;  // Wo split-K: K=768 -> 2 x 384
    go.bt[0] = wTl + 3 * DD2; go.bt[1] = wTl + 3 * DD2 + 384;
    go.bias[0] = go.bias[1] = nullptr;
    go.out[0] = p0; go.out[1] = p1;
    go.aoff[0] = 0; go.aoff[1] = 384;
    go.bt[2] = go.bt[0]; go.out[2] = p0; go.aoff[2] = 0; go.bias[2] = nullptr;
    k_gemm64<3><<<dim3(33, 6, 2), blk, 0, stream>>>((const short*)ctx, go, MROWS, DM, 384, DM, DM);

    k_ln_add2<<<dim3(MROWS), blk, 0, stream>>>(h, p0, p1, bo + l * DM,
                                               ln2g + l * DM, ln2b + l * DM, y);

    GemmPtrs g1;
    g1.bt[0] = g1.bt[1] = g1.bt[2] = w1Tl;
    g1.bias[0] = g1.bias[1] = g1.bias[2] = b1 + l * DF;
    g1.out[0] = g1.out[1] = g1.out[2] = t1;
    g1.aoff[0] = g1.aoff[1] = g1.aoff[2] = 0;
    k_gemm128<2><<<dim3(17, 24, 1), blk, 0, stream>>>((const short*)y, g1, MROWS, DF, DM, DM, DM);

    GemmPtrs g2;  // FFN2 split-K: K=3072 -> 2 x 1536
    g2.bt[0] = w2Tl; g2.bt[1] = w2Tl + 1536;
    g2.bias[0] = g2.bias[1] = nullptr;
    g2.out[0] = p0; g2.out[1] = p1;
    g2.aoff[0] = 0; g2.aoff[1] = 1536;
    g2.bt[2] = g2.bt[0]; g2.out[2] = p0; g2.aoff[2] = 0; g2.bias[2] = nullptr;
    k_gemm64<3><<<dim3(33, 6, 2), blk, 0, stream>>>((const short*)t1, g2, MROWS, DM, 1536, DF, DF);

    if (l < NLAY - 1) {
      k_ln_add2<<<dim3(MROWS), blk, 0, stream>>>(h, p0, p1, b2 + l * DM,
                                                 ln1g + (l + 1) * DM, ln1b + (l + 1) * DM, y);
    } else {
      k_final_add2<<<dim3(NB), blk, 0, stream>>>(h, p0, p1, b2 + l * DM, fg, fb, ow, ob, out);
    }
  }
}

// Round 14
// 1503.476 us; speedup vs baseline: 1.3709x; 1.0032x over previous
//
#include <hip/hip_runtime.h>
#include <hip/hip_bf16.h>
#include <math.h>

typedef __hip_bfloat16 bf16;
typedef __attribute__((ext_vector_type(8))) short short8;
typedef __attribute__((ext_vector_type(4))) short short4v;
typedef __attribute__((ext_vector_type(4))) float f32x4;

constexpr int NB = 16;     // batch
constexpr int ND = 128;    // nodes N
constexpr int SQ = 129;    // S = N+1
constexpr int NH = 24;     // heads
constexpr int DM = 768;    // model dim
constexpr int DF = 3072;   // ffn dim
constexpr int NLAY = 12;
constexpr int MROWS = NB * SQ;  // 2064
constexpr int DD2C = DM * DM;

__device__ __forceinline__ short f2bs(float f) {
  bf16 h = __float2bfloat16(f);
  return *(short*)&h;
}

__device__ __forceinline__ void gload16(const void* g, void* lds) {
  __builtin_amdgcn_global_load_lds(
      (const __attribute__((address_space(1))) unsigned int*)g,
      (__attribute__((address_space(3))) unsigned int*)lds, 16, 0, 0);
}

// ================= device bodies (shared by fused prologue + fallbacks) ======

__device__ __forceinline__ void dev_nodefeat_ln(
    char* smem, int bs, int t,
    const int* x, const int* ind, const int* outd,
    const float* atom, const float* ide, const float* ode, const float* gtok,
    const float* ab, const float* virt, const float* g, const float* bb,
    float* h, bf16* y, float* gab) {
  float* red = (float*)smem;
  int b = bs / SQ, s = bs % SQ;
  int lane = t & 63, wid = t >> 6;
  float vv[3];
  if (s == 0) {
    vv[0] = gtok[t]; vv[1] = gtok[t + 256]; vv[2] = gtok[t + 512];
  } else {
    int n = s - 1;
    const int* xr = x + (b * ND + n) * 9;
    int a0 = xr[0], a1 = xr[1], a2 = xr[2], a3 = xr[3], a4 = xr[4];
    int a5 = xr[5], a6 = xr[6], a7 = xr[7], a8 = xr[8];
    int ii = ind[b * ND + n], oo = outd[b * ND + n];
#pragma unroll
    for (int u = 0; u < 3; u++) {
      int c = t + u * 256;
      float acc = ide[(size_t)ii * DM + c] + ode[(size_t)oo * DM + c];
      acc += atom[(size_t)a0 * DM + c];
      acc += atom[(size_t)a1 * DM + c];
      acc += atom[(size_t)a2 * DM + c];
      acc += atom[(size_t)a3 * DM + c];
      acc += atom[(size_t)a4 * DM + c];
      acc += atom[(size_t)a5 * DM + c];
      acc += atom[(size_t)a6 * DM + c];
      acc += atom[(size_t)a7 * DM + c];
      acc += atom[(size_t)a8 * DM + c];
      vv[u] = acc;
    }
  }
  float* hrow = h + (size_t)bs * DM;
  hrow[t] = vv[0]; hrow[t + 256] = vv[1]; hrow[t + 512] = vv[2];
  float sum = vv[0] + vv[1] + vv[2];
#pragma unroll
  for (int o = 32; o > 0; o >>= 1) sum += __shfl_xor(sum, o);
  if (lane == 0) red[wid] = sum;
  __syncthreads();
  float mean = (red[0] + red[1] + red[2] + red[3]) * (1.f / 768.f);
  float d0 = vv[0] - mean, d1 = vv[1] - mean, d2 = vv[2] - mean;
  float q = d0 * d0 + d1 * d1 + d2 * d2;
#pragma unroll
  for (int o = 32; o > 0; o >>= 1) q += __shfl_xor(q, o);
  if (lane == 0) red[4 + wid] = q;
  __syncthreads();
  float var = (red[4] + red[5] + red[6] + red[7]) * (1.f / 768.f);
  float rstd = rsqrtf(var + 1e-5f);
  bf16* yr = y + (size_t)bs * DM;
  yr[t] = __float2bfloat16(d0 * rstd * g[t] + bb[t]);
  yr[t + 256] = __float2bfloat16(d1 * rstd * g[t + 256] + bb[t + 256]);
  yr[t + 512] = __float2bfloat16(d2 * rstd * g[t + 512] + bb[t + 512]);
  if (bs < NB) {
    int bb2 = bs;
    const int tot = NH * SQ + NH * ND;
    for (int idx = t; idx < tot; idx += 256) {
      if (idx < NH * SQ) {
        int hh = idx / SQ, j = idx % SQ;
        float v = 2.f * ab[((size_t)bb2 * SQ + 0) * SQ + j] + virt[hh];
        gab[(((size_t)bb2 * NH + hh) * SQ + 0) * SQ + j] = v;
      } else {
        int r = idx - NH * SQ;
        int hh = r / ND, i = r % ND + 1;
        float v = 2.f * ab[((size_t)bb2 * SQ + i) * SQ + 0] + virt[hh];
        gab[(((size_t)bb2 * NH + hh) * SQ + i) * SQ + 0] = v;
      }
    }
  }
}

// LDS union (32352 B):
//   [0,6240):      eidxs (early, 3840B) -> ot[24][65] (late, after extra barrier)
//   [6240,23648):  ei2 [64][136] shorts; per-row tail [128,136) holds metadata
//                  (rinv,a2,sp) -- never touched by build/pads/MFMA reads
//   [23648,32352): edT [32][136] shorts
__device__ __forceinline__ void dev_gab_edge(
    char* smem, int bi, int t,
    const int* spos, const int* eidx, const float* eemb, const float* edemb,
    const float* semb, const float* ab, float* gab) {
  int* eidxs = (int*)smem;                       // early life
  float* ot = (float*)smem;                      // late life [24][65]
  short* ei2 = (short*)(smem + 6240);
  short* edT = (short*)(smem + 23648);
  int half = bi & 1;
  int i = (bi >> 1) & 127;
  int b = bi >> 8;
  int j0 = half * 64;
  const size_t rowbase = ((size_t)(b * ND + i)) * ND + j0;

  const int* esrc = eidx + rowbase * 15;
  for (int idx = t; idx < 960; idx += 256) eidxs[idx] = esrc[idx];
  for (int u = t; u < 720; u += 256) {
    int dh = u / 6, kq = u % 6;
    f32x4 v = *(const f32x4*)&edemb[dh * 24 + kq * 4];
    edT[(kq * 4 + 0) * 136 + dh] = f2bs(v[0]);
    edT[(kq * 4 + 1) * 136 + dh] = f2bs(v[1]);
    edT[(kq * 4 + 2) * 136 + dh] = f2bs(v[2]);
    edT[(kq * 4 + 3) * 136 + dh] = f2bs(v[3]);
  }
  for (int u = t; u < 1472; u += 256) {
    int k, dh;
    if (u < 384) { k = u >> 4; dh = 120 + (u & 15); }
    else { int v = u - 384; k = 24 + v / 136; dh = v % 136; }
    edT[k * 136 + dh] = 0;
  }
  if (t < 64) {
    int j = t;
    int sp = spos[rowbase + j];
    int spc = (sp == 0) ? 1 : sp;
    spc = (spc > 1) ? spc - 1 : spc;
    if (spc > 5) spc = 5;
    float* mp = (float*)(smem + 6240 + j * 272 + 256);
    mp[0] = 1.f / (float)spc;
    mp[1] = 2.f * ab[((size_t)b * SQ + (i + 1)) * SQ + (j0 + j + 1)];
    ((int*)mp)[2] = sp;
  }
  __syncthreads();

  {
    int j = t & 63, d = t >> 6;
#pragma unroll
    for (int pass = 0; pass < 2; pass++) {
      if (pass == 1) {
        if (t >= 64) break;
        j = t; d = 4;
      }
      const int* ep = &eidxs[j * 15 + d * 3];
      const float* r0 = eemb + (size_t)ep[0] * NH;
      const float* r1 = eemb + (size_t)ep[1] * NH;
      const float* r2 = eemb + (size_t)ep[2] * NH;
#pragma unroll
      for (int hq = 0; hq < 6; hq++) {
        f32x4 s = (*(const f32x4*)&r0[hq * 4] + *(const f32x4*)&r1[hq * 4] +
                   *(const f32x4*)&r2[hq * 4]) * (1.f / 3.f);
        short4v o;
        o[0] = f2bs(s[0]); o[1] = f2bs(s[1]); o[2] = f2bs(s[2]); o[3] = f2bs(s[3]);
        *(short4v*)&ei2[j * 136 + d * 24 + hq * 4] = o;
      }
    }
  }
  for (int idx = t; idx < 64 * 8; idx += 256) {
    int j = idx >> 3;
    ei2[j * 136 + 120 + (idx & 7)] = 0;
  }
  __syncthreads();

  int lane = t & 63, w = t >> 6;
  int fr = lane & 15, q = lane >> 4, fo = q * 8;
  f32x4 acc0 = {0.f, 0.f, 0.f, 0.f}, acc1 = {0.f, 0.f, 0.f, 0.f};
#pragma unroll
  for (int kk = 0; kk < 4; kk++) {
    short8 af = *(const short8*)&ei2[(w * 16 + fr) * 136 + kk * 32 + fo];
    short8 b0 = *(const short8*)&edT[(fr) * 136 + kk * 32 + fo];
    short8 b1 = *(const short8*)&edT[(16 + fr) * 136 + kk * 32 + fo];
    acc0 = __builtin_amdgcn_mfma_f32_16x16x32_bf16(af, b0, acc0, 0, 0, 0);
    acc1 = __builtin_amdgcn_mfma_f32_16x16x32_bf16(af, b1, acc1, 0, 0, 0);
  }
  __syncthreads();  // eidxs fully dead; ot may now overwrite region0
#pragma unroll
  for (int e = 0; e < 4; e++) {
    int j = w * 16 + q * 4 + e;
    ot[fr * 65 + j] = acc0[e];
    if (fr < 8) ot[(16 + fr) * 65 + j] = acc1[e];
  }
  __syncthreads();
  size_t obase = (((size_t)b * NH) * SQ + (i + 1)) * SQ + (j0 + 1);
  for (int idx = t; idx < 24 * 64; idx += 256) {
    int k = idx >> 6, j = idx & 63;
    const float* mp = (const float*)(smem + 6240 + j * 272 + 256);
    float v = mp[1] + semb[((const int*)mp)[2] * NH + k] + ot[k * 65 + j] * mp[0];
    gab[obase + (size_t)k * SQ * SQ + j] = v;
  }
}

struct TAll {
  const float* wq; const float* wk; const float* wv; const float* wo;
  const float* w1; const float* w2;
  short* wT; short* w1T; short* w2T;
};

__device__ __forceinline__ void dev_transpose_all(char* smem, int id, int t, TAll p) {
  short* tile = (short*)smem;  // [64][66]
  const float* src; short* d; int R, C, r0, c0;
  if (id < 6912) {
    int l = id / 576, rem = id % 576, mat = rem / 144, tl = rem % 144;
    const float* srcs[4] = {p.wq, p.wk, p.wv, p.wo};
    src = srcs[mat] + (size_t)l * DD2C;
    d = p.wT + ((size_t)l * 4 + mat) * DD2C;
    R = 768; C = 768;
    r0 = (tl / 12) * 64; c0 = (tl % 12) * 64;
  } else if (id < 13824) {
    int id2 = id - 6912;
    int l = id2 / 576, tl = id2 % 576;
    src = p.w1 + (size_t)l * DM * DF;
    d = p.w1T + (size_t)l * DM * DF;
    R = 768; C = 3072;
    r0 = (tl / 48) * 64; c0 = (tl % 48) * 64;
  } else {
    int id2 = id - 13824;
    int l = id2 / 576, tl = id2 % 576;
    src = p.w2 + (size_t)l * DM * DF;
    d = p.w2T + (size_t)l * DM * DF;
    R = 3072; C = 768;
    r0 = (tl / 12) * 64; c0 = (tl % 12) * 64;
  }
  int tr = t >> 4, tc = (t & 15) * 4;
#pragma unroll
  for (int i = 0; i < 4; i++) {
    int r = tr + i * 16;
    f32x4 v = *(const f32x4*)(src + (size_t)(r0 + r) * C + c0 + tc);
    tile[r * 66 + tc + 0] = f2bs(v[0]);
    tile[r * 66 + tc + 1] = f2bs(v[1]);
    tile[r * 66 + tc + 2] = f2bs(v[2]);
    tile[r * 66 + tc + 3] = f2bs(v[3]);
  }
  __syncthreads();
#pragma unroll
  for (int i = 0; i < 4; i++) {
    int rr = tr + i * 16;
    short4v o;
    o[0] = tile[(tc + 0) * 66 + rr];
    o[1] = tile[(tc + 1) * 66 + rr];
    o[2] = tile[(tc + 2) * 66 + rr];
    o[3] = tile[(tc + 3) * 66 + rr];
    *(short4v*)(d + (size_t)(c0 + rr) * R + r0 + tc) = o;
  }
}

// ================= fused prologue (hoist path) =================
struct ProArgs {
  const int* x; const int* ind; const int* outd;
  const float* atom; const float* ide; const float* ode; const float* gtok;
  const float* ab; const float* virt; const float* g; const float* bb;
  float* h; bf16* y; float* gab;
  const int* spos; const int* eidx; const float* eemb; const float* edemb;
  const float* semb;
  TAll ta;
};

__global__ __launch_bounds__(256) void k_prologue(ProArgs a) {
  __shared__ __align__(16) char smem[32352];
  int id = blockIdx.x;
  int t = threadIdx.x;
  if (id < 2048) {
    dev_gab_edge(smem, id, t, a.spos, a.eidx, a.eemb, a.edemb, a.semb, a.ab, a.gab);
  } else if (id < 2048 + MROWS) {
    dev_nodefeat_ln(smem, id - 2048, t, a.x, a.ind, a.outd, a.atom, a.ide, a.ode,
                    a.gtok, a.ab, a.virt, a.g, a.bb, a.h, a.y, a.gab);
  } else {
    dev_transpose_all(smem, id - 2048 - MROWS, t, a.ta);
  }
}

// ---- fallbacks (non-hoist) ----
__global__ void k_nodefeat_ln(const int* x, const int* ind, const int* outd,
                              const float* atom, const float* ide, const float* ode,
                              const float* gtok, const float* ab, const float* virt,
                              const float* g, const float* bb,
                              float* h, bf16* y, float* gab) {
  __shared__ __align__(16) char smem[64];
  dev_nodefeat_ln(smem, blockIdx.x, threadIdx.x, x, ind, outd, atom, ide, ode, gtok,
                  ab, virt, g, bb, h, y, gab);
}

__global__ __launch_bounds__(256) void k_gab_edge(
    const int* spos, const int* eidx, const float* eemb, const float* edemb,
    const float* semb, const float* ab, float* gab) {
  __shared__ __align__(16) char smem[32352];
  dev_gab_edge(smem, blockIdx.x, threadIdx.x, spos, eidx, eemb, edemb, semb, ab, gab);
}

struct Ptrs4 { const float* p[4]; };

template <int NW>
__global__ void k_transpose(Ptrs4 ps, short* __restrict__ dst, int R, int C,
                            size_t sstride) {
  __shared__ short tile[64][66];
  int z = blockIdx.z;
  const float* src = ps.p[z % NW] + (size_t)(z / NW) * sstride;
  short* d = dst + (size_t)z * (size_t)R * C;
  int r0 = blockIdx.x * 64, c0 = blockIdx.y * 64;
  int t = threadIdx.x;
  int tr = t >> 4, tc = (t & 15) * 4;
#pragma unroll
  for (int i = 0; i < 4; i++) {
    int r = tr + i * 16;
    f32x4 v = *(const f32x4*)(src + (size_t)(r0 + r) * C + c0 + tc);
    tile[r][tc + 0] = f2bs(v[0]);
    tile[r][tc + 1] = f2bs(v[1]);
    tile[r][tc + 2] = f2bs(v[2]);
    tile[r][tc + 3] = f2bs(v[3]);
  }
  __syncthreads();
#pragma unroll
  for (int i = 0; i < 4; i++) {
    int rr = tr + i * 16;
    short4v o;
    o[0] = tile[tc + 0][rr];
    o[1] = tile[tc + 1][rr];
    o[2] = tile[tc + 2][rr];
    o[3] = tile[tc + 3][rr];
    *(short4v*)(d + (size_t)(c0 + rr) * R + r0 + tc) = o;
  }
}

// ---------------- fused: h += p0+p1+cbias; y = LN(h) ----------------
__global__ void k_ln_add2(float* __restrict__ h, const float* __restrict__ p0,
                          const float* __restrict__ p1, const float* __restrict__ cb,
                          const float* __restrict__ g, const float* __restrict__ bb,
                          bf16* __restrict__ y) {
  int r = blockIdx.x;
  int t = threadIdx.x, lane = t & 63, wid = t >> 6;
  __shared__ float red[8];
  size_t base = (size_t)r * DM;
  float v0 = h[base + t] + p0[base + t] + p1[base + t] + cb[t];
  float v1 = h[base + t + 256] + p0[base + t + 256] + p1[base + t + 256] + cb[t + 256];
  float v2 = h[base + t + 512] + p0[base + t + 512] + p1[base + t + 512] + cb[t + 512];
  h[base + t] = v0;
  h[base + t + 256] = v1;
  h[base + t + 512] = v2;
  float s = v0 + v1 + v2;
#pragma unroll
  for (int o = 32; o > 0; o >>= 1) s += __shfl_xor(s, o);
  if (lane == 0) red[wid] = s;
  __syncthreads();
  float mean = (red[0] + red[1] + red[2] + red[3]) * (1.f / 768.f);
  float d0 = v0 - mean, d1 = v1 - mean, d2 = v2 - mean;
  float q = d0 * d0 + d1 * d1 + d2 * d2;
#pragma unroll
  for (int o = 32; o > 0; o >>= 1) q += __shfl_xor(q, o);
  if (lane == 0) red[4 + wid] = q;
  __syncthreads();
  float var = (red[4] + red[5] + red[6] + red[7]) * (1.f / 768.f);
  float rstd = rsqrtf(var + 1e-5f);
  bf16* yr = y + base;
  yr[t] = __float2bfloat16(d0 * rstd * g[t] + bb[t]);
  yr[t + 256] = __float2bfloat16(d1 * rstd * g[t + 256] + bb[t + 256]);
  yr[t + 512] = __float2bfloat16(d2 * rstd * g[t + 512] + bb[t + 512]);
}

// ---------------- GEMM common ----------------
// MODE 2: GELU->bf16; MODE 3: raw fp32
struct GemmPtrs {
  const short* bt[3];
  const float* bias[3];
  void* out[3];
  int aoff[3];
};

template <int MODE>
__device__ __forceinline__ void gemm_store(void* outp, size_t idx, float v) {
  if (MODE == 3) {
    ((float*)outp)[idx] = v;
  } else {
    float gg = 0.5f * v * (1.f + erff(v * 0.70710678118654752f));
    ((bf16*)outp)[idx] = __float2bfloat16(gg);
  }
}

// 128x128 block, 4 waves x 64x64, BK=64, single-buffer, swizzled. 32KB -> 3/CU.
template <int MODE>
__global__ __launch_bounds__(256, 3) void k_gemm128(const short* __restrict__ A, GemmPtrs p,
                                                    int M, int N, int K, int lda, int ldb) {
  __shared__ short At[128 * 64];
  __shared__ short Bt[128 * 64];
  int z = blockIdx.z;
  const short* BT = p.bt[z];
  const float* bias = p.bias[z];
  A += p.aoff[z];
  int m0 = blockIdx.x * 128, n0 = blockIdx.y * 128;
  int t = threadIdx.x, lane = t & 63, wid = t >> 6;
  int wr = wid >> 1, wc = wid & 1;
  f32x4 acc[4][4];
#pragma unroll
  for (int a = 0; a < 4; a++)
#pragma unroll
    for (int c = 0; c < 4; c++) acc[a][c] = (f32x4){0.f, 0.f, 0.f, 0.f};

  int lrow8 = lane >> 3;
  int lseg = (lane & 7) ^ lrow8;
  const short* gA[4];
  const short* gB[4];
#pragma unroll
  for (int i = 0; i < 4; i++) {
    int ar = m0 + wid * 32 + i * 8 + lrow8;
    if (ar >= M) ar = M - 1;
    gA[i] = A + (size_t)ar * lda + lseg * 8;
    int br = n0 + wid * 32 + i * 8 + lrow8;
    gB[i] = BT + (size_t)br * ldb + lseg * 8;
  }

  const int NIT = K >> 6;
  int fr = lane & 15, q = lane >> 4;
  for (int it = 0; it < NIT; ++it) {
    int k0 = it << 6;
#pragma unroll
    for (int i = 0; i < 4; i++) {
      gload16(gA[i] + k0, &At[(wid * 32 + i * 8) * 64]);
      gload16(gB[i] + k0, &Bt[(wid * 32 + i * 8) * 64]);
    }
    __syncthreads();
#pragma unroll
    for (int kk = 0; kk < 2; kk++) {
      int sg = ((q + kk * 4) ^ (fr & 7)) * 8;
      short8 af[4], bf[4];
#pragma unroll
      for (int mr = 0; mr < 4; mr++)
        af[mr] = *(const short8*)&At[(wr * 64 + mr * 16 + fr) * 64 + sg];
#pragma unroll
      for (int nc = 0; nc < 4; nc++)
        bf[nc] = *(const short8*)&Bt[(wc * 64 + nc * 16 + fr) * 64 + sg];
#pragma unroll
      for (int mr = 0; mr < 4; mr++)
#pragma unroll
        for (int nc = 0; nc < 4; nc++)
          acc[mr][nc] = __builtin_amdgcn_mfma_f32_16x16x32_bf16(af[mr], bf[nc], acc[mr][nc], 0, 0, 0);
    }
    __syncthreads();
  }

  int rsub = q * 4;
#pragma unroll
  for (int nc = 0; nc < 4; nc++) {
    int col = n0 + wc * 64 + nc * 16 + fr;
    float bv = (MODE == 3) ? 0.f : bias[col];
#pragma unroll
    for (int mr = 0; mr < 4; mr++) {
#pragma unroll
      for (int e = 0; e < 4; e++) {
        int r = m0 + wr * 64 + mr * 16 + rsub + e;
        if (r < M) gemm_store<MODE>(p.out[z], (size_t)r * N + col, acc[mr][nc][e] + bv);
      }
    }
  }
}

// 64x128 block, 4 waves x 32x64, BK=64, single-buffer, swizzled. 24KB -> 4/CU.
template <int MODE>
__global__ __launch_bounds__(256, 4) void k_gemm64(const short* __restrict__ A, GemmPtrs p,
                                                   int M, int N, int K, int lda, int ldb) {
  __shared__ short At[64 * 64];
  __shared__ short Bt[128 * 64];
  int z = blockIdx.z;
  const short* BT = p.bt[z];
  const float* bias = p.bias[z];
  A += p.aoff[z];
  int m0 = blockIdx.x * 64, n0 = blockIdx.y * 128;
  int t = threadIdx.x, lane = t & 63, wid = t >> 6;
  int wr = wid >> 1, wc = wid & 1;
  f32x4 acc[2][4];
#pragma unroll
  for (int a = 0; a < 2; a++)
#pragma unroll
    for (int c = 0; c < 4; c++) acc[a][c] = (f32x4){0.f, 0.f, 0.f, 0.f};

  int lrow8 = lane >> 3;
  int lseg = (lane & 7) ^ lrow8;
  const short* gA[2];
  const short* gB[4];
#pragma unroll
  for (int i = 0; i < 2; i++) {
    int ar = m0 + wid * 16 + i * 8 + lrow8;
    if (ar >= M) ar = M - 1;
    gA[i] = A + (size_t)ar * lda + lseg * 8;
  }
#pragma unroll
  for (int i = 0; i < 4; i++) {
    int br = n0 + wid * 32 + i * 8 + lrow8;
    gB[i] = BT + (size_t)br * ldb + lseg * 8;
  }

  const int NIT = K >> 6;
  int fr = lane & 15, q = lane >> 4;
  for (int it = 0; it < NIT; ++it) {
    int k0 = it << 6;
#pragma unroll
    for (int i = 0; i < 2; i++) gload16(gA[i] + k0, &At[(wid * 16 + i * 8) * 64]);
#pragma unroll
    for (int i = 0; i < 4; i++) gload16(gB[i] + k0, &Bt[(wid * 32 + i * 8) * 64]);
    __syncthreads();
#pragma unroll
    for (int kk = 0; kk < 2; kk++) {
      int sg = ((q + kk * 4) ^ (fr & 7)) * 8;
      short8 af[2], bf[4];
#pragma unroll
      for (int mr = 0; mr < 2; mr++)
        af[mr] = *(const short8*)&At[(wr * 32 + mr * 16 + fr) * 64 + sg];
#pragma unroll
      for (int nc = 0; nc < 4; nc++)
        bf[nc] = *(const short8*)&Bt[(wc * 64 + nc * 16 + fr) * 64 + sg];
#pragma unroll
      for (int mr = 0; mr < 2; mr++)
#pragma unroll
        for (int nc = 0; nc < 4; nc++)
          acc[mr][nc] = __builtin_amdgcn_mfma_f32_16x16x32_bf16(af[mr], bf[nc], acc[mr][nc], 0, 0, 0);
    }
    __syncthreads();
  }

  int rsub = q * 4;
#pragma unroll
  for (int nc = 0; nc < 4; nc++) {
    int col = n0 + wc * 64 + nc * 16 + fr;
    float bv = (MODE == 3) ? 0.f : bias[col];
#pragma unroll
    for (int mr = 0; mr < 2; mr++) {
#pragma unroll
      for (int e = 0; e < 4; e++) {
        int r = m0 + wr * 32 + mr * 16 + rsub + e;
        if (r < M) gemm_store<MODE>(p.out[z], (size_t)r * N + col, acc[mr][nc][e] + bv);
      }
    }
  }
}

// ---------------- fused QKV projection + MFMA flash attention ----------------
__global__ __launch_bounds__(256) void k_fattn(const bf16* __restrict__ y,
                                               const short* __restrict__ wTl,
                                               const float* __restrict__ bq,
                                               const float* __restrict__ bk,
                                               const float* __restrict__ bv,
                                               const float* __restrict__ gab,
                                               bf16* __restrict__ ctx) {
  __shared__ short Ql[144 * 40];
  __shared__ short Kl[144 * 40];
  __shared__ short Vt[32 * 168];
  __shared__ short U[15360];     // phase1: Ay[144*64]=9216 + Bw[96*64]=6144; phase2: Pc
  __shared__ float bqa[32], bka[32], bva[32];
  short* Ay = U;
  short* Bw = U + 9216;
  short* Pc = U;
  int bh = blockIdx.x;
  int b = bh / NH, hh = bh % NH;
  int t = threadIdx.x;
  int lane = t & 63, w = t >> 6;

  for (int idx = t; idx < 32 * 39; idx += 256) {
    int d = idx / 39, kk = 129 + (idx % 39);
    Vt[d * 168 + kk] = 0;
  }
  if (t < 32) {
    bqa[t] = bq[hh * 32 + t];
    bka[t] = bk[hh * 32 + t];
    bva[t] = bv[hh * 32 + t];
  }

  // ---- phase 1: QKV via MFMA over 12 K-tiles of 64 ----
  f32x4 acc[3][3][2];
#pragma unroll
  for (int i = 0; i < 3; i++)
#pragma unroll
    for (int m = 0; m < 3; m++)
#pragma unroll
      for (int nt = 0; nt < 2; nt++) acc[i][m][nt] = (f32x4){0.f, 0.f, 0.f, 0.f};

  int lrow8 = lane >> 3;
  int lseg8 = (lane & 7) ^ lrow8;
  int fr = lane & 15, q = lane >> 4;
  const short* ybase = (const short*)y + (size_t)(b * SQ) * DM;

  for (int kt = 0; kt < 12; ++kt) {
    int k0 = kt << 6;
    __syncthreads();
    for (int i = w; i < 9; i += 4) {
      gload16(ybase + (size_t)(i * 16 + lrow8) * DM + k0 + lseg8 * 8, &Ay[(i * 16) * 64]);
      gload16(ybase + (size_t)(i * 16 + 8 + lrow8) * DM + k0 + lseg8 * 8,
              &Ay[(i * 16 + 8) * 64]);
    }
    for (int i = w; i < 6; i += 4) {
      int m = i >> 1, half = i & 1;
      const short* wb = wTl + (size_t)m * DD2C + (size_t)(hh * 32 + half * 16) * DM + k0;
      gload16(wb + (size_t)lrow8 * DM + lseg8 * 8, &Bw[(m * 32 + half * 16) * 64]);
      gload16(wb + (size_t)(8 + lrow8) * DM + lseg8 * 8, &Bw[(m * 32 + half * 16 + 8) * 64]);
    }
    __syncthreads();
#pragma unroll
    for (int kk = 0; kk < 2; kk++) {
      int sg = ((q + kk * 4) ^ (fr & 7)) * 8;
#pragma unroll
      for (int i = 0; i < 3; i++) {
        int mt = w + 4 * i;
        if (mt > 8) break;
        short8 af = *(const short8*)&Ay[(mt * 16 + fr) * 64 + sg];
#pragma unroll
        for (int m = 0; m < 3; m++)
#pragma unroll
          for (int nt = 0; nt < 2; nt++) {
            short8 bf = *(const short8*)&Bw[(m * 32 + nt * 16 + fr) * 64 + sg];
            acc[i][m][nt] = __builtin_amdgcn_mfma_f32_16x16x32_bf16(af, bf, acc[i][m][nt], 0, 0, 0);
          }
      }
    }
  }
  __syncthreads();
#pragma unroll
  for (int i = 0; i < 3; i++) {
    int mt = w + 4 * i;
    if (mt > 8) break;
#pragma unroll
    for (int nt = 0; nt < 2; nt++) {
      int coll = nt * 16 + fr;
      float bqv = bqa[coll], bkv = bka[coll], bvv = bva[coll];
#pragma unroll
      for (int e = 0; e < 4; e++) {
        int row = mt * 16 + q * 4 + e;
        Ql[row * 40 + coll] = f2bs(acc[i][0][nt][e] + bqv);
        Kl[row * 40 + coll] = f2bs(acc[i][1][nt][e] + bkv);
        if (row < 129) Vt[coll * 168 + row] = f2bs(acc[i][2][nt][e] + bvv);
      }
    }
  }
  __syncthreads();

  // ---- phase 2: QK^T -> softmax -> PV ----
  int c16 = lane & 15, q4 = lane >> 4;
  const float scale = 0.17677669529663689f;  // 1/sqrt(32)
  const float* gabp = gab + (((size_t)(b * NH + hh)) * SQ) * SQ;

  for (int mt = w; mt < 9; mt += 4) {
    f32x4 sc[9];
    short8 aq = *(const short8*)&Ql[(mt * 16 + c16) * 40 + q4 * 8];
#pragma unroll
    for (int nt = 0; nt < 9; nt++) {
      short8 bk8 = *(const short8*)&Kl[(nt * 16 + c16) * 40 + q4 * 8];
      f32x4 zz = {0.f, 0.f, 0.f, 0.f};
      sc[nt] = __builtin_amdgcn_mfma_f32_16x16x32_bf16(aq, bk8, zz, 0, 0, 0);
    }
#pragma unroll
    for (int e = 0; e < 4; e++) {
      int row = mt * 16 + q4 * 4 + e;
      int rr = row < 129 ? row : 128;
      const float* grow = gabp + (size_t)rr * SQ;
      float mloc = -1e30f;
#pragma unroll
      for (int nt = 0; nt < 9; nt++) {
        int col = nt * 16 + c16;
        float s = (col < 129) ? (sc[nt][e] * scale + grow[col]) : -1e30f;
        sc[nt][e] = s;
        mloc = fmaxf(mloc, s);
      }
#pragma unroll
      for (int o = 1; o < 16; o <<= 1) mloc = fmaxf(mloc, __shfl_xor(mloc, o));
      float sum = 0.f;
#pragma unroll
      for (int nt = 0; nt < 9; nt++) {
        float pp = __expf(sc[nt][e] - mloc);
        sc[nt][e] = pp;
        sum += pp;
      }
#pragma unroll
      for (int o = 1; o < 16; o <<= 1) sum += __shfl_xor(sum, o);
      float inv = 1.f / sum;
#pragma unroll
      for (int nt = 0; nt < 9; nt++) sc[nt][e] *= inv;
    }
    f32x4 oacc0 = {0.f, 0.f, 0.f, 0.f}, oacc1 = {0.f, 0.f, 0.f, 0.f};
#pragma unroll
    for (int c = 0; c < 5; c++) {
#pragma unroll
      for (int u = 0; u < 2; u++) {
        int nt = c * 2 + u;
        if (nt < 9) {
#pragma unroll
          for (int e = 0; e < 4; e++)
            Pc[(mt * 16 + q4 * 4 + e) * 40 + u * 16 + c16] = f2bs(sc[nt][e]);
        } else {
#pragma unroll
          for (int e = 0; e < 4; e++)
            Pc[(mt * 16 + q4 * 4 + e) * 40 + u * 16 + c16] = 0;
        }
      }
      asm volatile("s_waitcnt lgkmcnt(0)" ::: "memory");
      __builtin_amdgcn_sched_barrier(0);
      short8 ap = *(const short8*)&Pc[(mt * 16 + c16) * 40 + q4 * 8];
      short8 bv0 = *(const short8*)&Vt[(c16) * 168 + c * 32 + q4 * 8];
      short8 bv1 = *(const short8*)&Vt[(16 + c16) * 168 + c * 32 + q4 * 8];
      oacc0 = __builtin_amdgcn_mfma_f32_16x16x32_bf16(ap, bv0, oacc0, 0, 0, 0);
      oacc1 = __builtin_amdgcn_mfma_f32_16x16x32_bf16(ap, bv1, oacc1, 0, 0, 0);
    }
#pragma unroll
    for (int e = 0; e < 4; e++) {
      int row = mt * 16 + q4 * 4 + e;
      if (row < 129) {
        size_t obase = ((size_t)(b * SQ + row)) * DM + hh * 32;
        ctx[obase + c16] = __float2bfloat16(oacc0[e]);
        ctx[obase + 16 + c16] = __float2bfloat16(oacc1[e]);
      }
    }
  }
}

// ---------------- final: h_row0 + p0 + p1 + cbias -> LN -> project ----------------
__global__ void k_final_add2(const float* __restrict__ h, const float* __restrict__ p0,
                             const float* __restrict__ p1, const float* __restrict__ cb,
                             const float* __restrict__ g, const float* __restrict__ bb,
                             const float* __restrict__ ow, const float* __restrict__ ob,
                             float* __restrict__ out) {
  int b = blockIdx.x;
  int t = threadIdx.x, lane = t & 63, wid = t >> 6;
  __shared__ float red[8];
  __shared__ float yn[768];
  size_t base = (size_t)(b * SQ) * DM;
  float v0 = h[base + t] + p0[base + t] + p1[base + t] + cb[t];
  float v1 = h[base + t + 256] + p0[base + t + 256] + p1[base + t + 256] + cb[t + 256];
  float v2 = h[base + t + 512] + p0[base + t + 512] + p1[base + t + 512] + cb[t + 512];
  float s = v0 + v1 + v2;
#pragma unroll
  for (int o = 32; o > 0; o >>= 1) s += __shfl_xor(s, o);
  if (lane == 0) red[wid] = s;
  __syncthreads();
  float mean = (red[0] + red[1] + red[2] + red[3]) * (1.f / 768.f);
  float d0 = v0 - mean, d1 = v1 - mean, d2 = v2 - mean;
  float q = d0 * d0 + d1 * d1 + d2 * d2;
#pragma unroll
  for (int o = 32; o > 0; o >>= 1) q += __shfl_xor(q, o);
  if (lane == 0) red[4 + wid] = q;
  __syncthreads();
  float var = (red[4] + red[5] + red[6] + red[7]) * (1.f / 768.f);
  float rstd = rsqrtf(var + 1e-5f);
  yn[t] = d0 * rstd * g[t] + bb[t];
  yn[t + 256] = d1 * rstd * g[t + 256] + bb[t + 256];
  yn[t + 512] = d2 * rstd * g[t + 512] + bb[t + 512];
  __syncthreads();
  if (t < 128) {
    float acc = ob[t];
    for (int d = 0; d < 768; d++) acc += yn[d] * ow[d * 128 + t];
    out[b * 128 + t] = acc;
  }
}

extern "C" void kernel_launch(void* const* d_in, const int* in_sizes, int n_in,
                              void* d_out, int out_size, void* d_ws, size_t ws_size,
                              hipStream_t stream) {
  (void)in_sizes; (void)n_in; (void)out_size;
  const int* x     = (const int*)d_in[0];
  const int* ind   = (const int*)d_in[1];
  const int* outd  = (const int*)d_in[2];
  const int* spos  = (const int*)d_in[3];
  const int* eidx  = (const int*)d_in[4];
  const float* ab   = (const float*)d_in[5];
  const float* atom = (const float*)d_in[6];
  const float* ide  = (const float*)d_in[7];
  const float* ode  = (const float*)d_in[8];
  const float* gtok = (const float*)d_in[9];
  const float* eemb = (const float*)d_in[10];
  const float* edemb= (const float*)d_in[11];
  const float* semb = (const float*)d_in[12];
  const float* virt = (const float*)d_in[13];
  const float* ln1g = (const float*)d_in[14];
  const float* ln1b = (const float*)d_in[15];
  const float* wq  = (const float*)d_in[16];
  const float* bq   = (const float*)d_in[17];
  const float* wk  = (const float*)d_in[18];
  const float* bk   = (const float*)d_in[19];
  const float* wv  = (const float*)d_in[20];
  const float* bv   = (const float*)d_in[21];
  const float* wo  = (const float*)d_in[22];
  const float* bo   = (const float*)d_in[23];
  const float* ln2g = (const float*)d_in[24];
  const float* ln2b = (const float*)d_in[25];
  const float* w1  = (const float*)d_in[26];
  const float* b1   = (const float*)d_in[27];
  const float* w2  = (const float*)d_in[28];
  const float* b2   = (const float*)d_in[29];
  const float* fg   = (const float*)d_in[30];
  const float* fb   = (const float*)d_in[31];
  const float* ow   = (const float*)d_in[32];
  const float* ob   = (const float*)d_in[33];
  float* out = (float*)d_out;

  const int DD2 = DM * DM;
  const size_t WQKVO = (size_t)DD2;
  const size_t WFF = (size_t)DM * DF;

  char* ws = (char*)d_ws;
  size_t off = 0;
  auto alloc = [&](size_t bytes) -> void* {
    void* p = ws + off;
    off += (bytes + 255) & ~(size_t)255;
    return p;
  };
  float* gab = (float*)alloc((size_t)NB * NH * SQ * SQ * 4);
  float* h   = (float*)alloc((size_t)MROWS * DM * 4);
  bf16* y    = (bf16*)alloc((size_t)MROWS * DM * 2);
  bf16* ctx  = (bf16*)alloc((size_t)MROWS * DM * 2);
  bf16* t1   = (bf16*)alloc((size_t)MROWS * DF * 2);
  float* p0  = (float*)alloc((size_t)MROWS * DM * 4);
  float* p1  = (float*)alloc((size_t)MROWS * DM * 4);

  size_t need_hoist = off + ((size_t)NLAY * 4 * WQKVO + 2 * (size_t)NLAY * WFF) * 2 + (1 << 20);
  bool hoist = ws_size >= need_hoist;
  short* wT  = (short*)alloc((hoist ? (size_t)NLAY * 4 * WQKVO : 4 * WQKVO) * 2);
  short* w1T = (short*)alloc((hoist ? (size_t)NLAY * WFF : WFF) * 2);
  short* w2T = (short*)alloc((hoist ? (size_t)NLAY * WFF : WFF) * 2);

  dim3 blk(256);
  if (hoist) {
    ProArgs pa;
    pa.x = x; pa.ind = ind; pa.outd = outd;
    pa.atom = atom; pa.ide = ide; pa.ode = ode; pa.gtok = gtok;
    pa.ab = ab; pa.virt = virt; pa.g = ln1g; pa.bb = ln1b;
    pa.h = h; pa.y = y; pa.gab = gab;
    pa.spos = spos; pa.eidx = eidx; pa.eemb = eemb; pa.edemb = edemb; pa.semb = semb;
    pa.ta.wq = wq; pa.ta.wk = wk; pa.ta.wv = wv; pa.ta.wo = wo;
    pa.ta.w1 = w1; pa.ta.w2 = w2;
    pa.ta.wT = wT; pa.ta.w1T = w1T; pa.ta.w2T = w2T;
    k_prologue<<<dim3(2048 + MROWS + 20736), blk, 0, stream>>>(pa);
  } else {
    k_nodefeat_ln<<<dim3(MROWS), blk, 0, stream>>>(x, ind, outd, atom, ide, ode, gtok,
                                                   ab, virt, ln1g, ln1b, h, y, gab);
    k_gab_edge<<<dim3(NB * ND * 2), blk, 0, stream>>>(spos, eidx, eemb, edemb, semb, ab, gab);
  }

  for (int l = 0; l < NLAY; l++) {
    if (!hoist) {
      Ptrs4 pq;
      pq.p[0] = wq + (size_t)l * DD2; pq.p[1] = wk + (size_t)l * DD2;
      pq.p[2] = wv + (size_t)l * DD2; pq.p[3] = wo + (size_t)l * DD2;
      k_transpose<4><<<dim3(12, 12, 4), blk, 0, stream>>>(pq, wT, DM, DM, 0);
      Ptrs4 pa2; pa2.p[0] = w1 + (size_t)l * WFF; pa2.p[1] = pa2.p[2] = pa2.p[3] = pa2.p[0];
      k_transpose<1><<<dim3(12, 48, 1), blk, 0, stream>>>(pa2, w1T, DM, DF, 0);
      Ptrs4 pb; pb.p[0] = w2 + (size_t)l * WFF; pb.p[1] = pb.p[2] = pb.p[3] = pb.p[0];
      k_transpose<1><<<dim3(48, 12, 1), blk, 0, stream>>>(pb, w2T, DF, DM, 0);
    }
    const short* wTl  = wT  + (hoist ? (size_t)l * 4 * WQKVO : 0);
    const short* w1Tl = w1T + (hoist ? (size_t)l * WFF : 0);
    const short* w2Tl = w2T + (hoist ? (size_t)l * WFF : 0);

    // fused QKV + attention
    k_fattn<<<dim3(NB * NH), blk, 0, stream>>>(y, wTl, bq + l * DM, bk + l * DM,
                                               bv + l * DM, gab, ctx);

    GemmPtrs go;  // Wo split-K: K=768 -> 2 x 384
    go.bt[0] = wTl + 3 * DD2; go.bt[1] = wTl + 3 * DD2 + 384;
    go.bias[0] = go.bias[1] = nullptr;
    go.out[0] = p0; go.out[1] = p1;
    go.aoff[0] = 0; go.aoff[1] = 384;
    go.bt[2] = go.bt[0]; go.out[2] = p0; go.aoff[2] = 0; go.bias[2] = nullptr;
    k_gemm64<3><<<dim3(33, 6, 2), blk, 0, stream>>>((const short*)ctx, go, MROWS, DM, 384, DM, DM);

    k_ln_add2<<<dim3(MROWS), blk, 0, stream>>>(h, p0, p1, bo + l * DM,
                                               ln2g + l * DM, ln2b + l * DM, y);

    GemmPtrs g1;
    g1.bt[0] = g1.bt[1] = g1.bt[2] = w1Tl;
    g1.bias[0] = g1.bias[1] = g1.bias[2] = b1 + l * DF;
    g1.out[0] = g1.out[1] = g1.out[2] = t1;
    g1.aoff[0] = g1.aoff[1] = g1.aoff[2] = 0;
    k_gemm128<2><<<dim3(17, 24, 1), blk, 0, stream>>>((const short*)y, g1, MROWS, DF, DM, DM, DM);

    GemmPtrs g2;  // FFN2 split-K: K=3072 -> 2 x 1536
    g2.bt[0] = w2Tl; g2.bt[1] = w2Tl + 1536;
    g2.bias[0] = g2.bias[1] = nullptr;
    g2.out[0] = p0; g2.out[1] = p1;
    g2.aoff[0] = 0; g2.aoff[1] = 1536;
    g2.bt[2] = g2.bt[0]; g2.out[2] = p0; g2.aoff[2] = 0; g2.bias[2] = nullptr;
    k_gemm64<3><<<dim3(33, 6, 2), blk, 0, stream>>>((const short*)t1, g2, MROWS, DM, 1536, DF, DF);

    if (l < NLAY - 1) {
      k_ln_add2<<<dim3(MROWS), blk, 0, stream>>>(h, p0, p1, b2 + l * DM,
                                                 ln1g + (l + 1) * DM, ln1b + (l + 1) * DM, y);
    } else {
      k_final_add2<<<dim3(NB), blk, 0, stream>>>(h, p0, p1, b2 + l * DM, fg, fb, ow, ob, out);
    }
  }
}